// Round 3
// baseline (6955.691 us; speedup 1.0000x reference)
//
#include <hip/hip_runtime.h>

typedef unsigned short u16;

#define B_   128
#define N_   388
#define NT   128
#define NS   260
#define C_   768
#define H_   12
#define D_   64
#define K3   2304   // 3*C

#define QKV_LEN  114425856ll   // 49664*2304  (bf16 ws)
#define KSM_LEN  25559040ll    // 33280*768
#define CAT_LEN  38141952ll    // 49664*768
#define MEM_LEN  6291456ll     // 128*12*64*64 (f32, in d_out)

__device__ __forceinline__ float bf2f(u16 u) {
    union { unsigned int i; float f; } v; v.i = ((unsigned int)u) << 16; return v.f;
}
__device__ __forceinline__ u16 f2bf(float f) {
    union { float f; unsigned int i; } v; v.f = f;
    unsigned int r = v.i + 0x7fffu + ((v.i >> 16) & 1u);
    return (u16)(r >> 16);
}
__device__ __forceinline__ float elu1(float x) { return x > 0.f ? x + 1.f : __expf(x); }

// ---------------------------------------------------------------------------
// C[M x Nout] = A @ W^T + bias. K fixed = 768. W,bias are f32.
// A is f32 (AF32=1) or bf16 ws (AF32=0). C is f32 (CF32=1) or bf16 ws.
// A row r -> b = r / rows_per_b, j = r % rows_per_b,
//   elem index = off0 + b*stride_b + j*stride_r
// BM=128, BN=64, BK=16, 256 threads, 8x4 per thread, f32 accumulate.
// ---------------------------------------------------------------------------
template<int AF32, int CF32>
__global__ __launch_bounds__(256) void gemm_bt(
    const void* __restrict__ Av, long long off0, int rows_per_b,
    long long stride_b, long long stride_r,
    const float* __restrict__ W, const float* __restrict__ bias,
    void* __restrict__ Cv, int Nout)
{
    __shared__ float As[16][132];
    __shared__ float Bs[16][68];

    int t  = threadIdx.x;
    int m0 = blockIdx.y * 128;
    int n0 = blockIdx.x * 64;

    int ar = t >> 1;          // 128 rows
    int ak = (t & 1) * 8;     // two 8-wide k-halves
    int grow = m0 + ar;
    int ab = grow / rows_per_b;
    int aj = grow - ab * rows_per_b;
    long long abase = off0 + (long long)ab * stride_b + (long long)aj * stride_r + ak;

    int br = t >> 2;          // 64 rows
    int bk = (t & 3) * 4;     // four 4-wide k-quarters
    const float* bptr = W + (long long)(n0 + br) * C_ + bk;

    int tm = t & 15;
    int tn = t >> 4;

    float acc[8][4];
#pragma unroll
    for (int i = 0; i < 8; i++)
#pragma unroll
        for (int j = 0; j < 4; j++) acc[i][j] = 0.f;

    for (int kt = 0; kt < C_; kt += 16) {
        if (AF32) {
            const float* aptr = (const float*)Av + abase + kt;
            float4 a0 = *(const float4*)(aptr);
            float4 a1 = *(const float4*)(aptr + 4);
            As[ak + 0][ar] = a0.x; As[ak + 1][ar] = a0.y;
            As[ak + 2][ar] = a0.z; As[ak + 3][ar] = a0.w;
            As[ak + 4][ar] = a1.x; As[ak + 5][ar] = a1.y;
            As[ak + 6][ar] = a1.z; As[ak + 7][ar] = a1.w;
        } else {
            const u16* aptr = (const u16*)Av + abase + kt;
            uint4 a4 = *(const uint4*)(aptr);
            As[ak + 0][ar] = bf2f((u16)(a4.x)); As[ak + 1][ar] = bf2f((u16)(a4.x >> 16));
            As[ak + 2][ar] = bf2f((u16)(a4.y)); As[ak + 3][ar] = bf2f((u16)(a4.y >> 16));
            As[ak + 4][ar] = bf2f((u16)(a4.z)); As[ak + 5][ar] = bf2f((u16)(a4.z >> 16));
            As[ak + 6][ar] = bf2f((u16)(a4.w)); As[ak + 7][ar] = bf2f((u16)(a4.w >> 16));
        }
        float4 b4 = *(const float4*)(bptr + kt);
        Bs[bk + 0][br] = b4.x; Bs[bk + 1][br] = b4.y;
        Bs[bk + 2][br] = b4.z; Bs[bk + 3][br] = b4.w;
        __syncthreads();
#pragma unroll
        for (int k = 0; k < 16; k++) {
            float a[8], b[4];
            *(float4*)&a[0] = *(const float4*)&As[k][tm * 8];
            *(float4*)&a[4] = *(const float4*)&As[k][tm * 8 + 4];
            *(float4*)&b[0] = *(const float4*)&Bs[k][tn * 4];
#pragma unroll
            for (int i = 0; i < 8; i++)
#pragma unroll
                for (int j = 0; j < 4; j++)
                    acc[i][j] = fmaf(a[i], b[j], acc[i][j]);
        }
        __syncthreads();
    }

#pragma unroll
    for (int j = 0; j < 4; j++) {
        float bb = bias[n0 + tn * 4 + j];
#pragma unroll
        for (int i = 0; i < 8; i++) {
            float v = acc[i][j] + bb;
            long long idx = (long long)(m0 + tm * 8 + i) * Nout + (n0 + tn * 4 + j);
            if (CF32) ((float*)Cv)[idx] = v;
            else      ((u16*)Cv)[idx]  = f2bf(v);
        }
    }
}

// ---------------------------------------------------------------------------
// attn_mt: per (b,h), 128 threads, one q-row per thread, flash over 4 tiles
// of 32 keys. qkv ws is bf16. Writes concat rows [0, NT).
// ---------------------------------------------------------------------------
__global__ __launch_bounds__(128, 2) void attn_mt_kernel(
    const u16* __restrict__ qkv, u16* __restrict__ concat)
{
    __shared__ float Ks[32][68];
    __shared__ float Vs[32][68];

    int bh = blockIdx.x;
    int b = bh / H_, h = bh % H_;
    int tid = threadIdx.x;

    const u16* qrow = qkv + ((long long)(b * N_ + tid)) * K3 + h * D_;
    float q[64];
#pragma unroll
    for (int c = 0; c < 64; c += 8) {
        uint4 t4 = *(const uint4*)(qrow + c);
        q[c + 0] = bf2f((u16)(t4.x)); q[c + 1] = bf2f((u16)(t4.x >> 16));
        q[c + 2] = bf2f((u16)(t4.y)); q[c + 3] = bf2f((u16)(t4.y >> 16));
        q[c + 4] = bf2f((u16)(t4.z)); q[c + 5] = bf2f((u16)(t4.z >> 16));
        q[c + 6] = bf2f((u16)(t4.w)); q[c + 7] = bf2f((u16)(t4.w >> 16));
    }

    float mcur = -1e30f, l = 0.f, acc[64];
#pragma unroll
    for (int i = 0; i < 64; i++) acc[i] = 0.f;

    for (int kt = 0; kt < NT; kt += 32) {
        for (int idx = tid; idx < 32 * 16; idx += 128) {
            int j = idx >> 4, c = (idx & 15) * 4;
            long long roff = ((long long)(b * N_ + kt + j)) * K3 + h * D_ + c;
            uint2 kk = *(const uint2*)(qkv + roff + C_);
            uint2 vv = *(const uint2*)(qkv + roff + 2 * C_);
            Ks[j][c + 0] = bf2f((u16)(kk.x)); Ks[j][c + 1] = bf2f((u16)(kk.x >> 16));
            Ks[j][c + 2] = bf2f((u16)(kk.y)); Ks[j][c + 3] = bf2f((u16)(kk.y >> 16));
            Vs[j][c + 0] = bf2f((u16)(vv.x)); Vs[j][c + 1] = bf2f((u16)(vv.x >> 16));
            Vs[j][c + 2] = bf2f((u16)(vv.y)); Vs[j][c + 3] = bf2f((u16)(vv.y >> 16));
        }
        __syncthreads();

        float sc[32];
        float tmax = mcur;
#pragma unroll
        for (int j = 0; j < 32; j++) {
            float s0 = 0, s1 = 0, s2 = 0, s3 = 0;
#pragma unroll
            for (int dd = 0; dd < 64; dd += 4) {
                float4 kk = *(const float4*)&Ks[j][dd];
                s0 = fmaf(q[dd],     kk.x, s0);
                s1 = fmaf(q[dd + 1], kk.y, s1);
                s2 = fmaf(q[dd + 2], kk.z, s2);
                s3 = fmaf(q[dd + 3], kk.w, s3);
            }
            float s = ((s0 + s1) + (s2 + s3)) * 0.125f;
            sc[j] = s;
            tmax = fmaxf(tmax, s);
        }
        float corr = __expf(mcur - tmax);
        l *= corr;
#pragma unroll
        for (int i = 0; i < 64; i++) acc[i] *= corr;
#pragma unroll
        for (int j = 0; j < 32; j++) {
            float p = __expf(sc[j] - tmax);
            l += p;
#pragma unroll
            for (int dd = 0; dd < 64; dd += 4) {
                float4 vv = *(const float4*)&Vs[j][dd];
                acc[dd]     += p * vv.x;
                acc[dd + 1] += p * vv.y;
                acc[dd + 2] += p * vv.z;
                acc[dd + 3] += p * vv.w;
            }
        }
        mcur = tmax;
        __syncthreads();
    }

    float invl = 1.f / l;
    u16* orow = concat + ((long long)(b * N_ + tid)) * C_ + h * D_;
#pragma unroll
    for (int dd = 0; dd < 64; dd++) orow[dd] = f2bf(acc[dd] * invl);
}

// ---------------------------------------------------------------------------
// attn_s: per (b,h), 320 threads (260 active q-rows), flash over 13 tiles.
// mem/z/betas are f32 inputs. Fuses sigma_q@mem/(sigma_q@z) + beta blend.
// Writes concat rows [NT, N).
// ---------------------------------------------------------------------------
__global__ __launch_bounds__(320, 2) void attn_s_kernel(
    const u16* __restrict__ qkv, const float* __restrict__ memin,
    const float* __restrict__ zin, const float* __restrict__ betas,
    u16* __restrict__ concat)
{
    __shared__ float Ks[32][68];
    __shared__ float Vs[32][68];
    __shared__ float mem_lds[4096];
    __shared__ float z_lds[64];
    __shared__ float beta_lds[64];

    int bh = blockIdx.x;
    int b = bh / H_, h = bh % H_;
    int tid = threadIdx.x;

    for (int idx = tid; idx < 4096; idx += 320)
        mem_lds[idx] = memin[(long long)bh * 4096 + idx];
    if (tid < 64) {
        z_lds[tid] = zin[bh * 64 + tid];
        float bb = betas[h * D_ + tid];
        beta_lds[tid] = 1.f / (1.f + __expf(-bb));
    }

    int qi = tid;
    bool active = qi < NS;
    int qn = active ? qi : (NS - 1);
    const u16* qrow = qkv + ((long long)(b * N_ + NT + qn)) * K3 + h * D_;
    float q[64];
#pragma unroll
    for (int c = 0; c < 64; c += 8) {
        uint4 t4 = *(const uint4*)(qrow + c);
        q[c + 0] = bf2f((u16)(t4.x)); q[c + 1] = bf2f((u16)(t4.x >> 16));
        q[c + 2] = bf2f((u16)(t4.y)); q[c + 3] = bf2f((u16)(t4.y >> 16));
        q[c + 4] = bf2f((u16)(t4.z)); q[c + 5] = bf2f((u16)(t4.z >> 16));
        q[c + 6] = bf2f((u16)(t4.w)); q[c + 7] = bf2f((u16)(t4.w >> 16));
    }

    float mcur = -1e30f, l = 0.f, acc[64];
#pragma unroll
    for (int i = 0; i < 64; i++) acc[i] = 0.f;

    __syncthreads();

    for (int kt = 0; kt < N_; kt += 32) {
        int jn = (N_ - kt < 32) ? (N_ - kt) : 32;
        for (int idx = tid; idx < 32 * 16; idx += 320) {
            int j = idx >> 4, c = (idx & 15) * 4;
            if (j < jn) {
                long long roff = ((long long)(b * N_ + kt + j)) * K3 + h * D_ + c;
                uint2 kk = *(const uint2*)(qkv + roff + C_);
                uint2 vv = *(const uint2*)(qkv + roff + 2 * C_);
                Ks[j][c + 0] = bf2f((u16)(kk.x)); Ks[j][c + 1] = bf2f((u16)(kk.x >> 16));
                Ks[j][c + 2] = bf2f((u16)(kk.y)); Ks[j][c + 3] = bf2f((u16)(kk.y >> 16));
                Vs[j][c + 0] = bf2f((u16)(vv.x)); Vs[j][c + 1] = bf2f((u16)(vv.x >> 16));
                Vs[j][c + 2] = bf2f((u16)(vv.y)); Vs[j][c + 3] = bf2f((u16)(vv.y >> 16));
            }
        }
        __syncthreads();

        if (active) {
            float sc[32];
            float tmax = mcur;
#pragma unroll
            for (int j = 0; j < 32; j++) {
                if (j < jn) {
                    float s0 = 0, s1 = 0, s2 = 0, s3 = 0;
#pragma unroll
                    for (int dd = 0; dd < 64; dd += 4) {
                        float4 kk = *(const float4*)&Ks[j][dd];
                        s0 = fmaf(q[dd],     kk.x, s0);
                        s1 = fmaf(q[dd + 1], kk.y, s1);
                        s2 = fmaf(q[dd + 2], kk.z, s2);
                        s3 = fmaf(q[dd + 3], kk.w, s3);
                    }
                    float s = ((s0 + s1) + (s2 + s3)) * 0.125f;
                    sc[j] = s;
                    tmax = fmaxf(tmax, s);
                }
            }
            float corr = __expf(mcur - tmax);
            l *= corr;
#pragma unroll
            for (int i = 0; i < 64; i++) acc[i] *= corr;
#pragma unroll
            for (int j = 0; j < 32; j++) {
                if (j < jn) {
                    float p = __expf(sc[j] - tmax);
                    l += p;
#pragma unroll
                    for (int dd = 0; dd < 64; dd += 4) {
                        float4 vv = *(const float4*)&Vs[j][dd];
                        acc[dd]     += p * vv.x;
                        acc[dd + 1] += p * vv.y;
                        acc[dd + 2] += p * vv.z;
                        acc[dd + 3] += p * vv.w;
                    }
                }
            }
            mcur = tmax;
        }
        __syncthreads();
    }

    if (active) {
        float invl = 1.f / l;
#pragma unroll
        for (int dd = 0; dd < 64; dd++) q[dd] = elu1(q[dd]);
        float denom = 0.f;
#pragma unroll
        for (int dd = 0; dd < 64; dd++) denom = fmaf(q[dd], z_lds[dd], denom);
        float rden = 1.f / denom;
        u16* orow = concat + ((long long)(b * N_ + NT + qi)) * C_ + h * D_;
#pragma unroll
        for (int e = 0; e < 64; e++) {
            float n0 = 0, n1 = 0, n2 = 0, n3 = 0;
#pragma unroll
            for (int dd = 0; dd < 64; dd += 4) {
                n0 = fmaf(q[dd],     mem_lds[dd * 64 + e],       n0);
                n1 = fmaf(q[dd + 1], mem_lds[(dd + 1) * 64 + e], n1);
                n2 = fmaf(q[dd + 2], mem_lds[(dd + 2) * 64 + e], n2);
                n3 = fmaf(q[dd + 3], mem_lds[(dd + 3) * 64 + e], n3);
            }
            float am = ((n0 + n1) + (n2 + n3)) * rden;
            float bb = beta_lds[e];
            float o = bb * am + (1.f - bb) * (acc[e] * invl);
            orow[e] = f2bf(o);
        }
    }
}

// ---------------------------------------------------------------------------
// sigma_pred: per (b,h), 256 threads. In place on bf16 ws:
//   ksm <- sigma_k = elu(ksm)+1 ; vsm <- v_s_mem - pred. Writes f32 z_new.
// ---------------------------------------------------------------------------
__global__ __launch_bounds__(256) void sigma_pred_kernel(
    u16* __restrict__ ksm, u16* __restrict__ vsm,
    const float* __restrict__ memin, const float* __restrict__ zin,
    float* __restrict__ z_out)
{
    __shared__ float mem_lds[4096];
    __shared__ float z_lds[64];
    __shared__ float zred[4][64];

    int bh = blockIdx.x;
    int b = bh / H_, h = bh % H_;
    int tid = threadIdx.x;
    int wv = tid >> 6, lane = tid & 63;

    for (int idx = tid; idx < 4096; idx += 256)
        mem_lds[idx] = memin[(long long)bh * 4096 + idx];
    if (tid < 64) z_lds[tid] = zin[bh * 64 + tid];
    __syncthreads();

    float zacc = 0.f;
    for (int n = wv; n < NS; n += 4) {
        long long roff = ((long long)(b * NS + n)) * C_ + h * D_;
        float x = bf2f(ksm[roff + lane]);
        float sig = elu1(x);
        ksm[roff + lane] = f2bf(sig);
        zacc += sig;

        float tz = sig * z_lds[lane];
#pragma unroll
        for (int o = 32; o; o >>= 1) tz += __shfl_xor(tz, o);
        float rden = 1.f / tz;

        float num = 0.f;
#pragma unroll
        for (int dd = 0; dd < 64; dd++)
            num = fmaf(__shfl(sig, dd), mem_lds[dd * 64 + lane], num);
        float pred = num * rden;

        float w = bf2f(vsm[roff + lane]) - pred;
        vsm[roff + lane] = f2bf(w);
    }
    zred[wv][lane] = zacc;
    __syncthreads();
    if (wv == 0) {
        float tot = zred[0][lane] + zred[1][lane] + zred[2][lane] + zred[3][lane];
        z_out[bh * 64 + lane] = zin[bh * 64 + lane] + tot;
    }
}

// ---------------------------------------------------------------------------
// mem_update: per (b,h), 256 threads. mem_new (f32) = mem (f32) +
//   sum_n sigma[n][d] * w[n][e]   (sigma/w in bf16 ws)
// ---------------------------------------------------------------------------
__global__ __launch_bounds__(256) void mem_update_kernel(
    const u16* __restrict__ ksm, const u16* __restrict__ vsm,
    const float* __restrict__ memin, float* __restrict__ mem_out)
{
    int bh = blockIdx.x;
    int b = bh / H_, h = bh % H_;
    int t = threadIdx.x;
    int e = t & 63, dg = t >> 6;

    float acc[16];
#pragma unroll
    for (int i = 0; i < 16; i++) acc[i] = 0.f;

    for (int n = 0; n < NS; n++) {
        long long roff = ((long long)(b * NS + n)) * C_ + h * D_;
        float wval = bf2f(vsm[roff + e]);
        uint4 s4a = *(const uint4*)(ksm + roff + dg * 16);
        uint4 s4b = *(const uint4*)(ksm + roff + dg * 16 + 8);
        float sv[16];
        sv[0]  = bf2f((u16)s4a.x); sv[1]  = bf2f((u16)(s4a.x >> 16));
        sv[2]  = bf2f((u16)s4a.y); sv[3]  = bf2f((u16)(s4a.y >> 16));
        sv[4]  = bf2f((u16)s4a.z); sv[5]  = bf2f((u16)(s4a.z >> 16));
        sv[6]  = bf2f((u16)s4a.w); sv[7]  = bf2f((u16)(s4a.w >> 16));
        sv[8]  = bf2f((u16)s4b.x); sv[9]  = bf2f((u16)(s4b.x >> 16));
        sv[10] = bf2f((u16)s4b.y); sv[11] = bf2f((u16)(s4b.y >> 16));
        sv[12] = bf2f((u16)s4b.z); sv[13] = bf2f((u16)(s4b.w >> 16) * 0.f + (u16)(s4b.z >> 16));
        sv[14] = bf2f((u16)s4b.w); sv[15] = bf2f((u16)(s4b.w >> 16));
#pragma unroll
        for (int i = 0; i < 16; i++) acc[i] = fmaf(sv[i], wval, acc[i]);
    }

    long long mbase = (long long)bh * 4096;
#pragma unroll
    for (int i = 0; i < 16; i++) {
        int dd = dg * 16 + i;
        mem_out[mbase + dd * 64 + e] = memin[mbase + dd * 64 + e] + acc[i];
    }
}

// ---------------------------------------------------------------------------
extern "C" void kernel_launch(void* const* d_in, const int* in_sizes, int n_in,
                              void* d_out, int out_size, void* d_ws, size_t ws_size,
                              hipStream_t stream)
{
    const float* x      = (const float*)d_in[0];
    const float* mem    = (const float*)d_in[1];
    const float* z      = (const float*)d_in[2];
    const float* qkv_w  = (const float*)d_in[3];
    const float* qkv_b  = (const float*)d_in[4];
    const float* proj_w = (const float*)d_in[5];
    const float* proj_b = (const float*)d_in[6];
    const float* memk_w = (const float*)d_in[7];
    const float* memk_b = (const float*)d_in[8];
    const float* memv_w = (const float*)d_in[9];
    const float* memv_b = (const float*)d_in[10];
    const float* betas  = (const float*)d_in[11];

    u16* ws     = (u16*)d_ws;
    u16* qkv    = ws;                 // bf16 ws
    u16* ksm    = qkv + QKV_LEN;
    u16* vsm    = ksm + KSM_LEN;
    u16* concat = vsm + KSM_LEN;

    float* out     = (float*)d_out;
    float* mem_out = out + CAT_LEN;
    float* z_out   = mem_out + MEM_LEN;

    // 1. qkv = x @ qkv_w^T + qkv_b           (A f32 -> C bf16 ws)
    gemm_bt<1, 0><<<dim3(K3 / 64, 49664 / 128), dim3(256), 0, stream>>>(
        x, 0ll, 49664, 0ll, 768ll, qkv_w, qkv_b, qkv, K3);
    // 2. k_s_mem = k_f[:, NT:, :] @ memk_w^T (A bf16 ws -> C bf16 ws)
    gemm_bt<0, 0><<<dim3(C_ / 64, 33280 / 128), dim3(256), 0, stream>>>(
        qkv, (long long)(NT * K3 + C_), NS, (long long)N_ * K3, (long long)K3,
        memk_w, memk_b, ksm, C_);
    // 3. v_s_mem = v_f[:, NT:, :] @ memv_w^T
    gemm_bt<0, 0><<<dim3(C_ / 64, 33280 / 128), dim3(256), 0, stream>>>(
        qkv, (long long)(NT * K3 + 2 * C_), NS, (long long)N_ * K3, (long long)K3,
        memv_w, memv_b, vsm, C_);
    // 4. token/token attention -> concat[:, :NT]
    attn_mt_kernel<<<dim3(B_ * H_), dim3(128), 0, stream>>>(qkv, concat);
    // 5. spatial attention + memory readout + beta blend -> concat[:, NT:]
    attn_s_kernel<<<dim3(B_ * H_), dim3(320), 0, stream>>>(qkv, mem, z, betas, concat);
    // 6. sigma_k / pred (in-place) + z_new (f32)
    sigma_pred_kernel<<<dim3(B_ * H_), dim3(256), 0, stream>>>(ksm, vsm, mem, z, z_out);
    // 7. mem_new (f32)
    mem_update_kernel<<<dim3(B_ * H_), dim3(256), 0, stream>>>(ksm, vsm, mem, mem_out);
    // 8. out = concat @ proj_w^T + proj_b    (A bf16 ws -> C f32 out)
    gemm_bt<0, 1><<<dim3(C_ / 64, 49664 / 128), dim3(256), 0, stream>>>(
        concat, 0ll, 49664, 0ll, 768ll, proj_w, proj_b, out, C_);
}

// Round 4
// 3233.160 us; speedup vs baseline: 2.1514x; 2.1514x over previous
//
#include <hip/hip_runtime.h>

typedef unsigned short u16;
typedef __attribute__((ext_vector_type(8))) short  vbf8;   // 8 bf16 (4 VGPRs)
typedef __attribute__((ext_vector_type(4))) float  vf4;    // 4 f32 acc

#define B_   128
#define N_   388
#define NT   128
#define NS   260
#define C_   768
#define H_   12
#define D_   64
#define K3   2304   // 3*C

#define QKV_LEN  114425856ll   // 49664*2304  (bf16 ws)
#define KSM_LEN  25559040ll    // 33280*768
#define CAT_LEN  38141952ll    // 49664*768
#define MEM_LEN  6291456ll     // 128*12*64*64 (f32, in d_out)

// bf16 weights: [qkv_w | memk_w | memv_w | proj_w]
#define WOFF_QKV  0ll
#define WOFF_MEMK 1769472ll
#define WOFF_MEMV 2359296ll
#define WOFF_PROJ 2949120ll
__device__ __align__(16) u16 g_wbf[3538944];

__device__ __forceinline__ float bf2f(u16 u) {
    union { unsigned int i; float f; } v; v.i = ((unsigned int)u) << 16; return v.f;
}
__device__ __forceinline__ u16 f2bf(float f) {
    union { float f; unsigned int i; } v; v.f = f;
    unsigned int r = v.i + 0x7fffu + ((v.i >> 16) & 1u);
    return (u16)(r >> 16);
}
__device__ __forceinline__ float elu1(float x) { return x > 0.f ? x + 1.f : __expf(x); }

// ---------------------------------------------------------------------------
// f32 -> bf16 converters (n multiple of 8)
// ---------------------------------------------------------------------------
__global__ __launch_bounds__(256) void convert_bf16(
    const float* __restrict__ src, u16* __restrict__ dst, long long n)
{
    long long i0 = ((long long)blockIdx.x * 256 + threadIdx.x) * 8;
    long long stride = (long long)gridDim.x * 256 * 8;
    for (long long i = i0; i < n; i += stride) {
        float4 a = *(const float4*)(src + i);
        float4 b = *(const float4*)(src + i + 4);
        ushort4 u1; u1.x = f2bf(a.x); u1.y = f2bf(a.y); u1.z = f2bf(a.z); u1.w = f2bf(a.w);
        ushort4 u2; u2.x = f2bf(b.x); u2.y = f2bf(b.y); u2.z = f2bf(b.z); u2.w = f2bf(b.w);
        *(ushort4*)(dst + i)     = u1;
        *(ushort4*)(dst + i + 4) = u2;
    }
}

__global__ __launch_bounds__(256) void convert_wbf(
    const float* __restrict__ src, long long dst_off, long long n)
{
    u16* dst = g_wbf + dst_off;
    long long i0 = ((long long)blockIdx.x * 256 + threadIdx.x) * 8;
    long long stride = (long long)gridDim.x * 256 * 8;
    for (long long i = i0; i < n; i += stride) {
        float4 a = *(const float4*)(src + i);
        float4 b = *(const float4*)(src + i + 4);
        ushort4 u1; u1.x = f2bf(a.x); u1.y = f2bf(a.y); u1.z = f2bf(a.z); u1.w = f2bf(a.w);
        ushort4 u2; u2.x = f2bf(b.x); u2.y = f2bf(b.y); u2.z = f2bf(b.z); u2.w = f2bf(b.w);
        *(ushort4*)(dst + i)     = u1;
        *(ushort4*)(dst + i + 4) = u2;
    }
}

// ---------------------------------------------------------------------------
// MFMA GEMM: C[M x Nout] = A @ W^T + bias.  K = 768 fixed.
// A bf16 (row addressing: r -> b=r/rows_per_b, j=r%rows_per_b,
//   elem = off0 + b*stride_b + j*stride_r), W bf16 [Nout][768] (in g_wbf),
// bias f32, C f32 (CF32=1) or bf16 (CF32=0).
// 128x128 tile, BK=32, 256 thr (4 waves 2x2), 4x4 16x16x32 frags/wave,
// reg-staged double-buffered LDS, one barrier per K-step.
// ---------------------------------------------------------------------------
template<int CF32>
__global__ __launch_bounds__(256) void gemm_mfma(
    const u16* __restrict__ A, long long off0, int rows_per_b,
    long long stride_b, long long stride_r,
    long long w_off, const float* __restrict__ bias,
    void* __restrict__ Cv, int Nout)
{
    __shared__ __align__(16) u16 lds[2][2][4096];   // [buf][A=0/B=1][128*32]

    const u16* W = g_wbf + w_off;

    int t  = threadIdx.x;
    int m0 = blockIdx.y * 128;
    int n0 = blockIdx.x * 128;

    // ---- staging addresses: thread t covers flat elems t*8 and 2048+t*8
    int r0 = t >> 2;           // row 0..63 (and +64)
    int c0 = (t & 3) * 8;      // k offset
    long long aoff0, aoff1;
    {
        int g1 = m0 + r0, g2 = m0 + r0 + 64;
        int b1 = g1 / rows_per_b, j1 = g1 - b1 * rows_per_b;
        int b2 = g2 / rows_per_b, j2 = g2 - b2 * rows_per_b;
        aoff0 = off0 + (long long)b1 * stride_b + (long long)j1 * stride_r + c0;
        aoff1 = off0 + (long long)b2 * stride_b + (long long)j2 * stride_r + c0;
    }
    const u16* wp0 = W + (long long)(n0 + r0) * 768 + c0;
    const u16* wp1 = W + (long long)(n0 + r0 + 64) * 768 + c0;

    // ---- fragment read offsets (elements)
    int lane = t & 63;
    int wid  = t >> 6;
    int wm = wid >> 1, wn = wid & 1;
    int lr = lane & 15;         // frag row (A) / frag col-source row (B)
    int kg = lane >> 4;         // k-group
    int a_rd = (wm * 64 + lr) * 32 + kg * 8;
    int b_rd = (wn * 64 + lr) * 32 + kg * 8;

    vf4 acc[4][4];
#pragma unroll
    for (int i = 0; i < 4; i++)
#pragma unroll
        for (int j = 0; j < 4; j++) acc[i][j] = vf4{0.f, 0.f, 0.f, 0.f};

    // ---- prologue: stage tile 0
    {
        vbf8 sa0 = *(const vbf8*)(A + aoff0);
        vbf8 sa1 = *(const vbf8*)(A + aoff1);
        vbf8 sb0 = *(const vbf8*)(wp0);
        vbf8 sb1 = *(const vbf8*)(wp1);
        *(vbf8*)&lds[0][0][t * 8]        = sa0;
        *(vbf8*)&lds[0][0][2048 + t * 8] = sa1;
        *(vbf8*)&lds[0][1][t * 8]        = sb0;
        *(vbf8*)&lds[0][1][2048 + t * 8] = sb1;
    }

    int cur = 0;
    for (int kt = 0; kt < 768; kt += 32) {
        bool last = (kt == 768 - 32);
        vbf8 na0, na1, nb0, nb1;
        if (!last) {   // issue next-tile loads early (hide HBM latency under MFMA)
            na0 = *(const vbf8*)(A + aoff0 + kt + 32);
            na1 = *(const vbf8*)(A + aoff1 + kt + 32);
            nb0 = *(const vbf8*)(wp0 + kt + 32);
            nb1 = *(const vbf8*)(wp1 + kt + 32);
        }
        __syncthreads();   // buf[cur] writes visible; prior reads of buf[cur^1] done

        vbf8 af[4], bf[4];
#pragma unroll
        for (int f = 0; f < 4; f++) {
            af[f] = *(const vbf8*)&lds[cur][0][a_rd + f * 512];
            bf[f] = *(const vbf8*)&lds[cur][1][b_rd + f * 512];
        }
#pragma unroll
        for (int i = 0; i < 4; i++)
#pragma unroll
            for (int j = 0; j < 4; j++)
                acc[i][j] = __builtin_amdgcn_mfma_f32_16x16x32_bf16(
                    af[i], bf[j], acc[i][j], 0, 0, 0);

        if (!last) {
            *(vbf8*)&lds[cur ^ 1][0][t * 8]        = na0;
            *(vbf8*)&lds[cur ^ 1][0][2048 + t * 8] = na1;
            *(vbf8*)&lds[cur ^ 1][1][t * 8]        = nb0;
            *(vbf8*)&lds[cur ^ 1][1][2048 + t * 8] = nb1;
            cur ^= 1;
        }
    }

    // ---- epilogue: C/D layout col=lane&15, row=(lane>>4)*4+reg [m89/m91]
#pragma unroll
    for (int i = 0; i < 4; i++) {
        int row = m0 + wm * 64 + i * 16 + kg * 4;
#pragma unroll
        for (int j = 0; j < 4; j++) {
            int col = n0 + wn * 64 + j * 16 + lr;
            float bb = bias[col];
#pragma unroll
            for (int r = 0; r < 4; r++) {
                float v = acc[i][j][r] + bb;
                long long idx = (long long)(row + r) * Nout + col;
                if (CF32) ((float*)Cv)[idx] = v;
                else      ((u16*)Cv)[idx]  = f2bf(v);
            }
        }
    }
}

// ---------------------------------------------------------------------------
// attn_mt: per (b,h), 128 threads, one q-row per thread, flash over 4 tiles
// of 32 keys. qkv ws is bf16. Writes concat rows [0, NT).
// ---------------------------------------------------------------------------
__global__ __launch_bounds__(128, 2) void attn_mt_kernel(
    const u16* __restrict__ qkv, u16* __restrict__ concat)
{
    __shared__ float Ks[32][68];
    __shared__ float Vs[32][68];

    int bh = blockIdx.x;
    int b = bh / H_, h = bh % H_;
    int tid = threadIdx.x;

    const u16* qrow = qkv + ((long long)(b * N_ + tid)) * K3 + h * D_;
    float q[64];
#pragma unroll
    for (int c = 0; c < 64; c += 8) {
        uint4 t4 = *(const uint4*)(qrow + c);
        q[c + 0] = bf2f((u16)(t4.x)); q[c + 1] = bf2f((u16)(t4.x >> 16));
        q[c + 2] = bf2f((u16)(t4.y)); q[c + 3] = bf2f((u16)(t4.y >> 16));
        q[c + 4] = bf2f((u16)(t4.z)); q[c + 5] = bf2f((u16)(t4.z >> 16));
        q[c + 6] = bf2f((u16)(t4.w)); q[c + 7] = bf2f((u16)(t4.w >> 16));
    }

    float mcur = -1e30f, l = 0.f, acc[64];
#pragma unroll
    for (int i = 0; i < 64; i++) acc[i] = 0.f;

    for (int kt = 0; kt < NT; kt += 32) {
        for (int idx = tid; idx < 32 * 16; idx += 128) {
            int j = idx >> 4, c = (idx & 15) * 4;
            long long roff = ((long long)(b * N_ + kt + j)) * K3 + h * D_ + c;
            uint2 kk = *(const uint2*)(qkv + roff + C_);
            uint2 vv = *(const uint2*)(qkv + roff + 2 * C_);
            Ks[j][c + 0] = bf2f((u16)(kk.x)); Ks[j][c + 1] = bf2f((u16)(kk.x >> 16));
            Ks[j][c + 2] = bf2f((u16)(kk.y)); Ks[j][c + 3] = bf2f((u16)(kk.y >> 16));
            Vs[j][c + 0] = bf2f((u16)(vv.x)); Vs[j][c + 1] = bf2f((u16)(vv.x >> 16));
            Vs[j][c + 2] = bf2f((u16)(vv.y)); Vs[j][c + 3] = bf2f((u16)(vv.y >> 16));
        }
        __syncthreads();

        float sc[32];
        float tmax = mcur;
#pragma unroll
        for (int j = 0; j < 32; j++) {
            float s0 = 0, s1 = 0, s2 = 0, s3 = 0;
#pragma unroll
            for (int dd = 0; dd < 64; dd += 4) {
                float4 kk = *(const float4*)&Ks[j][dd];
                s0 = fmaf(q[dd],     kk.x, s0);
                s1 = fmaf(q[dd + 1], kk.y, s1);
                s2 = fmaf(q[dd + 2], kk.z, s2);
                s3 = fmaf(q[dd + 3], kk.w, s3);
            }
            float s = ((s0 + s1) + (s2 + s3)) * 0.125f;
            sc[j] = s;
            tmax = fmaxf(tmax, s);
        }
        float corr = __expf(mcur - tmax);
        l *= corr;
#pragma unroll
        for (int i = 0; i < 64; i++) acc[i] *= corr;
#pragma unroll
        for (int j = 0; j < 32; j++) {
            float p = __expf(sc[j] - tmax);
            l += p;
#pragma unroll
            for (int dd = 0; dd < 64; dd += 4) {
                float4 vv = *(const float4*)&Vs[j][dd];
                acc[dd]     += p * vv.x;
                acc[dd + 1] += p * vv.y;
                acc[dd + 2] += p * vv.z;
                acc[dd + 3] += p * vv.w;
            }
        }
        mcur = tmax;
        __syncthreads();
    }

    float invl = 1.f / l;
    u16* orow = concat + ((long long)(b * N_ + tid)) * C_ + h * D_;
#pragma unroll
    for (int dd = 0; dd < 64; dd++) orow[dd] = f2bf(acc[dd] * invl);
}

// ---------------------------------------------------------------------------
// attn_s: per (b,h), 320 threads (260 active q-rows), flash over 13 tiles.
// mem/z/betas f32. Fuses sigma_q@mem/(sigma_q@z) + beta blend.
// Writes concat rows [NT, N).
// ---------------------------------------------------------------------------
__global__ __launch_bounds__(320, 2) void attn_s_kernel(
    const u16* __restrict__ qkv, const float* __restrict__ memin,
    const float* __restrict__ zin, const float* __restrict__ betas,
    u16* __restrict__ concat)
{
    __shared__ float Ks[32][68];
    __shared__ float Vs[32][68];
    __shared__ float mem_lds[4096];
    __shared__ float z_lds[64];
    __shared__ float beta_lds[64];

    int bh = blockIdx.x;
    int b = bh / H_, h = bh % H_;
    int tid = threadIdx.x;

    for (int idx = tid; idx < 4096; idx += 320)
        mem_lds[idx] = memin[(long long)bh * 4096 + idx];
    if (tid < 64) {
        z_lds[tid] = zin[bh * 64 + tid];
        float bb = betas[h * D_ + tid];
        beta_lds[tid] = 1.f / (1.f + __expf(-bb));
    }

    int qi = tid;
    bool active = qi < NS;
    int qn = active ? qi : (NS - 1);
    const u16* qrow = qkv + ((long long)(b * N_ + NT + qn)) * K3 + h * D_;
    float q[64];
#pragma unroll
    for (int c = 0; c < 64; c += 8) {
        uint4 t4 = *(const uint4*)(qrow + c);
        q[c + 0] = bf2f((u16)(t4.x)); q[c + 1] = bf2f((u16)(t4.x >> 16));
        q[c + 2] = bf2f((u16)(t4.y)); q[c + 3] = bf2f((u16)(t4.y >> 16));
        q[c + 4] = bf2f((u16)(t4.z)); q[c + 5] = bf2f((u16)(t4.z >> 16));
        q[c + 6] = bf2f((u16)(t4.w)); q[c + 7] = bf2f((u16)(t4.w >> 16));
    }

    float mcur = -1e30f, l = 0.f, acc[64];
#pragma unroll
    for (int i = 0; i < 64; i++) acc[i] = 0.f;

    __syncthreads();

    for (int kt = 0; kt < N_; kt += 32) {
        int jn = (N_ - kt < 32) ? (N_ - kt) : 32;
        for (int idx = tid; idx < 32 * 16; idx += 320) {
            int j = idx >> 4, c = (idx & 15) * 4;
            if (j < jn) {
                long long roff = ((long long)(b * N_ + kt + j)) * K3 + h * D_ + c;
                uint2 kk = *(const uint2*)(qkv + roff + C_);
                uint2 vv = *(const uint2*)(qkv + roff + 2 * C_);
                Ks[j][c + 0] = bf2f((u16)(kk.x)); Ks[j][c + 1] = bf2f((u16)(kk.x >> 16));
                Ks[j][c + 2] = bf2f((u16)(kk.y)); Ks[j][c + 3] = bf2f((u16)(kk.y >> 16));
                Vs[j][c + 0] = bf2f((u16)(vv.x)); Vs[j][c + 1] = bf2f((u16)(vv.x >> 16));
                Vs[j][c + 2] = bf2f((u16)(vv.y)); Vs[j][c + 3] = bf2f((u16)(vv.y >> 16));
            }
        }
        __syncthreads();

        if (active) {
            float sc[32];
            float tmax = mcur;
#pragma unroll
            for (int j = 0; j < 32; j++) {
                if (j < jn) {
                    float s0 = 0, s1 = 0, s2 = 0, s3 = 0;
#pragma unroll
                    for (int dd = 0; dd < 64; dd += 4) {
                        float4 kk = *(const float4*)&Ks[j][dd];
                        s0 = fmaf(q[dd],     kk.x, s0);
                        s1 = fmaf(q[dd + 1], kk.y, s1);
                        s2 = fmaf(q[dd + 2], kk.z, s2);
                        s3 = fmaf(q[dd + 3], kk.w, s3);
                    }
                    float s = ((s0 + s1) + (s2 + s3)) * 0.125f;
                    sc[j] = s;
                    tmax = fmaxf(tmax, s);
                }
            }
            float corr = __expf(mcur - tmax);
            l *= corr;
#pragma unroll
            for (int i = 0; i < 64; i++) acc[i] *= corr;
#pragma unroll
            for (int j = 0; j < 32; j++) {
                if (j < jn) {
                    float p = __expf(sc[j] - tmax);
                    l += p;
#pragma unroll
                    for (int dd = 0; dd < 64; dd += 4) {
                        float4 vv = *(const float4*)&Vs[j][dd];
                        acc[dd]     += p * vv.x;
                        acc[dd + 1] += p * vv.y;
                        acc[dd + 2] += p * vv.z;
                        acc[dd + 3] += p * vv.w;
                    }
                }
            }
            mcur = tmax;
        }
        __syncthreads();
    }

    if (active) {
        float invl = 1.f / l;
#pragma unroll
        for (int dd = 0; dd < 64; dd++) q[dd] = elu1(q[dd]);
        float denom = 0.f;
#pragma unroll
        for (int dd = 0; dd < 64; dd++) denom = fmaf(q[dd], z_lds[dd], denom);
        float rden = 1.f / denom;
        u16* orow = concat + ((long long)(b * N_ + NT + qi)) * C_ + h * D_;
#pragma unroll
        for (int e = 0; e < 64; e++) {
            float n0 = 0, n1 = 0, n2 = 0, n3 = 0;
#pragma unroll
            for (int dd = 0; dd < 64; dd += 4) {
                n0 = fmaf(q[dd],     mem_lds[dd * 64 + e],       n0);
                n1 = fmaf(q[dd + 1], mem_lds[(dd + 1) * 64 + e], n1);
                n2 = fmaf(q[dd + 2], mem_lds[(dd + 2) * 64 + e], n2);
                n3 = fmaf(q[dd + 3], mem_lds[(dd + 3) * 64 + e], n3);
            }
            float am = ((n0 + n1) + (n2 + n3)) * rden;
            float bb = beta_lds[e];
            float o = bb * am + (1.f - bb) * (acc[e] * invl);
            orow[e] = f2bf(o);
        }
    }
}

// ---------------------------------------------------------------------------
// sigma_pred: per (b,h), 256 threads. In place on bf16 ws:
//   ksm <- sigma_k = elu(ksm)+1 ; vsm <- v_s_mem - pred. Writes f32 z_new.
// ---------------------------------------------------------------------------
__global__ __launch_bounds__(256) void sigma_pred_kernel(
    u16* __restrict__ ksm, u16* __restrict__ vsm,
    const float* __restrict__ memin, const float* __restrict__ zin,
    float* __restrict__ z_out)
{
    __shared__ float mem_lds[4096];
    __shared__ float z_lds[64];
    __shared__ float zred[4][64];

    int bh = blockIdx.x;
    int b = bh / H_, h = bh % H_;
    int tid = threadIdx.x;
    int wv = tid >> 6, lane = tid & 63;

    for (int idx = tid; idx < 4096; idx += 256)
        mem_lds[idx] = memin[(long long)bh * 4096 + idx];
    if (tid < 64) z_lds[tid] = zin[bh * 64 + tid];
    __syncthreads();

    float zacc = 0.f;
    for (int n = wv; n < NS; n += 4) {
        long long roff = ((long long)(b * NS + n)) * C_ + h * D_;
        float x = bf2f(ksm[roff + lane]);
        float sig = elu1(x);
        ksm[roff + lane] = f2bf(sig);
        zacc += sig;

        float tz = sig * z_lds[lane];
#pragma unroll
        for (int o = 32; o; o >>= 1) tz += __shfl_xor(tz, o);
        float rden = 1.f / tz;

        float num = 0.f;
#pragma unroll
        for (int dd = 0; dd < 64; dd++)
            num = fmaf(__shfl(sig, dd), mem_lds[dd * 64 + lane], num);
        float pred = num * rden;

        float w = bf2f(vsm[roff + lane]) - pred;
        vsm[roff + lane] = f2bf(w);
    }
    zred[wv][lane] = zacc;
    __syncthreads();
    if (wv == 0) {
        float tot = zred[0][lane] + zred[1][lane] + zred[2][lane] + zred[3][lane];
        z_out[bh * 64 + lane] = zin[bh * 64 + lane] + tot;
    }
}

// ---------------------------------------------------------------------------
// mem_update: per (b,h), 256 threads. mem_new (f32) = mem (f32) +
//   sum_n sigma[n][d] * w[n][e]   (sigma/w in bf16 ws)
// ---------------------------------------------------------------------------
__global__ __launch_bounds__(256) void mem_update_kernel(
    const u16* __restrict__ ksm, const u16* __restrict__ vsm,
    const float* __restrict__ memin, float* __restrict__ mem_out)
{
    int bh = blockIdx.x;
    int b = bh / H_, h = bh % H_;
    int t = threadIdx.x;
    int e = t & 63, dg = t >> 6;

    float acc[16];
#pragma unroll
    for (int i = 0; i < 16; i++) acc[i] = 0.f;

    for (int n = 0; n < NS; n++) {
        long long roff = ((long long)(b * NS + n)) * C_ + h * D_;
        float wval = bf2f(vsm[roff + e]);
        uint4 s4a = *(const uint4*)(ksm + roff + dg * 16);
        uint4 s4b = *(const uint4*)(ksm + roff + dg * 16 + 8);
        float sv[16];
        sv[0]  = bf2f((u16)s4a.x); sv[1]  = bf2f((u16)(s4a.x >> 16));
        sv[2]  = bf2f((u16)s4a.y); sv[3]  = bf2f((u16)(s4a.y >> 16));
        sv[4]  = bf2f((u16)s4a.z); sv[5]  = bf2f((u16)(s4a.z >> 16));
        sv[6]  = bf2f((u16)s4a.w); sv[7]  = bf2f((u16)(s4a.w >> 16));
        sv[8]  = bf2f((u16)s4b.x); sv[9]  = bf2f((u16)(s4b.x >> 16));
        sv[10] = bf2f((u16)s4b.y); sv[11] = bf2f((u16)(s4b.y >> 16));
        sv[12] = bf2f((u16)s4b.z); sv[13] = bf2f((u16)(s4b.z >> 16));
        sv[14] = bf2f((u16)s4b.w); sv[15] = bf2f((u16)(s4b.w >> 16));
#pragma unroll
        for (int i = 0; i < 16; i++) acc[i] = fmaf(sv[i], wval, acc[i]);
    }

    long long mbase = (long long)bh * 4096;
#pragma unroll
    for (int i = 0; i < 16; i++) {
        int dd = dg * 16 + i;
        mem_out[mbase + dd * 64 + e] = memin[mbase + dd * 64 + e] + acc[i];
    }
}

// ---------------------------------------------------------------------------
extern "C" void kernel_launch(void* const* d_in, const int* in_sizes, int n_in,
                              void* d_out, int out_size, void* d_ws, size_t ws_size,
                              hipStream_t stream)
{
    const float* x      = (const float*)d_in[0];
    const float* mem    = (const float*)d_in[1];
    const float* z      = (const float*)d_in[2];
    const float* qkv_w  = (const float*)d_in[3];
    const float* qkv_b  = (const float*)d_in[4];
    const float* proj_w = (const float*)d_in[5];
    const float* proj_b = (const float*)d_in[6];
    const float* memk_w = (const float*)d_in[7];
    const float* memk_b = (const float*)d_in[8];
    const float* memv_w = (const float*)d_in[9];
    const float* memv_b = (const float*)d_in[10];
    const float* betas  = (const float*)d_in[11];

    u16* ws     = (u16*)d_ws;
    u16* qkv    = ws;                 // bf16 ws
    u16* ksm    = qkv + QKV_LEN;
    u16* vsm    = ksm + KSM_LEN;
    u16* concat = vsm + KSM_LEN;      // doubles as x_bf before attn writes it

    float* out     = (float*)d_out;
    float* mem_out = out + CAT_LEN;
    float* z_out   = mem_out + MEM_LEN;

    u16* x_bf = concat;   // alias: dead after qkv GEMM, overwritten by attn

    // 0. bf16 conversions
    convert_bf16<<<dim3(2048), dim3(256), 0, stream>>>(x, x_bf, CAT_LEN);
    convert_wbf<<<dim3(864), dim3(256), 0, stream>>>(qkv_w,  WOFF_QKV,  1769472ll);
    convert_wbf<<<dim3(288), dim3(256), 0, stream>>>(memk_w, WOFF_MEMK, 589824ll);
    convert_wbf<<<dim3(288), dim3(256), 0, stream>>>(memv_w, WOFF_MEMV, 589824ll);
    convert_wbf<<<dim3(288), dim3(256), 0, stream>>>(proj_w, WOFF_PROJ, 589824ll);

    // 1. qkv = x @ qkv_w^T + qkv_b           (bf16 -> bf16 ws)
    gemm_mfma<0><<<dim3(K3 / 128, 49664 / 128), dim3(256), 0, stream>>>(
        x_bf, 0ll, 49664, 0ll, 768ll, WOFF_QKV, qkv_b, qkv, K3);
    // 2. k_s_mem = k_f[:, NT:, :] @ memk_w^T
    gemm_mfma<0><<<dim3(C_ / 128, 33280 / 128), dim3(256), 0, stream>>>(
        qkv, (long long)(NT * K3 + C_), NS, (long long)N_ * K3, (long long)K3,
        WOFF_MEMK, memk_b, ksm, C_);
    // 3. v_s_mem = v_f[:, NT:, :] @ memv_w^T
    gemm_mfma<0><<<dim3(C_ / 128, 33280 / 128), dim3(256), 0, stream>>>(
        qkv, (long long)(NT * K3 + 2 * C_), NS, (long long)N_ * K3, (long long)K3,
        WOFF_MEMV, memv_b, vsm, C_);
    // 4. token/token attention -> concat[:, :NT]   (overwrites x_bf region)
    attn_mt_kernel<<<dim3(B_ * H_), dim3(128), 0, stream>>>(qkv, concat);
    // 5. spatial attention + memory readout + beta blend -> concat[:, NT:]
    attn_s_kernel<<<dim3(B_ * H_), dim3(320), 0, stream>>>(qkv, mem, z, betas, concat);
    // 6. sigma_k / pred (in-place) + z_new (f32)
    sigma_pred_kernel<<<dim3(B_ * H_), dim3(256), 0, stream>>>(ksm, vsm, mem, z, z_out);
    // 7. mem_new (f32)
    mem_update_kernel<<<dim3(B_ * H_), dim3(256), 0, stream>>>(ksm, vsm, mem, mem_out);
    // 8. out = concat @ proj_w^T + proj_b    (bf16 -> f32 out)
    gemm_mfma<1><<<dim3(C_ / 128, 49664 / 128), dim3(256), 0, stream>>>(
        concat, 0ll, 49664, 0ll, 768ll, WOFF_PROJ, proj_b, out, C_);
}

// Round 5
// 1405.983 us; speedup vs baseline: 4.9472x; 2.2996x over previous
//
#include <hip/hip_runtime.h>

typedef unsigned short u16;
typedef __attribute__((ext_vector_type(8))) short  vbf8;   // 8 bf16 (4 VGPRs)
typedef __attribute__((ext_vector_type(4))) float  vf4;    // 4 f32 acc

#define B_   128
#define N_   388
#define NT   128
#define NS   260
#define C_   768
#define H_   12
#define D_   64
#define K3   2304   // 3*C

#define QKV_LEN  114425856ll   // 49664*2304  (bf16 ws)
#define KSM_LEN  25559040ll    // 33280*768
#define CAT_LEN  38141952ll    // 49664*768
#define MEM_LEN  6291456ll     // 128*12*64*64 (f32, in d_out)

// bf16 weights: [qkv_w | memk_w | memv_w | proj_w]
#define WOFF_QKV  0ll
#define WOFF_MEMK 1769472ll
#define WOFF_MEMV 2359296ll
#define WOFF_PROJ 2949120ll
__device__ __align__(16) u16 g_wbf[3538944];

__device__ __forceinline__ float bf2f(u16 u) {
    union { unsigned int i; float f; } v; v.i = ((unsigned int)u) << 16; return v.f;
}
__device__ __forceinline__ u16 f2bf(float f) {
    union { float f; unsigned int i; } v; v.f = f;
    unsigned int r = v.i + 0x7fffu + ((v.i >> 16) & 1u);
    return (u16)(r >> 16);
}
__device__ __forceinline__ float elu1(float x) { return x > 0.f ? x + 1.f : __expf(x); }

// ---------------------------------------------------------------------------
// f32 -> bf16 converters
// ---------------------------------------------------------------------------
__global__ __launch_bounds__(256) void convert_bf16(
    const float* __restrict__ src, u16* __restrict__ dst, long long n)
{
    long long i0 = ((long long)blockIdx.x * 256 + threadIdx.x) * 8;
    long long stride = (long long)gridDim.x * 256 * 8;
    for (long long i = i0; i < n; i += stride) {
        float4 a = *(const float4*)(src + i);
        float4 b = *(const float4*)(src + i + 4);
        ushort4 u1; u1.x = f2bf(a.x); u1.y = f2bf(a.y); u1.z = f2bf(a.z); u1.w = f2bf(a.w);
        ushort4 u2; u2.x = f2bf(b.x); u2.y = f2bf(b.y); u2.z = f2bf(b.z); u2.w = f2bf(b.w);
        *(ushort4*)(dst + i)     = u1;
        *(ushort4*)(dst + i + 4) = u2;
    }
}

__global__ __launch_bounds__(256) void convert_wbf(
    const float* __restrict__ src, long long dst_off, long long n)
{
    u16* dst = g_wbf + dst_off;
    long long i0 = ((long long)blockIdx.x * 256 + threadIdx.x) * 8;
    long long stride = (long long)gridDim.x * 256 * 8;
    for (long long i = i0; i < n; i += stride) {
        float4 a = *(const float4*)(src + i);
        float4 b = *(const float4*)(src + i + 4);
        ushort4 u1; u1.x = f2bf(a.x); u1.y = f2bf(a.y); u1.z = f2bf(a.z); u1.w = f2bf(a.w);
        ushort4 u2; u2.x = f2bf(b.x); u2.y = f2bf(b.y); u2.z = f2bf(b.z); u2.w = f2bf(b.w);
        *(ushort4*)(dst + i)     = u1;
        *(ushort4*)(dst + i + 4) = u2;
    }
}

// ---------------------------------------------------------------------------
// memT[bh][dout][din] = bf16(mem[bh][din][dout])  -- per-head transpose
// ---------------------------------------------------------------------------
__global__ __launch_bounds__(256) void memT_kernel(
    const float* __restrict__ memin, u16* __restrict__ memT)
{
    __shared__ float ml[64 * 65];
    int bh = blockIdx.x, t = threadIdx.x;
    const float* src = memin + (long long)bh * 4096;
#pragma unroll
    for (int i = 0; i < 16; i++) {
        int idx = i * 256 + t;                       // din*64+dout
        ml[(idx >> 6) * 65 + (idx & 63)] = src[idx];
    }
    __syncthreads();
    u16* dst = memT + (long long)bh * 4096;
#pragma unroll
    for (int i = 0; i < 16; i++) {
        int o = i * 256 + t;                         // dout*64+din
        int dout = o >> 6, din = o & 63;
        dst[o] = f2bf(ml[din * 65 + dout]);
    }
}

// ---------------------------------------------------------------------------
// MFMA GEMM (unchanged from round 4): C = A @ W^T + bias, K=768.
// ---------------------------------------------------------------------------
template<int CF32>
__global__ __launch_bounds__(256) void gemm_mfma(
    const u16* __restrict__ A, long long off0, int rows_per_b,
    long long stride_b, long long stride_r,
    long long w_off, const float* __restrict__ bias,
    void* __restrict__ Cv, int Nout)
{
    __shared__ __align__(16) u16 lds[2][2][4096];

    const u16* W = g_wbf + w_off;

    int t  = threadIdx.x;
    int m0 = blockIdx.y * 128;
    int n0 = blockIdx.x * 128;

    int r0 = t >> 2;
    int c0 = (t & 3) * 8;
    long long aoff0, aoff1;
    {
        int g1 = m0 + r0, g2 = m0 + r0 + 64;
        int b1 = g1 / rows_per_b, j1 = g1 - b1 * rows_per_b;
        int b2 = g2 / rows_per_b, j2 = g2 - b2 * rows_per_b;
        aoff0 = off0 + (long long)b1 * stride_b + (long long)j1 * stride_r + c0;
        aoff1 = off0 + (long long)b2 * stride_b + (long long)j2 * stride_r + c0;
    }
    const u16* wp0 = W + (long long)(n0 + r0) * 768 + c0;
    const u16* wp1 = W + (long long)(n0 + r0 + 64) * 768 + c0;

    int lane = t & 63;
    int wid  = t >> 6;
    int wm = wid >> 1, wn = wid & 1;
    int lr = lane & 15;
    int kg = lane >> 4;
    int a_rd = (wm * 64 + lr) * 32 + kg * 8;
    int b_rd = (wn * 64 + lr) * 32 + kg * 8;

    vf4 acc[4][4];
#pragma unroll
    for (int i = 0; i < 4; i++)
#pragma unroll
        for (int j = 0; j < 4; j++) acc[i][j] = vf4{0.f, 0.f, 0.f, 0.f};

    {
        vbf8 sa0 = *(const vbf8*)(A + aoff0);
        vbf8 sa1 = *(const vbf8*)(A + aoff1);
        vbf8 sb0 = *(const vbf8*)(wp0);
        vbf8 sb1 = *(const vbf8*)(wp1);
        *(vbf8*)&lds[0][0][t * 8]        = sa0;
        *(vbf8*)&lds[0][0][2048 + t * 8] = sa1;
        *(vbf8*)&lds[0][1][t * 8]        = sb0;
        *(vbf8*)&lds[0][1][2048 + t * 8] = sb1;
    }

    int cur = 0;
    for (int kt = 0; kt < 768; kt += 32) {
        bool last = (kt == 768 - 32);
        vbf8 na0, na1, nb0, nb1;
        if (!last) {
            na0 = *(const vbf8*)(A + aoff0 + kt + 32);
            na1 = *(const vbf8*)(A + aoff1 + kt + 32);
            nb0 = *(const vbf8*)(wp0 + kt + 32);
            nb1 = *(const vbf8*)(wp1 + kt + 32);
        }
        __syncthreads();

        vbf8 af[4], bf[4];
#pragma unroll
        for (int f = 0; f < 4; f++) {
            af[f] = *(const vbf8*)&lds[cur][0][a_rd + f * 512];
            bf[f] = *(const vbf8*)&lds[cur][1][b_rd + f * 512];
        }
#pragma unroll
        for (int i = 0; i < 4; i++)
#pragma unroll
            for (int j = 0; j < 4; j++)
                acc[i][j] = __builtin_amdgcn_mfma_f32_16x16x32_bf16(
                    af[i], bf[j], acc[i][j], 0, 0, 0);

        if (!last) {
            *(vbf8*)&lds[cur ^ 1][0][t * 8]        = na0;
            *(vbf8*)&lds[cur ^ 1][0][2048 + t * 8] = na1;
            *(vbf8*)&lds[cur ^ 1][1][t * 8]        = nb0;
            *(vbf8*)&lds[cur ^ 1][1][2048 + t * 8] = nb1;
            cur ^= 1;
        }
    }

#pragma unroll
    for (int i = 0; i < 4; i++) {
        int row = m0 + wm * 64 + i * 16 + kg * 4;
#pragma unroll
        for (int j = 0; j < 4; j++) {
            int col = n0 + wn * 64 + j * 16 + lr;
            float bb = bias[col];
#pragma unroll
            for (int r = 0; r < 4; r++) {
                float v = acc[i][j][r] + bb;
                long long idx = (long long)(row + r) * Nout + col;
                if (CF32) ((float*)Cv)[idx] = v;
                else      ((u16*)Cv)[idx]  = f2bf(v);
            }
        }
    }
}

// ---------------------------------------------------------------------------
// Unified MFMA flash attention.
// grid = (7, B*H). qb<2: MT part (q rows qb*64.., keys 0..127, plain softmax).
// qb>=2: S part (q rows NT+(qb-2)*64.., keys 0..387, fused mem readout+blend).
// Block: 256 thr = 4 waves; wave w owns 16 q-rows. 32-key tiles.
// Frag conventions (verified by the passing GEMM): A row / B col = lane&15,
// k = (lane>>4)*8+j ; D col = lane&15, row = (lane>>4)*4+reg.
// ---------------------------------------------------------------------------
__global__ __launch_bounds__(256) void attn_mfma_kernel(
    const u16* __restrict__ qkv, const u16* __restrict__ memT,
    const float* __restrict__ zin, const float* __restrict__ betas,
    u16* __restrict__ concat)
{
    __shared__ __align__(16) u16 Kl[32 * 64];   // row-major, slot-XOR swizzled
    __shared__ __align__(16) u16 Vt[64 * 40];   // transposed, stride-40 pad
    __shared__ __align__(16) u16 Pl[4][16 * 40];// per-wave P, stride-40 pad
    __shared__ float red[4][16];

    int qb = blockIdx.x;
    int bh = blockIdx.y;
    int b = bh / H_, h = bh % H_;
    int t = threadIdx.x, lane = t & 63, w = t >> 6;
    int lr = lane & 15, q4 = lane >> 4;

    bool mt = qb < 2;
    int q0_tok = mt ? qb * 64 : NT + (qb - 2) * 64;
    int nkeys  = mt ? NT : N_;
    int ntiles = (nkeys + 31) >> 5;

    // Q fragments (A-layout: row = lr, k = q4*8+j)
    int qrow_tok = q0_tok + w * 16 + lr;
    if (qrow_tok > N_ - 1) qrow_tok = N_ - 1;
    const u16* qbase = qkv + ((long long)(b * N_ + qrow_tok)) * K3 + h * D_;
    vbf8 qf0 = *(const vbf8*)(qbase + q4 * 8);
    vbf8 qf1 = *(const vbf8*)(qbase + 32 + q4 * 8);

    // staging assignments
    int sk_k = t >> 3, sd_k = (t & 7) * 8;      // K: global-coalesced
    int sk_v = t & 31, sd_v = (t >> 5) * 8;     // V: LDS-bank-friendly transpose

    float m[4], l[4];
    vf4 accO[4];
#pragma unroll
    for (int r = 0; r < 4; r++) { m[r] = -1e30f; l[r] = 0.f; }
#pragma unroll
    for (int dc = 0; dc < 4; dc++) accO[dc] = vf4{0.f, 0.f, 0.f, 0.f};

    for (int kt = 0; kt < ntiles; kt++) {
        int kbase = kt * 32;
        int kvalid = nkeys - kbase; if (kvalid > 32) kvalid = 32;

        // ---- stage K (swizzled) + V (transposed)
        {
            int gk = kbase + sk_k;
            vbf8 kv;
#pragma unroll
            for (int u = 0; u < 8; u++) ((short*)&kv)[u] = 0;
            if (gk < nkeys)
                kv = *(const vbf8*)(qkv + ((long long)(b * N_ + gk)) * K3 + C_ + h * D_ + sd_k);
            *(vbf8*)((char*)Kl + ((sk_k * 128 + sd_k * 2) ^ ((sk_k & 7) << 4))) = kv;

            int gv = kbase + sk_v;
            vbf8 vv;
#pragma unroll
            for (int u = 0; u < 8; u++) ((short*)&vv)[u] = 0;
            if (gv < nkeys)
                vv = *(const vbf8*)(qkv + ((long long)(b * N_ + gv)) * K3 + 2 * C_ + h * D_ + sd_v);
#pragma unroll
            for (int u = 0; u < 8; u++) Vt[(sd_v + u) * 40 + sk_v] = ((u16*)&vv)[u];
        }
        __syncthreads();

        // ---- S = (Q K^T) * scale, masked
        vf4 S[2];
#pragma unroll
        for (int ks = 0; ks < 2; ks++) {
            int krow = ks * 16 + lr;
            int swz = (krow & 7) << 4;
            vbf8 b0 = *(const vbf8*)((char*)Kl + ((krow * 128 + q4 * 16) ^ swz));
            vbf8 b1 = *(const vbf8*)((char*)Kl + ((krow * 128 + 64 + q4 * 16) ^ swz));
            vf4 z4 = vf4{0.f, 0.f, 0.f, 0.f};
            vf4 s = __builtin_amdgcn_mfma_f32_16x16x32_bf16(qf0, b0, z4, 0, 0, 0);
            s = __builtin_amdgcn_mfma_f32_16x16x32_bf16(qf1, b1, s, 0, 0, 0);
            bool inv = (ks * 16 + lr) >= kvalid;
#pragma unroll
            for (int r = 0; r < 4; r++)
                S[ks][r] = inv ? -1e30f : s[r] * 0.125f;
        }

        // ---- online softmax (row = q4*4+r, reduce over 16 key-lanes)
        float tm[4], ts[4], corr[4];
#pragma unroll
        for (int r = 0; r < 4; r++) tm[r] = fmaxf(S[0][r], S[1][r]);
#pragma unroll
        for (int off = 1; off <= 8; off <<= 1)
#pragma unroll
            for (int r = 0; r < 4; r++) tm[r] = fmaxf(tm[r], __shfl_xor(tm[r], off));
#pragma unroll
        for (int r = 0; r < 4; r++) {
            float nm = fmaxf(m[r], tm[r]);
            corr[r] = __expf(m[r] - nm);
            m[r] = nm;
        }
#pragma unroll
        for (int ks = 0; ks < 2; ks++)
#pragma unroll
            for (int r = 0; r < 4; r++) S[ks][r] = __expf(S[ks][r] - m[r]);
#pragma unroll
        for (int r = 0; r < 4; r++) ts[r] = S[0][r] + S[1][r];
#pragma unroll
        for (int off = 1; off <= 8; off <<= 1)
#pragma unroll
            for (int r = 0; r < 4; r++) ts[r] += __shfl_xor(ts[r], off);
#pragma unroll
        for (int r = 0; r < 4; r++) l[r] = l[r] * corr[r] + ts[r];
#pragma unroll
        for (int dc = 0; dc < 4; dc++)
#pragma unroll
            for (int r = 0; r < 4; r++) accO[dc][r] *= corr[r];

        // ---- P: D-layout -> LDS -> A-layout (wave-private, no barrier)
        {
            u16* pw = Pl[w];
#pragma unroll
            for (int ks = 0; ks < 2; ks++)
#pragma unroll
                for (int r = 0; r < 4; r++)
                    pw[(q4 * 4 + r) * 40 + ks * 16 + lr] = f2bf(S[ks][r]);
        }
        vbf8 pf = *(const vbf8*)&Pl[w][lr * 40 + q4 * 8];

        // ---- PV
#pragma unroll
        for (int dc = 0; dc < 4; dc++) {
            vbf8 vf = *(const vbf8*)&Vt[(dc * 16 + lr) * 40 + q4 * 8];
            accO[dc] = __builtin_amdgcn_mfma_f32_16x16x32_bf16(pf, vf, accO[dc], 0, 0, 0);
        }
        __syncthreads();
    }

    float invl[4];
#pragma unroll
    for (int r = 0; r < 4; r++) invl[r] = 1.f / l[r];

    if (mt) {
        int qtok = q0_tok + w * 16;
#pragma unroll
        for (int dc = 0; dc < 4; dc++)
#pragma unroll
            for (int r = 0; r < 4; r++) {
                int row = qtok + q4 * 4 + r;
                concat[((long long)(b * N_ + row)) * C_ + h * D_ + dc * 16 + lr] =
                    f2bf(accO[dc][r] * invl[r]);
            }
    } else {
        // sigma_q frags (A-layout, elementwise elu on Q) + denom = sigma_q . z
        const float* zp = zin + bh * 64;
        vbf8 sq0, sq1;
        float dpart = 0.f;
#pragma unroll
        for (int j = 0; j < 8; j++) {
            float s0 = elu1(bf2f(((u16*)&qf0)[j]));
            float s1 = elu1(bf2f(((u16*)&qf1)[j]));
            ((u16*)&sq0)[j] = f2bf(s0);
            ((u16*)&sq1)[j] = f2bf(s1);
            dpart += s0 * zp[q4 * 8 + j] + s1 * zp[32 + q4 * 8 + j];
        }
        dpart += __shfl_xor(dpart, 16);
        dpart += __shfl_xor(dpart, 32);
        if (q4 == 0) red[w][lr] = dpart;   // wave-local redistribute

        // att_mem numerator = sigma_q @ mem  (memT rows are dout)
        const u16* mtb = memT + (long long)bh * 4096;
        vf4 am[4];
#pragma unroll
        for (int dc = 0; dc < 4; dc++) {
            vbf8 b0 = *(const vbf8*)(mtb + (dc * 16 + lr) * 64 + q4 * 8);
            vbf8 b1 = *(const vbf8*)(mtb + (dc * 16 + lr) * 64 + 32 + q4 * 8);
            vf4 z4 = vf4{0.f, 0.f, 0.f, 0.f};
            vf4 a = __builtin_amdgcn_mfma_f32_16x16x32_bf16(sq0, b0, z4, 0, 0, 0);
            am[dc] = __builtin_amdgcn_mfma_f32_16x16x32_bf16(sq1, b1, a, 0, 0, 0);
        }
        float den[4];
#pragma unroll
        for (int r = 0; r < 4; r++) den[r] = 1.f / red[w][q4 * 4 + r];

        int qs0 = (qb - 2) * 64 + w * 16;
#pragma unroll
        for (int dc = 0; dc < 4; dc++) {
            float bb = betas[h * D_ + dc * 16 + lr];
            float beta = 1.f / (1.f + __expf(-bb));
#pragma unroll
            for (int r = 0; r < 4; r++) {
                int qs = qs0 + q4 * 4 + r;
                if (qs < NS) {
                    float o = beta * (am[dc][r] * den[r]) +
                              (1.f - beta) * (accO[dc][r] * invl[r]);
                    concat[((long long)(b * N_ + NT + qs)) * C_ + h * D_ + dc * 16 + lr] = f2bf(o);
                }
            }
        }
    }
}

// ---------------------------------------------------------------------------
// sigma_pred (unchanged): ksm <- elu(ksm)+1 ; vsm <- vsm - pred ; z_new.
// ---------------------------------------------------------------------------
__global__ __launch_bounds__(256) void sigma_pred_kernel(
    u16* __restrict__ ksm, u16* __restrict__ vsm,
    const float* __restrict__ memin, const float* __restrict__ zin,
    float* __restrict__ z_out)
{
    __shared__ float mem_lds[4096];
    __shared__ float z_lds[64];
    __shared__ float zred[4][64];

    int bh = blockIdx.x;
    int b = bh / H_, h = bh % H_;
    int tid = threadIdx.x;
    int wv = tid >> 6, lane = tid & 63;

    for (int idx = tid; idx < 4096; idx += 256)
        mem_lds[idx] = memin[(long long)bh * 4096 + idx];
    if (tid < 64) z_lds[tid] = zin[bh * 64 + tid];
    __syncthreads();

    float zacc = 0.f;
    for (int n = wv; n < NS; n += 4) {
        long long roff = ((long long)(b * NS + n)) * C_ + h * D_;
        float x = bf2f(ksm[roff + lane]);
        float sig = elu1(x);
        ksm[roff + lane] = f2bf(sig);
        zacc += sig;

        float tz = sig * z_lds[lane];
#pragma unroll
        for (int o = 32; o; o >>= 1) tz += __shfl_xor(tz, o);
        float rden = 1.f / tz;

        float num = 0.f;
#pragma unroll
        for (int dd = 0; dd < 64; dd++)
            num = fmaf(__shfl(sig, dd), mem_lds[dd * 64 + lane], num);
        float pred = num * rden;

        float w = bf2f(vsm[roff + lane]) - pred;
        vsm[roff + lane] = f2bf(w);
    }
    zred[wv][lane] = zacc;
    __syncthreads();
    if (wv == 0) {
        float tot = zred[0][lane] + zred[1][lane] + zred[2][lane] + zred[3][lane];
        z_out[bh * 64 + lane] = zin[bh * 64 + lane] + tot;
    }
}

// ---------------------------------------------------------------------------
// mem_update (unchanged)
// ---------------------------------------------------------------------------
__global__ __launch_bounds__(256) void mem_update_kernel(
    const u16* __restrict__ ksm, const u16* __restrict__ vsm,
    const float* __restrict__ memin, float* __restrict__ mem_out)
{
    int bh = blockIdx.x;
    int b = bh / H_, h = bh % H_;
    int t = threadIdx.x;
    int e = t & 63, dg = t >> 6;

    float acc[16];
#pragma unroll
    for (int i = 0; i < 16; i++) acc[i] = 0.f;

    for (int n = 0; n < NS; n++) {
        long long roff = ((long long)(b * NS + n)) * C_ + h * D_;
        float wval = bf2f(vsm[roff + e]);
        uint4 s4a = *(const uint4*)(ksm + roff + dg * 16);
        uint4 s4b = *(const uint4*)(ksm + roff + dg * 16 + 8);
        float sv[16];
        sv[0]  = bf2f((u16)s4a.x); sv[1]  = bf2f((u16)(s4a.x >> 16));
        sv[2]  = bf2f((u16)s4a.y); sv[3]  = bf2f((u16)(s4a.y >> 16));
        sv[4]  = bf2f((u16)s4a.z); sv[5]  = bf2f((u16)(s4a.z >> 16));
        sv[6]  = bf2f((u16)s4a.w); sv[7]  = bf2f((u16)(s4a.w >> 16));
        sv[8]  = bf2f((u16)s4b.x); sv[9]  = bf2f((u16)(s4b.x >> 16));
        sv[10] = bf2f((u16)s4b.y); sv[11] = bf2f((u16)(s4b.y >> 16));
        sv[12] = bf2f((u16)s4b.z); sv[13] = bf2f((u16)(s4b.z >> 16));
        sv[14] = bf2f((u16)s4b.w); sv[15] = bf2f((u16)(s4b.w >> 16));
#pragma unroll
        for (int i = 0; i < 16; i++) acc[i] = fmaf(sv[i], wval, acc[i]);
    }

    long long mbase = (long long)bh * 4096;
#pragma unroll
    for (int i = 0; i < 16; i++) {
        int dd = dg * 16 + i;
        mem_out[mbase + dd * 64 + e] = memin[mbase + dd * 64 + e] + acc[i];
    }
}

// ---------------------------------------------------------------------------
extern "C" void kernel_launch(void* const* d_in, const int* in_sizes, int n_in,
                              void* d_out, int out_size, void* d_ws, size_t ws_size,
                              hipStream_t stream)
{
    const float* x      = (const float*)d_in[0];
    const float* mem    = (const float*)d_in[1];
    const float* z      = (const float*)d_in[2];
    const float* qkv_w  = (const float*)d_in[3];
    const float* qkv_b  = (const float*)d_in[4];
    const float* proj_w = (const float*)d_in[5];
    const float* proj_b = (const float*)d_in[6];
    const float* memk_w = (const float*)d_in[7];
    const float* memk_b = (const float*)d_in[8];
    const float* memv_w = (const float*)d_in[9];
    const float* memv_b = (const float*)d_in[10];
    const float* betas  = (const float*)d_in[11];

    u16* ws     = (u16*)d_ws;
    u16* qkv    = ws;
    u16* ksm    = qkv + QKV_LEN;
    u16* vsm    = ksm + KSM_LEN;
    u16* concat = vsm + KSM_LEN;      // doubles as x_bf before attn writes it

    float* out     = (float*)d_out;
    float* mem_out = out + CAT_LEN;
    float* z_out   = mem_out + MEM_LEN;

    u16* x_bf = concat;               // alias: dead after qkv GEMM
    u16* memT = (u16*)mem_out;        // 12.6MB scratch inside 25MB region;
                                      // overwritten later by mem_update

    // 0. conversions
    convert_bf16<<<dim3(2048), dim3(256), 0, stream>>>(x, x_bf, CAT_LEN);
    convert_wbf<<<dim3(864), dim3(256), 0, stream>>>(qkv_w,  WOFF_QKV,  1769472ll);
    convert_wbf<<<dim3(288), dim3(256), 0, stream>>>(memk_w, WOFF_MEMK, 589824ll);
    convert_wbf<<<dim3(288), dim3(256), 0, stream>>>(memv_w, WOFF_MEMV, 589824ll);
    convert_wbf<<<dim3(288), dim3(256), 0, stream>>>(proj_w, WOFF_PROJ, 589824ll);
    memT_kernel<<<dim3(B_ * H_), dim3(256), 0, stream>>>(mem, memT);

    // 1. qkv = x @ qkv_w^T + qkv_b
    gemm_mfma<0><<<dim3(K3 / 128, 49664 / 128), dim3(256), 0, stream>>>(
        x_bf, 0ll, 49664, 0ll, 768ll, WOFF_QKV, qkv_b, qkv, K3);
    // 2. k_s_mem
    gemm_mfma<0><<<dim3(C_ / 128, 33280 / 128), dim3(256), 0, stream>>>(
        qkv, (long long)(NT * K3 + C_), NS, (long long)N_ * K3, (long long)K3,
        WOFF_MEMK, memk_b, ksm, C_);
    // 3. v_s_mem
    gemm_mfma<0><<<dim3(C_ / 128, 33280 / 128), dim3(256), 0, stream>>>(
        qkv, (long long)(NT * K3 + 2 * C_), NS, (long long)N_ * K3, (long long)K3,
        WOFF_MEMV, memv_b, vsm, C_);
    // 4+5. both attentions (MT + S incl. memory readout/blend) -> concat
    attn_mfma_kernel<<<dim3(7, B_ * H_), dim3(256), 0, stream>>>(
        qkv, memT, z, betas, concat);
    // 6. sigma_k / pred + z_new
    sigma_pred_kernel<<<dim3(B_ * H_), dim3(256), 0, stream>>>(ksm, vsm, mem, z, z_out);
    // 7. mem_new (overwrites memT scratch)
    mem_update_kernel<<<dim3(B_ * H_), dim3(256), 0, stream>>>(ksm, vsm, mem, mem_out);
    // 8. out = concat @ proj_w^T + proj_b
    gemm_mfma<1><<<dim3(C_ / 128, 49664 / 128), dim3(256), 0, stream>>>(
        concat, 0ll, 49664, 0ll, 768ll, WOFF_PROJ, proj_b, out, C_);
}

// Round 6
// 1356.659 us; speedup vs baseline: 5.1271x; 1.0364x over previous
//
#include <hip/hip_runtime.h>

typedef unsigned short u16;
typedef __attribute__((ext_vector_type(8))) short  vbf8;   // 8 bf16 (4 VGPRs)
typedef __attribute__((ext_vector_type(4))) float  vf4;    // 4 f32 acc

#define B_   128
#define N_   388
#define NT   128
#define NS   260
#define C_   768
#define H_   12
#define D_   64
#define K3   2304   // 3*C

#define QKV_LEN  114425856ll   // 49664*2304  (bf16 ws)
#define KSM_LEN  25559040ll    // 33280*768
#define CAT_LEN  38141952ll    // 49664*768
#define MEM_LEN  6291456ll     // 128*12*64*64 (f32, in d_out)

// bf16 weights: [qkv_w | memk_w | memv_w | proj_w]
#define WOFF_QKV  0ll
#define WOFF_MEMK 1769472ll
#define WOFF_MEMV 2359296ll
#define WOFF_PROJ 2949120ll
__device__ __align__(16) u16 g_wbf[3538944];

__device__ __forceinline__ float bf2f(u16 u) {
    union { unsigned int i; float f; } v; v.i = ((unsigned int)u) << 16; return v.f;
}
__device__ __forceinline__ u16 f2bf(float f) {
    union { float f; unsigned int i; } v; v.f = f;
    unsigned int r = v.i + 0x7fffu + ((v.i >> 16) & 1u);
    return (u16)(r >> 16);
}
__device__ __forceinline__ float elu1(float x) { return x > 0.f ? x + 1.f : __expf(x); }

// ---------------------------------------------------------------------------
// f32 -> bf16 converters
// ---------------------------------------------------------------------------
__global__ __launch_bounds__(256) void convert_bf16(
    const float* __restrict__ src, u16* __restrict__ dst, long long n)
{
    long long i0 = ((long long)blockIdx.x * 256 + threadIdx.x) * 8;
    long long stride = (long long)gridDim.x * 256 * 8;
    for (long long i = i0; i < n; i += stride) {
        float4 a = *(const float4*)(src + i);
        float4 b = *(const float4*)(src + i + 4);
        ushort4 u1; u1.x = f2bf(a.x); u1.y = f2bf(a.y); u1.z = f2bf(a.z); u1.w = f2bf(a.w);
        ushort4 u2; u2.x = f2bf(b.x); u2.y = f2bf(b.y); u2.z = f2bf(b.z); u2.w = f2bf(b.w);
        *(ushort4*)(dst + i)     = u1;
        *(ushort4*)(dst + i + 4) = u2;
    }
}

__global__ __launch_bounds__(256) void convert_wbf(
    const float* __restrict__ src, long long dst_off, long long n)
{
    u16* dst = g_wbf + dst_off;
    long long i0 = ((long long)blockIdx.x * 256 + threadIdx.x) * 8;
    long long stride = (long long)gridDim.x * 256 * 8;
    for (long long i = i0; i < n; i += stride) {
        float4 a = *(const float4*)(src + i);
        float4 b = *(const float4*)(src + i + 4);
        ushort4 u1; u1.x = f2bf(a.x); u1.y = f2bf(a.y); u1.z = f2bf(a.z); u1.w = f2bf(a.w);
        ushort4 u2; u2.x = f2bf(b.x); u2.y = f2bf(b.y); u2.z = f2bf(b.z); u2.w = f2bf(b.w);
        *(ushort4*)(dst + i)     = u1;
        *(ushort4*)(dst + i + 4) = u2;
    }
}

// ---------------------------------------------------------------------------
// memT[bh][dout][din] = bf16(mem[bh][din][dout])
// ---------------------------------------------------------------------------
__global__ __launch_bounds__(256) void memT_kernel(
    const float* __restrict__ memin, u16* __restrict__ memT)
{
    __shared__ float ml[64 * 65];
    int bh = blockIdx.x, t = threadIdx.x;
    const float* src = memin + (long long)bh * 4096;
#pragma unroll
    for (int i = 0; i < 16; i++) {
        int idx = i * 256 + t;
        ml[(idx >> 6) * 65 + (idx & 63)] = src[idx];
    }
    __syncthreads();
    u16* dst = memT + (long long)bh * 4096;
#pragma unroll
    for (int i = 0; i < 16; i++) {
        int o = i * 256 + t;
        int dout = o >> 6, din = o & 63;
        dst[o] = f2bf(ml[din * 65 + dout]);
    }
}

// ---------------------------------------------------------------------------
// MFMA GEMM (unchanged): C = A @ W^T + bias, K=768.
// ---------------------------------------------------------------------------
template<int CF32>
__global__ __launch_bounds__(256) void gemm_mfma(
    const u16* __restrict__ A, long long off0, int rows_per_b,
    long long stride_b, long long stride_r,
    long long w_off, const float* __restrict__ bias,
    void* __restrict__ Cv, int Nout)
{
    __shared__ __align__(16) u16 lds[2][2][4096];

    const u16* W = g_wbf + w_off;

    int t  = threadIdx.x;
    int m0 = blockIdx.y * 128;
    int n0 = blockIdx.x * 128;

    int r0 = t >> 2;
    int c0 = (t & 3) * 8;
    long long aoff0, aoff1;
    {
        int g1 = m0 + r0, g2 = m0 + r0 + 64;
        int b1 = g1 / rows_per_b, j1 = g1 - b1 * rows_per_b;
        int b2 = g2 / rows_per_b, j2 = g2 - b2 * rows_per_b;
        aoff0 = off0 + (long long)b1 * stride_b + (long long)j1 * stride_r + c0;
        aoff1 = off0 + (long long)b2 * stride_b + (long long)j2 * stride_r + c0;
    }
    const u16* wp0 = W + (long long)(n0 + r0) * 768 + c0;
    const u16* wp1 = W + (long long)(n0 + r0 + 64) * 768 + c0;

    int lane = t & 63;
    int wid  = t >> 6;
    int wm = wid >> 1, wn = wid & 1;
    int lr = lane & 15;
    int kg = lane >> 4;
    int a_rd = (wm * 64 + lr) * 32 + kg * 8;
    int b_rd = (wn * 64 + lr) * 32 + kg * 8;

    vf4 acc[4][4];
#pragma unroll
    for (int i = 0; i < 4; i++)
#pragma unroll
        for (int j = 0; j < 4; j++) acc[i][j] = vf4{0.f, 0.f, 0.f, 0.f};

    {
        vbf8 sa0 = *(const vbf8*)(A + aoff0);
        vbf8 sa1 = *(const vbf8*)(A + aoff1);
        vbf8 sb0 = *(const vbf8*)(wp0);
        vbf8 sb1 = *(const vbf8*)(wp1);
        *(vbf8*)&lds[0][0][t * 8]        = sa0;
        *(vbf8*)&lds[0][0][2048 + t * 8] = sa1;
        *(vbf8*)&lds[0][1][t * 8]        = sb0;
        *(vbf8*)&lds[0][1][2048 + t * 8] = sb1;
    }

    int cur = 0;
    for (int kt = 0; kt < 768; kt += 32) {
        bool last = (kt == 768 - 32);
        vbf8 na0, na1, nb0, nb1;
        if (!last) {
            na0 = *(const vbf8*)(A + aoff0 + kt + 32);
            na1 = *(const vbf8*)(A + aoff1 + kt + 32);
            nb0 = *(const vbf8*)(wp0 + kt + 32);
            nb1 = *(const vbf8*)(wp1 + kt + 32);
        }
        __syncthreads();

        vbf8 af[4], bf[4];
#pragma unroll
        for (int f = 0; f < 4; f++) {
            af[f] = *(const vbf8*)&lds[cur][0][a_rd + f * 512];
            bf[f] = *(const vbf8*)&lds[cur][1][b_rd + f * 512];
        }
#pragma unroll
        for (int i = 0; i < 4; i++)
#pragma unroll
            for (int j = 0; j < 4; j++)
                acc[i][j] = __builtin_amdgcn_mfma_f32_16x16x32_bf16(
                    af[i], bf[j], acc[i][j], 0, 0, 0);

        if (!last) {
            *(vbf8*)&lds[cur ^ 1][0][t * 8]        = na0;
            *(vbf8*)&lds[cur ^ 1][0][2048 + t * 8] = na1;
            *(vbf8*)&lds[cur ^ 1][1][t * 8]        = nb0;
            *(vbf8*)&lds[cur ^ 1][1][2048 + t * 8] = nb1;
            cur ^= 1;
        }
    }

#pragma unroll
    for (int i = 0; i < 4; i++) {
        int row = m0 + wm * 64 + i * 16 + kg * 4;
#pragma unroll
        for (int j = 0; j < 4; j++) {
            int col = n0 + wn * 64 + j * 16 + lr;
            float bb = bias[col];
#pragma unroll
            for (int r = 0; r < 4; r++) {
                float v = acc[i][j][r] + bb;
                long long idx = (long long)(row + r) * Nout + col;
                if (CF32) ((float*)Cv)[idx] = v;
                else      ((u16*)Cv)[idx]  = f2bf(v);
            }
        }
    }
}

// ---------------------------------------------------------------------------
// attn_s_mfma: one block per (b,h), 512 thr (8 waves). Stage all 388 K/V in
// LDS ONCE; each wave independently sweeps 16-q-row strips (17 strips) over
// 13 key-tiles with NO further barriers. Fused mem readout + beta blend.
// Frag conventions as the verified GEMM: A row / B col = lane&15,
// k = (lane>>4)*8+j ; D col = lane&15, row = (lane>>4)*4+reg.
// ---------------------------------------------------------------------------
#define SKP 416    // keys padded to 13*32
#define VTS 424    // Vt row stride (u16): 212 dwords ; 212%32=20 -> 2-way reads
__global__ __launch_bounds__(512) void attn_s_mfma(
    const u16* __restrict__ qkv, const u16* __restrict__ memT,
    const float* __restrict__ zin, const float* __restrict__ betas,
    u16* __restrict__ concat)
{
    __shared__ __align__(16) u16 Kl[SKP * 64];     // 53248 B, swizzled rows
    __shared__ __align__(16) u16 Vt[64 * VTS];     // 54272 B, [d][key]
    __shared__ __align__(16) u16 Pl[8][16 * 40];   // 10240 B
    __shared__ float red[8][16];

    int bh = blockIdx.x;
    int b = bh / H_, h = bh % H_;
    int t = threadIdx.x, lane = t & 63, w = t >> 6;
    int lr = lane & 15, q4 = lane >> 4;

    // ---- stage all K (swizzled) + V (transposed); zero pad keys >= 388
    {
        int key0 = t >> 3;
        int d0 = (t & 7) * 8;
        for (int kp = 0; kp < SKP; kp += 64) {
            int key = kp + key0;
            if (key < SKP) {
                vbf8 kv, vv;
#pragma unroll
                for (int u = 0; u < 8; u++) { ((short*)&kv)[u] = 0; ((short*)&vv)[u] = 0; }
                if (key < N_) {
                    const u16* base = qkv + ((long long)(b * N_ + key)) * K3 + h * D_;
                    kv = *(const vbf8*)(base + C_ + d0);
                    vv = *(const vbf8*)(base + 2 * C_ + d0);
                }
                *(vbf8*)((char*)Kl + ((key * 128 + d0 * 2) ^ ((key & 7) << 4))) = kv;
#pragma unroll
                for (int u = 0; u < 8; u++) Vt[(d0 + u) * VTS + key] = ((u16*)&vv)[u];
            }
        }
    }
    __syncthreads();

    const float* zp = zin + bh * 64;
    const u16* mtb = memT + (long long)bh * 4096;

    for (int s = w; s < 17; s += 8) {
        int qtok = NT + s * 16 + lr;
        if (qtok > N_ - 1) qtok = N_ - 1;
        const u16* qbase = qkv + ((long long)(b * N_ + qtok)) * K3 + h * D_;
        vbf8 qf0 = *(const vbf8*)(qbase + q4 * 8);
        vbf8 qf1 = *(const vbf8*)(qbase + 32 + q4 * 8);

        float m[4], l[4];
        vf4 accO[4];
#pragma unroll
        for (int r = 0; r < 4; r++) { m[r] = -1e30f; l[r] = 0.f; }
#pragma unroll
        for (int dc = 0; dc < 4; dc++) accO[dc] = vf4{0.f, 0.f, 0.f, 0.f};

        for (int kt = 0; kt < 13; kt++) {
            int kvalid = N_ - kt * 32; if (kvalid > 32) kvalid = 32;

            vf4 S[2];
#pragma unroll
            for (int ks = 0; ks < 2; ks++) {
                int krow = kt * 32 + ks * 16 + lr;
                int swz = (krow & 7) << 4;
                vbf8 b0 = *(const vbf8*)((char*)Kl + ((krow * 128 + q4 * 16) ^ swz));
                vbf8 b1 = *(const vbf8*)((char*)Kl + ((krow * 128 + 64 + q4 * 16) ^ swz));
                vf4 z4 = vf4{0.f, 0.f, 0.f, 0.f};
                vf4 sv = __builtin_amdgcn_mfma_f32_16x16x32_bf16(qf0, b0, z4, 0, 0, 0);
                sv = __builtin_amdgcn_mfma_f32_16x16x32_bf16(qf1, b1, sv, 0, 0, 0);
                bool inv = (ks * 16 + lr) >= kvalid;
#pragma unroll
                for (int r = 0; r < 4; r++)
                    S[ks][r] = inv ? -1e30f : sv[r] * 0.125f;
            }

            float tm[4], ts[4], corr[4];
#pragma unroll
            for (int r = 0; r < 4; r++) tm[r] = fmaxf(S[0][r], S[1][r]);
#pragma unroll
            for (int off = 1; off <= 8; off <<= 1)
#pragma unroll
                for (int r = 0; r < 4; r++) tm[r] = fmaxf(tm[r], __shfl_xor(tm[r], off));
#pragma unroll
            for (int r = 0; r < 4; r++) {
                float nm = fmaxf(m[r], tm[r]);
                corr[r] = __expf(m[r] - nm);
                m[r] = nm;
            }
#pragma unroll
            for (int ks = 0; ks < 2; ks++)
#pragma unroll
                for (int r = 0; r < 4; r++) S[ks][r] = __expf(S[ks][r] - m[r]);
#pragma unroll
            for (int r = 0; r < 4; r++) ts[r] = S[0][r] + S[1][r];
#pragma unroll
            for (int off = 1; off <= 8; off <<= 1)
#pragma unroll
                for (int r = 0; r < 4; r++) ts[r] += __shfl_xor(ts[r], off);
#pragma unroll
            for (int r = 0; r < 4; r++) l[r] = l[r] * corr[r] + ts[r];
#pragma unroll
            for (int dc = 0; dc < 4; dc++)
#pragma unroll
                for (int r = 0; r < 4; r++) accO[dc][r] *= corr[r];

            {
                u16* pw = Pl[w];
#pragma unroll
                for (int ks = 0; ks < 2; ks++)
#pragma unroll
                    for (int r = 0; r < 4; r++)
                        pw[(q4 * 4 + r) * 40 + ks * 16 + lr] = f2bf(S[ks][r]);
            }
            vbf8 pf = *(const vbf8*)&Pl[w][lr * 40 + q4 * 8];

#pragma unroll
            for (int dc = 0; dc < 4; dc++) {
                vbf8 vf_ = *(const vbf8*)&Vt[(dc * 16 + lr) * VTS + kt * 32 + q4 * 8];
                accO[dc] = __builtin_amdgcn_mfma_f32_16x16x32_bf16(pf, vf_, accO[dc], 0, 0, 0);
            }
        }

        float invl[4];
#pragma unroll
        for (int r = 0; r < 4; r++) invl[r] = 1.f / l[r];

        // sigma_q + denom
        vbf8 sq0, sq1;
        float dpart = 0.f;
#pragma unroll
        for (int j = 0; j < 8; j++) {
            float s0 = elu1(bf2f(((u16*)&qf0)[j]));
            float s1 = elu1(bf2f(((u16*)&qf1)[j]));
            ((u16*)&sq0)[j] = f2bf(s0);
            ((u16*)&sq1)[j] = f2bf(s1);
            dpart += s0 * zp[q4 * 8 + j] + s1 * zp[32 + q4 * 8 + j];
        }
        dpart += __shfl_xor(dpart, 16);
        dpart += __shfl_xor(dpart, 32);
        if (q4 == 0) red[w][lr] = dpart;

        vf4 am[4];
#pragma unroll
        for (int dc = 0; dc < 4; dc++) {
            vbf8 b0 = *(const vbf8*)(mtb + (dc * 16 + lr) * 64 + q4 * 8);
            vbf8 b1 = *(const vbf8*)(mtb + (dc * 16 + lr) * 64 + 32 + q4 * 8);
            vf4 z4 = vf4{0.f, 0.f, 0.f, 0.f};
            vf4 a = __builtin_amdgcn_mfma_f32_16x16x32_bf16(sq0, b0, z4, 0, 0, 0);
            am[dc] = __builtin_amdgcn_mfma_f32_16x16x32_bf16(sq1, b1, a, 0, 0, 0);
        }
        float den[4];
#pragma unroll
        for (int r = 0; r < 4; r++) den[r] = 1.f / red[w][q4 * 4 + r];

#pragma unroll
        for (int dc = 0; dc < 4; dc++) {
            float bb = betas[h * D_ + dc * 16 + lr];
            float beta = 1.f / (1.f + __expf(-bb));
#pragma unroll
            for (int r = 0; r < 4; r++) {
                int qs = s * 16 + q4 * 4 + r;
                if (qs < NS) {
                    float o = beta * (am[dc][r] * den[r]) +
                              (1.f - beta) * (accO[dc][r] * invl[r]);
                    concat[((long long)(b * N_ + NT + qs)) * C_ + h * D_ + dc * 16 + lr] = f2bf(o);
                }
            }
        }
    }
}

// ---------------------------------------------------------------------------
// attn_mt_mfma: one block per (b,h), 512 thr (8 waves). Stage 128 K/V once;
// wave w handles q rows w*16..w*16+15 over 4 key-tiles. Plain flash softmax.
// ---------------------------------------------------------------------------
#define MTS 136    // Vt stride: 68 dwords ; 68%32=4 -> 2-way reads
__global__ __launch_bounds__(512) void attn_mt_mfma(
    const u16* __restrict__ qkv, u16* __restrict__ concat)
{
    __shared__ __align__(16) u16 Kl[NT * 64];      // 16384 B, swizzled
    __shared__ __align__(16) u16 Vt[64 * MTS];     // 17408 B
    __shared__ __align__(16) u16 Pl[8][16 * 40];   // 10240 B

    int bh = blockIdx.x;
    int b = bh / H_, h = bh % H_;
    int t = threadIdx.x, lane = t & 63, w = t >> 6;
    int lr = lane & 15, q4 = lane >> 4;

    {
        int key0 = t >> 3;
        int d0 = (t & 7) * 8;
#pragma unroll
        for (int kp = 0; kp < NT; kp += 64) {
            int key = kp + key0;
            const u16* base = qkv + ((long long)(b * N_ + key)) * K3 + h * D_;
            vbf8 kv = *(const vbf8*)(base + C_ + d0);
            vbf8 vv = *(const vbf8*)(base + 2 * C_ + d0);
            *(vbf8*)((char*)Kl + ((key * 128 + d0 * 2) ^ ((key & 7) << 4))) = kv;
#pragma unroll
            for (int u = 0; u < 8; u++) Vt[(d0 + u) * MTS + key] = ((u16*)&vv)[u];
        }
    }
    __syncthreads();

    int qtok = w * 16 + lr;
    const u16* qbase = qkv + ((long long)(b * N_ + qtok)) * K3 + h * D_;
    vbf8 qf0 = *(const vbf8*)(qbase + q4 * 8);
    vbf8 qf1 = *(const vbf8*)(qbase + 32 + q4 * 8);

    float m[4], l[4];
    vf4 accO[4];
#pragma unroll
    for (int r = 0; r < 4; r++) { m[r] = -1e30f; l[r] = 0.f; }
#pragma unroll
    for (int dc = 0; dc < 4; dc++) accO[dc] = vf4{0.f, 0.f, 0.f, 0.f};

#pragma unroll
    for (int kt = 0; kt < 4; kt++) {
        vf4 S[2];
#pragma unroll
        for (int ks = 0; ks < 2; ks++) {
            int krow = kt * 32 + ks * 16 + lr;
            int swz = (krow & 7) << 4;
            vbf8 b0 = *(const vbf8*)((char*)Kl + ((krow * 128 + q4 * 16) ^ swz));
            vbf8 b1 = *(const vbf8*)((char*)Kl + ((krow * 128 + 64 + q4 * 16) ^ swz));
            vf4 z4 = vf4{0.f, 0.f, 0.f, 0.f};
            vf4 sv = __builtin_amdgcn_mfma_f32_16x16x32_bf16(qf0, b0, z4, 0, 0, 0);
            sv = __builtin_amdgcn_mfma_f32_16x16x32_bf16(qf1, b1, sv, 0, 0, 0);
#pragma unroll
            for (int r = 0; r < 4; r++) S[ks][r] = sv[r] * 0.125f;
        }

        float tm[4], ts[4], corr[4];
#pragma unroll
        for (int r = 0; r < 4; r++) tm[r] = fmaxf(S[0][r], S[1][r]);
#pragma unroll
        for (int off = 1; off <= 8; off <<= 1)
#pragma unroll
            for (int r = 0; r < 4; r++) tm[r] = fmaxf(tm[r], __shfl_xor(tm[r], off));
#pragma unroll
        for (int r = 0; r < 4; r++) {
            float nm = fmaxf(m[r], tm[r]);
            corr[r] = __expf(m[r] - nm);
            m[r] = nm;
        }
#pragma unroll
        for (int ks = 0; ks < 2; ks++)
#pragma unroll
            for (int r = 0; r < 4; r++) S[ks][r] = __expf(S[ks][r] - m[r]);
#pragma unroll
        for (int r = 0; r < 4; r++) ts[r] = S[0][r] + S[1][r];
#pragma unroll
        for (int off = 1; off <= 8; off <<= 1)
#pragma unroll
            for (int r = 0; r < 4; r++) ts[r] += __shfl_xor(ts[r], off);
#pragma unroll
        for (int r = 0; r < 4; r++) l[r] = l[r] * corr[r] + ts[r];
#pragma unroll
        for (int dc = 0; dc < 4; dc++)
#pragma unroll
            for (int r = 0; r < 4; r++) accO[dc][r] *= corr[r];

        {
            u16* pw = Pl[w];
#pragma unroll
            for (int ks = 0; ks < 2; ks++)
#pragma unroll
                for (int r = 0; r < 4; r++)
                    pw[(q4 * 4 + r) * 40 + ks * 16 + lr] = f2bf(S[ks][r]);
        }
        vbf8 pf = *(const vbf8*)&Pl[w][lr * 40 + q4 * 8];

#pragma unroll
        for (int dc = 0; dc < 4; dc++) {
            vbf8 vf_ = *(const vbf8*)&Vt[(dc * 16 + lr) * MTS + kt * 32 + q4 * 8];
            accO[dc] = __builtin_amdgcn_mfma_f32_16x16x32_bf16(pf, vf_, accO[dc], 0, 0, 0);
        }
    }

    float invl[4];
#pragma unroll
    for (int r = 0; r < 4; r++) invl[r] = 1.f / l[r];

    int qt0 = w * 16;
#pragma unroll
    for (int dc = 0; dc < 4; dc++)
#pragma unroll
        for (int r = 0; r < 4; r++) {
            int row = qt0 + q4 * 4 + r;
            concat[((long long)(b * N_ + row)) * C_ + h * D_ + dc * 16 + lr] =
                f2bf(accO[dc][r] * invl[r]);
        }
}

// ---------------------------------------------------------------------------
// sigma_pred (unchanged)
// ---------------------------------------------------------------------------
__global__ __launch_bounds__(256) void sigma_pred_kernel(
    u16* __restrict__ ksm, u16* __restrict__ vsm,
    const float* __restrict__ memin, const float* __restrict__ zin,
    float* __restrict__ z_out)
{
    __shared__ float mem_lds[4096];
    __shared__ float z_lds[64];
    __shared__ float zred[4][64];

    int bh = blockIdx.x;
    int b = bh / H_, h = bh % H_;
    int tid = threadIdx.x;
    int wv = tid >> 6, lane = tid & 63;

    for (int idx = tid; idx < 4096; idx += 256)
        mem_lds[idx] = memin[(long long)bh * 4096 + idx];
    if (tid < 64) z_lds[tid] = zin[bh * 64 + tid];
    __syncthreads();

    float zacc = 0.f;
    for (int n = wv; n < NS; n += 4) {
        long long roff = ((long long)(b * NS + n)) * C_ + h * D_;
        float x = bf2f(ksm[roff + lane]);
        float sig = elu1(x);
        ksm[roff + lane] = f2bf(sig);
        zacc += sig;

        float tz = sig * z_lds[lane];
#pragma unroll
        for (int o = 32; o; o >>= 1) tz += __shfl_xor(tz, o);
        float rden = 1.f / tz;

        float num = 0.f;
#pragma unroll
        for (int dd = 0; dd < 64; dd++)
            num = fmaf(__shfl(sig, dd), mem_lds[dd * 64 + lane], num);
        float pred = num * rden;

        float w = bf2f(vsm[roff + lane]) - pred;
        vsm[roff + lane] = f2bf(w);
    }
    zred[wv][lane] = zacc;
    __syncthreads();
    if (wv == 0) {
        float tot = zred[0][lane] + zred[1][lane] + zred[2][lane] + zred[3][lane];
        z_out[bh * 64 + lane] = zin[bh * 64 + lane] + tot;
    }
}

// ---------------------------------------------------------------------------
// mem_update (unchanged)
// ---------------------------------------------------------------------------
__global__ __launch_bounds__(256) void mem_update_kernel(
    const u16* __restrict__ ksm, const u16* __restrict__ vsm,
    const float* __restrict__ memin, float* __restrict__ mem_out)
{
    int bh = blockIdx.x;
    int b = bh / H_, h = bh % H_;
    int t = threadIdx.x;
    int e = t & 63, dg = t >> 6;

    float acc[16];
#pragma unroll
    for (int i = 0; i < 16; i++) acc[i] = 0.f;

    for (int n = 0; n < NS; n++) {
        long long roff = ((long long)(b * NS + n)) * C_ + h * D_;
        float wval = bf2f(vsm[roff + e]);
        uint4 s4a = *(const uint4*)(ksm + roff + dg * 16);
        uint4 s4b = *(const uint4*)(ksm + roff + dg * 16 + 8);
        float sv[16];
        sv[0]  = bf2f((u16)s4a.x); sv[1]  = bf2f((u16)(s4a.x >> 16));
        sv[2]  = bf2f((u16)s4a.y); sv[3]  = bf2f((u16)(s4a.y >> 16));
        sv[4]  = bf2f((u16)s4a.z); sv[5]  = bf2f((u16)(s4a.z >> 16));
        sv[6]  = bf2f((u16)s4a.w); sv[7]  = bf2f((u16)(s4a.w >> 16));
        sv[8]  = bf2f((u16)s4b.x); sv[9]  = bf2f((u16)(s4b.x >> 16));
        sv[10] = bf2f((u16)s4b.y); sv[11] = bf2f((u16)(s4b.y >> 16));
        sv[12] = bf2f((u16)s4b.z); sv[13] = bf2f((u16)(s4b.z >> 16));
        sv[14] = bf2f((u16)s4b.w); sv[15] = bf2f((u16)(s4b.w >> 16));
#pragma unroll
        for (int i = 0; i < 16; i++) acc[i] = fmaf(sv[i], wval, acc[i]);
    }

    long long mbase = (long long)bh * 4096;
#pragma unroll
    for (int i = 0; i < 16; i++) {
        int dd = dg * 16 + i;
        mem_out[mbase + dd * 64 + e] = memin[mbase + dd * 64 + e] + acc[i];
    }
}

// ---------------------------------------------------------------------------
extern "C" void kernel_launch(void* const* d_in, const int* in_sizes, int n_in,
                              void* d_out, int out_size, void* d_ws, size_t ws_size,
                              hipStream_t stream)
{
    const float* x      = (const float*)d_in[0];
    const float* mem    = (const float*)d_in[1];
    const float* z      = (const float*)d_in[2];
    const float* qkv_w  = (const float*)d_in[3];
    const float* qkv_b  = (const float*)d_in[4];
    const float* proj_w = (const float*)d_in[5];
    const float* proj_b = (const float*)d_in[6];
    const float* memk_w = (const float*)d_in[7];
    const float* memk_b = (const float*)d_in[8];
    const float* memv_w = (const float*)d_in[9];
    const float* memv_b = (const float*)d_in[10];
    const float* betas  = (const float*)d_in[11];

    u16* ws     = (u16*)d_ws;
    u16* qkv    = ws;
    u16* ksm    = qkv + QKV_LEN;
    u16* vsm    = ksm + KSM_LEN;
    u16* concat = vsm + KSM_LEN;      // doubles as x_bf before attn writes it

    float* out     = (float*)d_out;
    float* mem_out = out + CAT_LEN;
    float* z_out   = mem_out + MEM_LEN;

    u16* x_bf = concat;               // alias: dead after qkv GEMM
    u16* memT = (u16*)mem_out;        // scratch inside mem_out region;
                                      // overwritten later by mem_update

    // 0. conversions
    convert_bf16<<<dim3(2048), dim3(256), 0, stream>>>(x, x_bf, CAT_LEN);
    convert_wbf<<<dim3(864), dim3(256), 0, stream>>>(qkv_w,  WOFF_QKV,  1769472ll);
    convert_wbf<<<dim3(288), dim3(256), 0, stream>>>(memk_w, WOFF_MEMK, 589824ll);
    convert_wbf<<<dim3(288), dim3(256), 0, stream>>>(memv_w, WOFF_MEMV, 589824ll);
    convert_wbf<<<dim3(288), dim3(256), 0, stream>>>(proj_w, WOFF_PROJ, 589824ll);
    memT_kernel<<<dim3(B_ * H_), dim3(256), 0, stream>>>(mem, memT);

    // 1. qkv = x @ qkv_w^T + qkv_b
    gemm_mfma<0><<<dim3(K3 / 128, 49664 / 128), dim3(256), 0, stream>>>(
        x_bf, 0ll, 49664, 0ll, 768ll, WOFF_QKV, qkv_b, qkv, K3);
    // 2. k_s_mem
    gemm_mfma<0><<<dim3(C_ / 128, 33280 / 128), dim3(256), 0, stream>>>(
        qkv, (long long)(NT * K3 + C_), NS, (long long)N_ * K3, (long long)K3,
        WOFF_MEMK, memk_b, ksm, C_);
    // 3. v_s_mem
    gemm_mfma<0><<<dim3(C_ / 128, 33280 / 128), dim3(256), 0, stream>>>(
        qkv, (long long)(NT * K3 + 2 * C_), NS, (long long)N_ * K3, (long long)K3,
        WOFF_MEMV, memv_b, vsm, C_);
    // 4. spatial attention (+ mem readout + blend) -> concat[:, NT:]
    attn_s_mfma<<<dim3(B_ * H_), dim3(512), 0, stream>>>(
        qkv, memT, z, betas, concat);
    // 5. token/token attention -> concat[:, :NT]
    attn_mt_mfma<<<dim3(B_ * H_), dim3(512), 0, stream>>>(qkv, concat);
    // 6. sigma_k / pred + z_new
    sigma_pred_kernel<<<dim3(B_ * H_), dim3(256), 0, stream>>>(ksm, vsm, mem, z, z_out);
    // 7. mem_new (overwrites memT scratch)
    mem_update_kernel<<<dim3(B_ * H_), dim3(256), 0, stream>>>(ksm, vsm, mem, mem_out);
    // 8. out = concat @ proj_w^T + proj_b
    gemm_mfma<1><<<dim3(C_ / 128, 49664 / 128), dim3(256), 0, stream>>>(
        concat, 0ll, 49664, 0ll, 768ll, WOFF_PROJ, proj_b, out, C_);
}

// Round 7
// 1102.641 us; speedup vs baseline: 6.3082x; 1.2304x over previous
//
#include <hip/hip_runtime.h>

typedef unsigned short u16;
typedef __attribute__((ext_vector_type(8))) short  vbf8;   // 8 bf16 (4 VGPRs)
typedef __attribute__((ext_vector_type(4))) float  vf4;    // 4 f32 acc

#define B_   128
#define N_   388
#define NT   128
#define NS   260
#define C_   768
#define H_   12
#define D_   64
#define K3   2304   // 3*C

#define QKV_LEN  114425856ll   // 49664*2304  (bf16 ws)
#define KSM_LEN  25559040ll    // 33280*768
#define CAT_LEN  38141952ll    // 49664*768
#define MEM_LEN  6291456ll     // 128*12*64*64 (f32, in d_out)

#define SPS  288               // sigmaT/wT row stride (keys padded 260->288)
#define SWT_LEN 28311552ll     // 1536*64*288

// bf16 weights: [qkv_w | memk_w | memv_w | proj_w]
#define WOFF_QKV  0ll
#define WOFF_MEMK 1769472ll
#define WOFF_MEMV 2359296ll
#define WOFF_PROJ 2949120ll
__device__ __align__(16) u16 g_wbf[3538944];

__device__ __forceinline__ float bf2f(u16 u) {
    union { unsigned int i; float f; } v; v.i = ((unsigned int)u) << 16; return v.f;
}
__device__ __forceinline__ u16 f2bf(float f) {
    union { float f; unsigned int i; } v; v.f = f;
    unsigned int r = v.i + 0x7fffu + ((v.i >> 16) & 1u);
    return (u16)(r >> 16);
}
__device__ __forceinline__ float elu1(float x) { return x > 0.f ? x + 1.f : __expf(x); }

// ---------------------------------------------------------------------------
// f32 -> bf16 converters
// ---------------------------------------------------------------------------
__global__ __launch_bounds__(256) void convert_bf16(
    const float* __restrict__ src, u16* __restrict__ dst, long long n)
{
    long long i0 = ((long long)blockIdx.x * 256 + threadIdx.x) * 8;
    long long stride = (long long)gridDim.x * 256 * 8;
    for (long long i = i0; i < n; i += stride) {
        float4 a = *(const float4*)(src + i);
        float4 b = *(const float4*)(src + i + 4);
        ushort4 u1; u1.x = f2bf(a.x); u1.y = f2bf(a.y); u1.z = f2bf(a.z); u1.w = f2bf(a.w);
        ushort4 u2; u2.x = f2bf(b.x); u2.y = f2bf(b.y); u2.z = f2bf(b.z); u2.w = f2bf(b.w);
        *(ushort4*)(dst + i)     = u1;
        *(ushort4*)(dst + i + 4) = u2;
    }
}

__global__ __launch_bounds__(256) void convert_wbf(
    const float* __restrict__ src, long long dst_off, long long n)
{
    u16* dst = g_wbf + dst_off;
    long long i0 = ((long long)blockIdx.x * 256 + threadIdx.x) * 8;
    long long stride = (long long)gridDim.x * 256 * 8;
    for (long long i = i0; i < n; i += stride) {
        float4 a = *(const float4*)(src + i);
        float4 b = *(const float4*)(src + i + 4);
        ushort4 u1; u1.x = f2bf(a.x); u1.y = f2bf(a.y); u1.z = f2bf(a.z); u1.w = f2bf(a.w);
        ushort4 u2; u2.x = f2bf(b.x); u2.y = f2bf(b.y); u2.z = f2bf(b.z); u2.w = f2bf(b.w);
        *(ushort4*)(dst + i)     = u1;
        *(ushort4*)(dst + i + 4) = u2;
    }
}

// ---------------------------------------------------------------------------
// memT[bh][dout][din] = bf16(mem[bh][din][dout])
// ---------------------------------------------------------------------------
__global__ __launch_bounds__(256) void memT_kernel(
    const float* __restrict__ memin, u16* __restrict__ memT)
{
    __shared__ float ml[64 * 65];
    int bh = blockIdx.x, t = threadIdx.x;
    const float* src = memin + (long long)bh * 4096;
#pragma unroll
    for (int i = 0; i < 16; i++) {
        int idx = i * 256 + t;
        ml[(idx >> 6) * 65 + (idx & 63)] = src[idx];
    }
    __syncthreads();
    u16* dst = memT + (long long)bh * 4096;
#pragma unroll
    for (int i = 0; i < 16; i++) {
        int o = i * 256 + t;
        int dout = o >> 6, din = o & 63;
        dst[o] = f2bf(ml[din * 65 + dout]);
    }
}

// ---------------------------------------------------------------------------
// MFMA GEMM (unchanged): C = A @ W^T + bias, K=768.
// ---------------------------------------------------------------------------
template<int CF32>
__global__ __launch_bounds__(256) void gemm_mfma(
    const u16* __restrict__ A, long long off0, int rows_per_b,
    long long stride_b, long long stride_r,
    long long w_off, const float* __restrict__ bias,
    void* __restrict__ Cv, int Nout)
{
    __shared__ __align__(16) u16 lds[2][2][4096];

    const u16* W = g_wbf + w_off;

    int t  = threadIdx.x;
    int m0 = blockIdx.y * 128;
    int n0 = blockIdx.x * 128;

    int r0 = t >> 2;
    int c0 = (t & 3) * 8;
    long long aoff0, aoff1;
    {
        int g1 = m0 + r0, g2 = m0 + r0 + 64;
        int b1 = g1 / rows_per_b, j1 = g1 - b1 * rows_per_b;
        int b2 = g2 / rows_per_b, j2 = g2 - b2 * rows_per_b;
        aoff0 = off0 + (long long)b1 * stride_b + (long long)j1 * stride_r + c0;
        aoff1 = off0 + (long long)b2 * stride_b + (long long)j2 * stride_r + c0;
    }
    const u16* wp0 = W + (long long)(n0 + r0) * 768 + c0;
    const u16* wp1 = W + (long long)(n0 + r0 + 64) * 768 + c0;

    int lane = t & 63;
    int wid  = t >> 6;
    int wm = wid >> 1, wn = wid & 1;
    int lr = lane & 15;
    int kg = lane >> 4;
    int a_rd = (wm * 64 + lr) * 32 + kg * 8;
    int b_rd = (wn * 64 + lr) * 32 + kg * 8;

    vf4 acc[4][4];
#pragma unroll
    for (int i = 0; i < 4; i++)
#pragma unroll
        for (int j = 0; j < 4; j++) acc[i][j] = vf4{0.f, 0.f, 0.f, 0.f};

    {
        vbf8 sa0 = *(const vbf8*)(A + aoff0);
        vbf8 sa1 = *(const vbf8*)(A + aoff1);
        vbf8 sb0 = *(const vbf8*)(wp0);
        vbf8 sb1 = *(const vbf8*)(wp1);
        *(vbf8*)&lds[0][0][t * 8]        = sa0;
        *(vbf8*)&lds[0][0][2048 + t * 8] = sa1;
        *(vbf8*)&lds[0][1][t * 8]        = sb0;
        *(vbf8*)&lds[0][1][2048 + t * 8] = sb1;
    }

    int cur = 0;
    for (int kt = 0; kt < 768; kt += 32) {
        bool last = (kt == 768 - 32);
        vbf8 na0, na1, nb0, nb1;
        if (!last) {
            na0 = *(const vbf8*)(A + aoff0 + kt + 32);
            na1 = *(const vbf8*)(A + aoff1 + kt + 32);
            nb0 = *(const vbf8*)(wp0 + kt + 32);
            nb1 = *(const vbf8*)(wp1 + kt + 32);
        }
        __syncthreads();

        vbf8 af[4], bf[4];
#pragma unroll
        for (int f = 0; f < 4; f++) {
            af[f] = *(const vbf8*)&lds[cur][0][a_rd + f * 512];
            bf[f] = *(const vbf8*)&lds[cur][1][b_rd + f * 512];
        }
#pragma unroll
        for (int i = 0; i < 4; i++)
#pragma unroll
            for (int j = 0; j < 4; j++)
                acc[i][j] = __builtin_amdgcn_mfma_f32_16x16x32_bf16(
                    af[i], bf[j], acc[i][j], 0, 0, 0);

        if (!last) {
            *(vbf8*)&lds[cur ^ 1][0][t * 8]        = na0;
            *(vbf8*)&lds[cur ^ 1][0][2048 + t * 8] = na1;
            *(vbf8*)&lds[cur ^ 1][1][t * 8]        = nb0;
            *(vbf8*)&lds[cur ^ 1][1][2048 + t * 8] = nb1;
            cur ^= 1;
        }
    }

#pragma unroll
    for (int i = 0; i < 4; i++) {
        int row = m0 + wm * 64 + i * 16 + kg * 4;
#pragma unroll
        for (int j = 0; j < 4; j++) {
            int col = n0 + wn * 64 + j * 16 + lr;
            float bb = bias[col];
#pragma unroll
            for (int r = 0; r < 4; r++) {
                float v = acc[i][j][r] + bb;
                long long idx = (long long)(row + r) * Nout + col;
                if (CF32) ((float*)Cv)[idx] = v;
                else      ((u16*)Cv)[idx]  = f2bf(v);
            }
        }
    }
}

// ---------------------------------------------------------------------------
// attn_s_mfma (unchanged from round 6)
// ---------------------------------------------------------------------------
#define SKP 416
#define VTS 424
__global__ __launch_bounds__(512) void attn_s_mfma(
    const u16* __restrict__ qkv, const u16* __restrict__ memT,
    const float* __restrict__ zin, const float* __restrict__ betas,
    u16* __restrict__ concat)
{
    __shared__ __align__(16) u16 Kl[SKP * 64];
    __shared__ __align__(16) u16 Vt[64 * VTS];
    __shared__ __align__(16) u16 Pl[8][16 * 40];
    __shared__ float red[8][16];

    int bh = blockIdx.x;
    int b = bh / H_, h = bh % H_;
    int t = threadIdx.x, lane = t & 63, w = t >> 6;
    int lr = lane & 15, q4 = lane >> 4;

    {
        int key0 = t >> 3;
        int d0 = (t & 7) * 8;
        for (int kp = 0; kp < SKP; kp += 64) {
            int key = kp + key0;
            if (key < SKP) {
                vbf8 kv, vv;
#pragma unroll
                for (int u = 0; u < 8; u++) { ((short*)&kv)[u] = 0; ((short*)&vv)[u] = 0; }
                if (key < N_) {
                    const u16* base = qkv + ((long long)(b * N_ + key)) * K3 + h * D_;
                    kv = *(const vbf8*)(base + C_ + d0);
                    vv = *(const vbf8*)(base + 2 * C_ + d0);
                }
                *(vbf8*)((char*)Kl + ((key * 128 + d0 * 2) ^ ((key & 7) << 4))) = kv;
#pragma unroll
                for (int u = 0; u < 8; u++) Vt[(d0 + u) * VTS + key] = ((u16*)&vv)[u];
            }
        }
    }
    __syncthreads();

    const float* zp = zin + bh * 64;
    const u16* mtb = memT + (long long)bh * 4096;

    for (int s = w; s < 17; s += 8) {
        int qtok = NT + s * 16 + lr;
        if (qtok > N_ - 1) qtok = N_ - 1;
        const u16* qbase = qkv + ((long long)(b * N_ + qtok)) * K3 + h * D_;
        vbf8 qf0 = *(const vbf8*)(qbase + q4 * 8);
        vbf8 qf1 = *(const vbf8*)(qbase + 32 + q4 * 8);

        float m[4], l[4];
        vf4 accO[4];
#pragma unroll
        for (int r = 0; r < 4; r++) { m[r] = -1e30f; l[r] = 0.f; }
#pragma unroll
        for (int dc = 0; dc < 4; dc++) accO[dc] = vf4{0.f, 0.f, 0.f, 0.f};

        for (int kt = 0; kt < 13; kt++) {
            int kvalid = N_ - kt * 32; if (kvalid > 32) kvalid = 32;

            vf4 S[2];
#pragma unroll
            for (int ks = 0; ks < 2; ks++) {
                int krow = kt * 32 + ks * 16 + lr;
                int swz = (krow & 7) << 4;
                vbf8 b0 = *(const vbf8*)((char*)Kl + ((krow * 128 + q4 * 16) ^ swz));
                vbf8 b1 = *(const vbf8*)((char*)Kl + ((krow * 128 + 64 + q4 * 16) ^ swz));
                vf4 z4 = vf4{0.f, 0.f, 0.f, 0.f};
                vf4 sv = __builtin_amdgcn_mfma_f32_16x16x32_bf16(qf0, b0, z4, 0, 0, 0);
                sv = __builtin_amdgcn_mfma_f32_16x16x32_bf16(qf1, b1, sv, 0, 0, 0);
                bool inv = (ks * 16 + lr) >= kvalid;
#pragma unroll
                for (int r = 0; r < 4; r++)
                    S[ks][r] = inv ? -1e30f : sv[r] * 0.125f;
            }

            float tm[4], ts[4], corr[4];
#pragma unroll
            for (int r = 0; r < 4; r++) tm[r] = fmaxf(S[0][r], S[1][r]);
#pragma unroll
            for (int off = 1; off <= 8; off <<= 1)
#pragma unroll
                for (int r = 0; r < 4; r++) tm[r] = fmaxf(tm[r], __shfl_xor(tm[r], off));
#pragma unroll
            for (int r = 0; r < 4; r++) {
                float nm = fmaxf(m[r], tm[r]);
                corr[r] = __expf(m[r] - nm);
                m[r] = nm;
            }
#pragma unroll
            for (int ks = 0; ks < 2; ks++)
#pragma unroll
                for (int r = 0; r < 4; r++) S[ks][r] = __expf(S[ks][r] - m[r]);
#pragma unroll
            for (int r = 0; r < 4; r++) ts[r] = S[0][r] + S[1][r];
#pragma unroll
            for (int off = 1; off <= 8; off <<= 1)
#pragma unroll
                for (int r = 0; r < 4; r++) ts[r] += __shfl_xor(ts[r], off);
#pragma unroll
            for (int r = 0; r < 4; r++) l[r] = l[r] * corr[r] + ts[r];
#pragma unroll
            for (int dc = 0; dc < 4; dc++)
#pragma unroll
                for (int r = 0; r < 4; r++) accO[dc][r] *= corr[r];

            {
                u16* pw = Pl[w];
#pragma unroll
                for (int ks = 0; ks < 2; ks++)
#pragma unroll
                    for (int r = 0; r < 4; r++)
                        pw[(q4 * 4 + r) * 40 + ks * 16 + lr] = f2bf(S[ks][r]);
            }
            vbf8 pf = *(const vbf8*)&Pl[w][lr * 40 + q4 * 8];

#pragma unroll
            for (int dc = 0; dc < 4; dc++) {
                vbf8 vf_ = *(const vbf8*)&Vt[(dc * 16 + lr) * VTS + kt * 32 + q4 * 8];
                accO[dc] = __builtin_amdgcn_mfma_f32_16x16x32_bf16(pf, vf_, accO[dc], 0, 0, 0);
            }
        }

        float invl[4];
#pragma unroll
        for (int r = 0; r < 4; r++) invl[r] = 1.f / l[r];

        vbf8 sq0, sq1;
        float dpart = 0.f;
#pragma unroll
        for (int j = 0; j < 8; j++) {
            float s0 = elu1(bf2f(((u16*)&qf0)[j]));
            float s1 = elu1(bf2f(((u16*)&qf1)[j]));
            ((u16*)&sq0)[j] = f2bf(s0);
            ((u16*)&sq1)[j] = f2bf(s1);
            dpart += s0 * zp[q4 * 8 + j] + s1 * zp[32 + q4 * 8 + j];
        }
        dpart += __shfl_xor(dpart, 16);
        dpart += __shfl_xor(dpart, 32);
        if (q4 == 0) red[w][lr] = dpart;

        vf4 am[4];
#pragma unroll
        for (int dc = 0; dc < 4; dc++) {
            vbf8 b0 = *(const vbf8*)(mtb + (dc * 16 + lr) * 64 + q4 * 8);
            vbf8 b1 = *(const vbf8*)(mtb + (dc * 16 + lr) * 64 + 32 + q4 * 8);
            vf4 z4 = vf4{0.f, 0.f, 0.f, 0.f};
            vf4 a = __builtin_amdgcn_mfma_f32_16x16x32_bf16(sq0, b0, z4, 0, 0, 0);
            am[dc] = __builtin_amdgcn_mfma_f32_16x16x32_bf16(sq1, b1, a, 0, 0, 0);
        }
        float den[4];
#pragma unroll
        for (int r = 0; r < 4; r++) den[r] = 1.f / red[w][q4 * 4 + r];

#pragma unroll
        for (int dc = 0; dc < 4; dc++) {
            float bb = betas[h * D_ + dc * 16 + lr];
            float beta = 1.f / (1.f + __expf(-bb));
#pragma unroll
            for (int r = 0; r < 4; r++) {
                int qs = s * 16 + q4 * 4 + r;
                if (qs < NS) {
                    float o = beta * (am[dc][r] * den[r]) +
                              (1.f - beta) * (accO[dc][r] * invl[r]);
                    concat[((long long)(b * N_ + NT + qs)) * C_ + h * D_ + dc * 16 + lr] = f2bf(o);
                }
            }
        }
    }
}

// ---------------------------------------------------------------------------
// attn_mt_mfma (unchanged from round 6)
// ---------------------------------------------------------------------------
#define MTS 136
__global__ __launch_bounds__(512) void attn_mt_mfma(
    const u16* __restrict__ qkv, u16* __restrict__ concat)
{
    __shared__ __align__(16) u16 Kl[NT * 64];
    __shared__ __align__(16) u16 Vt[64 * MTS];
    __shared__ __align__(16) u16 Pl[8][16 * 40];

    int bh = blockIdx.x;
    int b = bh / H_, h = bh % H_;
    int t = threadIdx.x, lane = t & 63, w = t >> 6;
    int lr = lane & 15, q4 = lane >> 4;

    {
        int key0 = t >> 3;
        int d0 = (t & 7) * 8;
#pragma unroll
        for (int kp = 0; kp < NT; kp += 64) {
            int key = kp + key0;
            const u16* base = qkv + ((long long)(b * N_ + key)) * K3 + h * D_;
            vbf8 kv = *(const vbf8*)(base + C_ + d0);
            vbf8 vv = *(const vbf8*)(base + 2 * C_ + d0);
            *(vbf8*)((char*)Kl + ((key * 128 + d0 * 2) ^ ((key & 7) << 4))) = kv;
#pragma unroll
            for (int u = 0; u < 8; u++) Vt[(d0 + u) * MTS + key] = ((u16*)&vv)[u];
        }
    }
    __syncthreads();

    int qtok = w * 16 + lr;
    const u16* qbase = qkv + ((long long)(b * N_ + qtok)) * K3 + h * D_;
    vbf8 qf0 = *(const vbf8*)(qbase + q4 * 8);
    vbf8 qf1 = *(const vbf8*)(qbase + 32 + q4 * 8);

    float m[4], l[4];
    vf4 accO[4];
#pragma unroll
    for (int r = 0; r < 4; r++) { m[r] = -1e30f; l[r] = 0.f; }
#pragma unroll
    for (int dc = 0; dc < 4; dc++) accO[dc] = vf4{0.f, 0.f, 0.f, 0.f};

#pragma unroll
    for (int kt = 0; kt < 4; kt++) {
        vf4 S[2];
#pragma unroll
        for (int ks = 0; ks < 2; ks++) {
            int krow = kt * 32 + ks * 16 + lr;
            int swz = (krow & 7) << 4;
            vbf8 b0 = *(const vbf8*)((char*)Kl + ((krow * 128 + q4 * 16) ^ swz));
            vbf8 b1 = *(const vbf8*)((char*)Kl + ((krow * 128 + 64 + q4 * 16) ^ swz));
            vf4 z4 = vf4{0.f, 0.f, 0.f, 0.f};
            vf4 sv = __builtin_amdgcn_mfma_f32_16x16x32_bf16(qf0, b0, z4, 0, 0, 0);
            sv = __builtin_amdgcn_mfma_f32_16x16x32_bf16(qf1, b1, sv, 0, 0, 0);
#pragma unroll
            for (int r = 0; r < 4; r++) S[ks][r] = sv[r] * 0.125f;
        }

        float tm[4], ts[4], corr[4];
#pragma unroll
        for (int r = 0; r < 4; r++) tm[r] = fmaxf(S[0][r], S[1][r]);
#pragma unroll
        for (int off = 1; off <= 8; off <<= 1)
#pragma unroll
            for (int r = 0; r < 4; r++) tm[r] = fmaxf(tm[r], __shfl_xor(tm[r], off));
#pragma unroll
        for (int r = 0; r < 4; r++) {
            float nm = fmaxf(m[r], tm[r]);
            corr[r] = __expf(m[r] - nm);
            m[r] = nm;
        }
#pragma unroll
        for (int ks = 0; ks < 2; ks++)
#pragma unroll
            for (int r = 0; r < 4; r++) S[ks][r] = __expf(S[ks][r] - m[r]);
#pragma unroll
        for (int r = 0; r < 4; r++) ts[r] = S[0][r] + S[1][r];
#pragma unroll
        for (int off = 1; off <= 8; off <<= 1)
#pragma unroll
            for (int r = 0; r < 4; r++) ts[r] += __shfl_xor(ts[r], off);
#pragma unroll
        for (int r = 0; r < 4; r++) l[r] = l[r] * corr[r] + ts[r];
#pragma unroll
        for (int dc = 0; dc < 4; dc++)
#pragma unroll
            for (int r = 0; r < 4; r++) accO[dc][r] *= corr[r];

        {
            u16* pw = Pl[w];
#pragma unroll
            for (int ks = 0; ks < 2; ks++)
#pragma unroll
                for (int r = 0; r < 4; r++)
                    pw[(q4 * 4 + r) * 40 + ks * 16 + lr] = f2bf(S[ks][r]);
        }
        vbf8 pf = *(const vbf8*)&Pl[w][lr * 40 + q4 * 8];

#pragma unroll
        for (int dc = 0; dc < 4; dc++) {
            vbf8 vf_ = *(const vbf8*)&Vt[(dc * 16 + lr) * MTS + kt * 32 + q4 * 8];
            accO[dc] = __builtin_amdgcn_mfma_f32_16x16x32_bf16(pf, vf_, accO[dc], 0, 0, 0);
        }
    }

    float invl[4];
#pragma unroll
    for (int r = 0; r < 4; r++) invl[r] = 1.f / l[r];

    int qt0 = w * 16;
#pragma unroll
    for (int dc = 0; dc < 4; dc++)
#pragma unroll
        for (int r = 0; r < 4; r++) {
            int row = qt0 + q4 * 4 + r;
            concat[((long long)(b * N_ + row)) * C_ + h * D_ + dc * 16 + lr] =
                f2bf(accO[dc][r] * invl[r]);
        }
}

// ---------------------------------------------------------------------------
// sigma_pred_mfma: per (b,h), 512 thr (8 waves). Strips of 16 key-rows
// (18 strips, n padded to 288). Per strip: sigma = elu(ksm)+1 as A-frags,
// num = sigma @ memT via MFMA, den = sigma.z via shuffles,
// w = vsm - num/den. Emits sigmaT/wT (n-contiguous, stride SPS) via per-wave
// LDS transpose, plus z_new = z + colsum(sigma).
// ---------------------------------------------------------------------------
__global__ __launch_bounds__(512) void sigma_pred_mfma(
    const u16* __restrict__ ksm, const u16* __restrict__ vsm,
    const u16* __restrict__ memT, const float* __restrict__ zin,
    u16* __restrict__ sigT, u16* __restrict__ wT,
    float* __restrict__ z_out)
{
    __shared__ u16 sigLDS[8][64][18];
    __shared__ u16 wLDS[8][64][18];
    __shared__ float red[8][16];
    __shared__ float zpart[8][64];
    __shared__ float zlds[64];

    int bh = blockIdx.x;
    int b = bh / H_, h = bh % H_;
    int t = threadIdx.x, lane = t & 63, w = t >> 6;
    int lr = lane & 15, q4 = lane >> 4;

    if (t < 64) zlds[t] = zin[bh * 64 + t];
    __syncthreads();

    const u16* mtb = memT + (long long)bh * 4096;
    float zacc[16];
#pragma unroll
    for (int j = 0; j < 16; j++) zacc[j] = 0.f;

    for (int s = w; s < 18; s += 8) {
        int n0 = s * 16;
        int nrow = n0 + lr;
        bool vrow = nrow < NS;
        int nclamp = vrow ? nrow : NS - 1;
        const u16* kbase = ksm + ((long long)(b * NS + nclamp)) * C_ + h * D_;
        vbf8 k0 = *(const vbf8*)(kbase + q4 * 8);
        vbf8 k1 = *(const vbf8*)(kbase + 32 + q4 * 8);

        vbf8 sq0, sq1;
        float dpart = 0.f;
#pragma unroll
        for (int j = 0; j < 8; j++) {
            float s0 = vrow ? elu1(bf2f(((u16*)&k0)[j])) : 0.f;
            float s1 = vrow ? elu1(bf2f(((u16*)&k1)[j])) : 0.f;
            ((u16*)&sq0)[j] = f2bf(s0);
            ((u16*)&sq1)[j] = f2bf(s1);
            zacc[j]     += s0;
            zacc[8 + j] += s1;
            dpart += s0 * zlds[q4 * 8 + j] + s1 * zlds[32 + q4 * 8 + j];
        }
        dpart += __shfl_xor(dpart, 16);
        dpart += __shfl_xor(dpart, 32);
        if (q4 == 0) red[w][lr] = dpart;

        // sigma -> LDS (layout [d][n-local])
#pragma unroll
        for (int j = 0; j < 8; j++) {
            sigLDS[w][q4 * 8 + j][lr]      = ((u16*)&sq0)[j];
            sigLDS[w][32 + q4 * 8 + j][lr] = ((u16*)&sq1)[j];
        }

        // num = sigma @ memT
        vf4 am[4];
#pragma unroll
        for (int dc = 0; dc < 4; dc++) {
            vbf8 b0 = *(const vbf8*)(mtb + (dc * 16 + lr) * 64 + q4 * 8);
            vbf8 b1 = *(const vbf8*)(mtb + (dc * 16 + lr) * 64 + 32 + q4 * 8);
            vf4 z4 = vf4{0.f, 0.f, 0.f, 0.f};
            vf4 a = __builtin_amdgcn_mfma_f32_16x16x32_bf16(sq0, b0, z4, 0, 0, 0);
            am[dc] = __builtin_amdgcn_mfma_f32_16x16x32_bf16(sq1, b1, a, 0, 0, 0);
        }
        float rden[4];
#pragma unroll
        for (int r = 0; r < 4; r++) rden[r] = 1.f / red[w][q4 * 4 + r];

        // w = vsm - pred -> LDS (layout [e][n-local])
#pragma unroll
        for (int dc = 0; dc < 4; dc++) {
            int e = dc * 16 + lr;
#pragma unroll
            for (int r = 0; r < 4; r++) {
                int nn = n0 + q4 * 4 + r;
                float wv = 0.f;
                if (nn < NS) {
                    float pv = am[dc][r] * rden[r];
                    wv = bf2f(vsm[((long long)(b * NS + nn)) * C_ + h * D_ + e]) - pv;
                }
                wLDS[w][e][q4 * 4 + r] = f2bf(wv);
            }
        }

        // transposed stores: lane -> d/e = lane, 16 n-contig values (32B)
        {
            long long dst = ((long long)bh * 64 + lane) * SPS + n0;
            unsigned pk[8];
#pragma unroll
            for (int j2 = 0; j2 < 8; j2++)
                pk[j2] = (unsigned)sigLDS[w][lane][2 * j2] |
                         ((unsigned)sigLDS[w][lane][2 * j2 + 1] << 16);
            *(uint4*)(sigT + dst)     = uint4{pk[0], pk[1], pk[2], pk[3]};
            *(uint4*)(sigT + dst + 8) = uint4{pk[4], pk[5], pk[6], pk[7]};
#pragma unroll
            for (int j2 = 0; j2 < 8; j2++)
                pk[j2] = (unsigned)wLDS[w][lane][2 * j2] |
                         ((unsigned)wLDS[w][lane][2 * j2 + 1] << 16);
            *(uint4*)(wT + dst)     = uint4{pk[0], pk[1], pk[2], pk[3]};
            *(uint4*)(wT + dst + 8) = uint4{pk[4], pk[5], pk[6], pk[7]};
        }
    }

    // z_new = z + colsum(sigma)
#pragma unroll
    for (int off = 1; off <= 8; off <<= 1)
#pragma unroll
        for (int j = 0; j < 16; j++) zacc[j] += __shfl_xor(zacc[j], off);
    if (lr == 0) {
#pragma unroll
        for (int j = 0; j < 8; j++) {
            zpart[w][q4 * 8 + j]      = zacc[j];
            zpart[w][32 + q4 * 8 + j] = zacc[8 + j];
        }
    }
    __syncthreads();
    if (t < 64) {
        float tot = 0.f;
#pragma unroll
        for (int ww = 0; ww < 8; ww++) tot += zpart[ww][t];
        z_out[bh * 64 + t] = zlds[t] + tot;
    }
}

// ---------------------------------------------------------------------------
// mem_update_mfma: per (b,h), 1 wave. mem_new = mem + sigT @ wT^T
// (both K-major along n, K = SPS = 288, zero-padded).
// ---------------------------------------------------------------------------
__global__ __launch_bounds__(64) void mem_update_mfma(
    const u16* __restrict__ sigT, const u16* __restrict__ wT,
    const float* __restrict__ memin, float* __restrict__ mem_out)
{
    int bh = blockIdx.x;
    int lane = threadIdx.x;
    int lr = lane & 15, q4 = lane >> 4;

    const u16* sb = sigT + (long long)bh * 64 * SPS;
    const u16* wb = wT   + (long long)bh * 64 * SPS;

    vf4 acc[4][4];
#pragma unroll
    for (int i = 0; i < 4; i++)
#pragma unroll
        for (int j = 0; j < 4; j++) acc[i][j] = vf4{0.f, 0.f, 0.f, 0.f};

    for (int kt = 0; kt < SPS; kt += 32) {
        vbf8 af[4], bf[4];
#pragma unroll
        for (int i = 0; i < 4; i++)
            af[i] = *(const vbf8*)(sb + (long long)(i * 16 + lr) * SPS + kt + q4 * 8);
#pragma unroll
        for (int j = 0; j < 4; j++)
            bf[j] = *(const vbf8*)(wb + (long long)(j * 16 + lr) * SPS + kt + q4 * 8);
#pragma unroll
        for (int i = 0; i < 4; i++)
#pragma unroll
            for (int j = 0; j < 4; j++)
                acc[i][j] = __builtin_amdgcn_mfma_f32_16x16x32_bf16(
                    af[i], bf[j], acc[i][j], 0, 0, 0);
    }

    long long mb = (long long)bh * 4096;
#pragma unroll
    for (int i = 0; i < 4; i++)
#pragma unroll
        for (int j = 0; j < 4; j++)
#pragma unroll
            for (int r = 0; r < 4; r++) {
                int d = i * 16 + q4 * 4 + r;
                int e = j * 16 + lr;
                mem_out[mb + d * 64 + e] = memin[mb + d * 64 + e] + acc[i][j][r];
            }
}

// ---------------------------------------------------------------------------
extern "C" void kernel_launch(void* const* d_in, const int* in_sizes, int n_in,
                              void* d_out, int out_size, void* d_ws, size_t ws_size,
                              hipStream_t stream)
{
    const float* x      = (const float*)d_in[0];
    const float* mem    = (const float*)d_in[1];
    const float* z      = (const float*)d_in[2];
    const float* qkv_w  = (const float*)d_in[3];
    const float* qkv_b  = (const float*)d_in[4];
    const float* proj_w = (const float*)d_in[5];
    const float* proj_b = (const float*)d_in[6];
    const float* memk_w = (const float*)d_in[7];
    const float* memk_b = (const float*)d_in[8];
    const float* memv_w = (const float*)d_in[9];
    const float* memv_b = (const float*)d_in[10];
    const float* betas  = (const float*)d_in[11];

    u16* ws     = (u16*)d_ws;
    u16* qkv    = ws;
    u16* ksm    = qkv + QKV_LEN;
    u16* vsm    = ksm + KSM_LEN;
    u16* concat = vsm + KSM_LEN;      // doubles as x_bf before attn writes it

    float* out     = (float*)d_out;
    float* mem_out = out + CAT_LEN;
    float* z_out   = mem_out + MEM_LEN;

    u16* x_bf = concat;               // alias: dead after qkv GEMM
    u16* memT = (u16*)mem_out;        // scratch in mem_out region (overwritten last)
    u16* sigT = qkv;                  // alias: qkv dead after attn kernels
    u16* wT   = qkv + SWT_LEN;        // 2*SWT_LEN = 56.6M <= QKV_LEN ✓

    // 0. conversions
    convert_bf16<<<dim3(2048), dim3(256), 0, stream>>>(x, x_bf, CAT_LEN);
    convert_wbf<<<dim3(864), dim3(256), 0, stream>>>(qkv_w,  WOFF_QKV,  1769472ll);
    convert_wbf<<<dim3(288), dim3(256), 0, stream>>>(memk_w, WOFF_MEMK, 589824ll);
    convert_wbf<<<dim3(288), dim3(256), 0, stream>>>(memv_w, WOFF_MEMV, 589824ll);
    convert_wbf<<<dim3(288), dim3(256), 0, stream>>>(proj_w, WOFF_PROJ, 589824ll);
    memT_kernel<<<dim3(B_ * H_), dim3(256), 0, stream>>>(mem, memT);

    // 1. qkv = x @ qkv_w^T + qkv_b
    gemm_mfma<0><<<dim3(K3 / 128, 49664 / 128), dim3(256), 0, stream>>>(
        x_bf, 0ll, 49664, 0ll, 768ll, WOFF_QKV, qkv_b, qkv, K3);
    // 2. k_s_mem
    gemm_mfma<0><<<dim3(C_ / 128, 33280 / 128), dim3(256), 0, stream>>>(
        qkv, (long long)(NT * K3 + C_), NS, (long long)N_ * K3, (long long)K3,
        WOFF_MEMK, memk_b, ksm, C_);
    // 3. v_s_mem
    gemm_mfma<0><<<dim3(C_ / 128, 33280 / 128), dim3(256), 0, stream>>>(
        qkv, (long long)(NT * K3 + 2 * C_), NS, (long long)N_ * K3, (long long)K3,
        WOFF_MEMV, memv_b, vsm, C_);
    // 4. spatial attention (+ mem readout + blend) -> concat[:, NT:]
    attn_s_mfma<<<dim3(B_ * H_), dim3(512), 0, stream>>>(
        qkv, memT, z, betas, concat);
    // 5. token/token attention -> concat[:, :NT]
    attn_mt_mfma<<<dim3(B_ * H_), dim3(512), 0, stream>>>(qkv, concat);
    // 6. sigma/pred -> sigT/wT (overwrites qkv region) + z_new
    sigma_pred_mfma<<<dim3(B_ * H_), dim3(512), 0, stream>>>(
        ksm, vsm, memT, z, sigT, wT, z_out);
    // 7. mem_new = mem + sigT @ wT^T (overwrites memT scratch)
    mem_update_mfma<<<dim3(B_ * H_), dim3(64), 0, stream>>>(
        sigT, wT, mem, mem_out);
    // 8. out = concat @ proj_w^T + proj_b
    gemm_mfma<1><<<dim3(C_ / 128, 49664 / 128), dim3(256), 0, stream>>>(
        concat, 0ll, 49664, 0ll, 768ll, WOFF_PROJ, proj_b, out, C_);
}

// Round 8
// 1004.208 us; speedup vs baseline: 6.9265x; 1.0980x over previous
//
#include <hip/hip_runtime.h>

typedef unsigned short u16;
typedef __attribute__((ext_vector_type(8))) short  vbf8;   // 8 bf16 (4 VGPRs)
typedef __attribute__((ext_vector_type(4))) float  vf4;    // 4 f32 acc

#define B_   128
#define N_   388
#define NT   128
#define NS   260
#define C_   768
#define H_   12
#define D_   64
#define K3   2304   // 3*C

#define QKV_LEN  114425856ll   // 49664*2304  (bf16 ws)
#define KSM_LEN  25559040ll    // 33280*768
#define CAT_LEN  38141952ll    // 49664*768
#define MEM_LEN  6291456ll     // 128*12*64*64 (f32, in d_out)

#define SPS  288               // sigmaT/wT row stride (keys padded 260->288)
#define SWT_LEN 28311552ll     // 1536*64*288

// bf16 weights: [qkv_w | memk_w | memv_w | proj_w]
#define WOFF_QKV  0ll
#define WOFF_MEMK 1769472ll
#define WOFF_MEMV 2359296ll
#define WOFF_PROJ 2949120ll
__device__ __align__(16) u16 g_wbf[3538944];

__device__ __forceinline__ float bf2f(u16 u) {
    union { unsigned int i; float f; } v; v.i = ((unsigned int)u) << 16; return v.f;
}
__device__ __forceinline__ u16 f2bf(float f) {
    union { float f; unsigned int i; } v; v.f = f;
    unsigned int r = v.i + 0x7fffu + ((v.i >> 16) & 1u);
    return (u16)(r >> 16);
}
__device__ __forceinline__ float elu1(float x) { return x > 0.f ? x + 1.f : __expf(x); }

__device__ __forceinline__ void gload_lds16(const u16* g, u16* l) {
    __builtin_amdgcn_global_load_lds(
        (const __attribute__((address_space(1))) unsigned int*)g,
        (__attribute__((address_space(3))) unsigned int*)l, 16, 0, 0);
}

// ---------------------------------------------------------------------------
// f32 -> bf16 converters
// ---------------------------------------------------------------------------
__global__ __launch_bounds__(256) void convert_bf16(
    const float* __restrict__ src, u16* __restrict__ dst, long long n)
{
    long long i0 = ((long long)blockIdx.x * 256 + threadIdx.x) * 8;
    long long stride = (long long)gridDim.x * 256 * 8;
    for (long long i = i0; i < n; i += stride) {
        float4 a = *(const float4*)(src + i);
        float4 b = *(const float4*)(src + i + 4);
        ushort4 u1; u1.x = f2bf(a.x); u1.y = f2bf(a.y); u1.z = f2bf(a.z); u1.w = f2bf(a.w);
        ushort4 u2; u2.x = f2bf(b.x); u2.y = f2bf(b.y); u2.z = f2bf(b.z); u2.w = f2bf(b.w);
        *(ushort4*)(dst + i)     = u1;
        *(ushort4*)(dst + i + 4) = u2;
    }
}

__global__ __launch_bounds__(256) void convert_wbf(
    const float* __restrict__ src, long long dst_off, long long n)
{
    u16* dst = g_wbf + dst_off;
    long long i0 = ((long long)blockIdx.x * 256 + threadIdx.x) * 8;
    long long stride = (long long)gridDim.x * 256 * 8;
    for (long long i = i0; i < n; i += stride) {
        float4 a = *(const float4*)(src + i);
        float4 b = *(const float4*)(src + i + 4);
        ushort4 u1; u1.x = f2bf(a.x); u1.y = f2bf(a.y); u1.z = f2bf(a.z); u1.w = f2bf(a.w);
        ushort4 u2; u2.x = f2bf(b.x); u2.y = f2bf(b.y); u2.z = f2bf(b.z); u2.w = f2bf(b.w);
        *(ushort4*)(dst + i)     = u1;
        *(ushort4*)(dst + i + 4) = u2;
    }
}

// ---------------------------------------------------------------------------
// memT[bh][dout][din] = bf16(mem[bh][din][dout])
// ---------------------------------------------------------------------------
__global__ __launch_bounds__(256) void memT_kernel(
    const float* __restrict__ memin, u16* __restrict__ memT)
{
    __shared__ float ml[64 * 65];
    int bh = blockIdx.x, t = threadIdx.x;
    const float* src = memin + (long long)bh * 4096;
#pragma unroll
    for (int i = 0; i < 16; i++) {
        int idx = i * 256 + t;
        ml[(idx >> 6) * 65 + (idx & 63)] = src[idx];
    }
    __syncthreads();
    u16* dst = memT + (long long)bh * 4096;
#pragma unroll
    for (int i = 0; i < 16; i++) {
        int o = i * 256 + t;
        int dout = o >> 6, din = o & 63;
        dst[o] = f2bf(ml[din * 65 + dout]);
    }
}

// ---------------------------------------------------------------------------
// MFMA GEMM v2: C = A @ W^T + bias, K=768. 128x128 tile, BK=32, 256 thr.
// global_load_lds staging (linear LDS), involutive slot swizzle
// (phys = log ^ (row&3), applied to global src addr AND frag reads),
// 1-D grid with bijective XCD swizzle, LDS-staged coalesced epilogue.
// ---------------------------------------------------------------------------
template<int CF32>
__global__ __launch_bounds__(256) void gemm_mfma(
    const u16* __restrict__ A, long long off0, int rows_per_b,
    long long stride_b, long long stride_r,
    long long w_off, const float* __restrict__ bias,
    void* __restrict__ Cv, int Nout, int nbx)
{
    __shared__ __align__(16) u16 lds[2][2][4096];   // [buf][A=0/B=1][128*32]

    const u16* W = g_wbf + w_off;
    int t = threadIdx.x;

    // XCD swizzle: consecutive new-ids share the A-row-block -> same XCD L2
    int wg = blockIdx.x;
    wg = (wg & 7) * ((int)gridDim.x >> 3) + (wg >> 3);
    int m0 = (wg / nbx) * 128;
    int n0 = (wg % nbx) * 128;

    int lane = t & 63, w = t >> 6;
    int w512 = w * 512;

    // staging: thread t owns linear LDS elems t*8 of each 64-row half.
    // physical slot (t&3) holds logical k-chunk (t&3)^(srow&3).
    int srow  = t >> 2;
    int scol  = (((t & 3) ^ (srow & 3))) * 8;
    long long aoff0, aoff1;
    {
        int g1 = m0 + srow, g2 = g1 + 64;
        int b1 = g1 / rows_per_b, j1 = g1 - b1 * rows_per_b;
        int b2 = g2 / rows_per_b, j2 = g2 - b2 * rows_per_b;
        aoff0 = off0 + (long long)b1 * stride_b + (long long)j1 * stride_r + scol;
        aoff1 = off0 + (long long)b2 * stride_b + (long long)j2 * stride_r + scol;
    }
    const u16* wp0 = W + (long long)(n0 + srow) * 768 + scol;
    const u16* wp1 = W + (long long)(n0 + srow + 64) * 768 + scol;

    // fragment read offsets: row = base+lr, slot = kg ^ (lr&3)
    int lr = lane & 15, kg = lane >> 4;
    int wm = w >> 1, wn = w & 1;
    int aslot = (kg ^ (lr & 3)) * 8;
    int abase = (wm * 64 + lr) * 32 + aslot;
    int bbase = (wn * 64 + lr) * 32 + aslot;

    vf4 acc[4][4];
#pragma unroll
    for (int i = 0; i < 4; i++)
#pragma unroll
        for (int j = 0; j < 4; j++) acc[i][j] = vf4{0.f, 0.f, 0.f, 0.f};

    auto stage = [&](int buf, int kt) {
        gload_lds16(A + aoff0 + kt, &lds[buf][0][w512]);
        gload_lds16(A + aoff1 + kt, &lds[buf][0][2048 + w512]);
        gload_lds16(wp0 + kt,       &lds[buf][1][w512]);
        gload_lds16(wp1 + kt,       &lds[buf][1][2048 + w512]);
    };

    stage(0, 0);
    __syncthreads();          // barrier drains vmcnt -> tile 0 ready

    int cur = 0;
    for (int kt = 0; kt < 768; kt += 32) {
        if (kt != 736) stage(cur ^ 1, kt + 32);

        vbf8 af[4], bf[4];
#pragma unroll
        for (int f = 0; f < 4; f++) {
            af[f] = *(const vbf8*)&lds[cur][0][abase + f * 512];
            bf[f] = *(const vbf8*)&lds[cur][1][bbase + f * 512];
        }
#pragma unroll
        for (int i = 0; i < 4; i++)
#pragma unroll
            for (int j = 0; j < 4; j++)
                acc[i][j] = __builtin_amdgcn_mfma_f32_16x16x32_bf16(
                    af[i], bf[j], acc[i][j], 0, 0, 0);

        __syncthreads();      // staged buf ready; reads of cur done
        cur ^= 1;
    }

    // ---- epilogue via LDS (coalesced global stores) ----
    if (!CF32) {
        u16* ct = &lds[0][0][0];   // 16384 u16 = 32 KB = full 128x128 bf16
#pragma unroll
        for (int i = 0; i < 4; i++)
#pragma unroll
            for (int j = 0; j < 4; j++) {
                int col = wn * 64 + j * 16 + lr;
                float bb = bias[n0 + col];
#pragma unroll
                for (int r = 0; r < 4; r++)
                    ct[(wm * 64 + i * 16 + kg * 4 + r) * 128 + col] =
                        f2bf(acc[i][j][r] + bb);
            }
        __syncthreads();
        int col0 = (t & 15) * 8;
#pragma unroll
        for (int rr = 0; rr < 8; rr++) {
            int row_l = rr * 16 + (t >> 4);
            vbf8 v = *(const vbf8*)&ct[row_l * 128 + col0];
            *(vbf8*)((u16*)Cv + (long long)(m0 + row_l) * Nout + n0 + col0) = v;
        }
    } else {
        float* cf = (float*)&lds[0][0][0];  // 8192 f32 = 32 KB = 64x128 half
#pragma unroll
        for (int p = 0; p < 2; p++) {
            if (wm == p) {
#pragma unroll
                for (int i = 0; i < 4; i++)
#pragma unroll
                    for (int j = 0; j < 4; j++) {
                        int col = wn * 64 + j * 16 + lr;
                        float bb = bias[n0 + col];
#pragma unroll
                        for (int r = 0; r < 4; r++)
                            cf[(i * 16 + kg * 4 + r) * 128 + col] =
                                acc[i][j][r] + bb;
                    }
            }
            __syncthreads();
            int col0 = (t & 15) * 8;
#pragma unroll
            for (int rr = 0; rr < 4; rr++) {
                int row_l = rr * 16 + (t >> 4);
                float4 v0 = *(const float4*)&cf[row_l * 128 + col0];
                float4 v1 = *(const float4*)&cf[row_l * 128 + col0 + 4];
                float* dst = (float*)Cv + (long long)(m0 + p * 64 + row_l) * Nout + n0 + col0;
                *(float4*)dst = v0;
                *(float4*)(dst + 4) = v1;
            }
            __syncthreads();
        }
    }
}

// ---------------------------------------------------------------------------
// attn_s_mfma (unchanged)
// ---------------------------------------------------------------------------
#define SKP 416
#define VTS 424
__global__ __launch_bounds__(512) void attn_s_mfma(
    const u16* __restrict__ qkv, const u16* __restrict__ memT,
    const float* __restrict__ zin, const float* __restrict__ betas,
    u16* __restrict__ concat)
{
    __shared__ __align__(16) u16 Kl[SKP * 64];
    __shared__ __align__(16) u16 Vt[64 * VTS];
    __shared__ __align__(16) u16 Pl[8][16 * 40];
    __shared__ float red[8][16];

    int bh = blockIdx.x;
    int b = bh / H_, h = bh % H_;
    int t = threadIdx.x, lane = t & 63, w = t >> 6;
    int lr = lane & 15, q4 = lane >> 4;

    {
        int key0 = t >> 3;
        int d0 = (t & 7) * 8;
        for (int kp = 0; kp < SKP; kp += 64) {
            int key = kp + key0;
            if (key < SKP) {
                vbf8 kv, vv;
#pragma unroll
                for (int u = 0; u < 8; u++) { ((short*)&kv)[u] = 0; ((short*)&vv)[u] = 0; }
                if (key < N_) {
                    const u16* base = qkv + ((long long)(b * N_ + key)) * K3 + h * D_;
                    kv = *(const vbf8*)(base + C_ + d0);
                    vv = *(const vbf8*)(base + 2 * C_ + d0);
                }
                *(vbf8*)((char*)Kl + ((key * 128 + d0 * 2) ^ ((key & 7) << 4))) = kv;
#pragma unroll
                for (int u = 0; u < 8; u++) Vt[(d0 + u) * VTS + key] = ((u16*)&vv)[u];
            }
        }
    }
    __syncthreads();

    const float* zp = zin + bh * 64;
    const u16* mtb = memT + (long long)bh * 4096;

    for (int s = w; s < 17; s += 8) {
        int qtok = NT + s * 16 + lr;
        if (qtok > N_ - 1) qtok = N_ - 1;
        const u16* qbase = qkv + ((long long)(b * N_ + qtok)) * K3 + h * D_;
        vbf8 qf0 = *(const vbf8*)(qbase + q4 * 8);
        vbf8 qf1 = *(const vbf8*)(qbase + 32 + q4 * 8);

        float m[4], l[4];
        vf4 accO[4];
#pragma unroll
        for (int r = 0; r < 4; r++) { m[r] = -1e30f; l[r] = 0.f; }
#pragma unroll
        for (int dc = 0; dc < 4; dc++) accO[dc] = vf4{0.f, 0.f, 0.f, 0.f};

        for (int kt = 0; kt < 13; kt++) {
            int kvalid = N_ - kt * 32; if (kvalid > 32) kvalid = 32;

            vf4 S[2];
#pragma unroll
            for (int ks = 0; ks < 2; ks++) {
                int krow = kt * 32 + ks * 16 + lr;
                int swz = (krow & 7) << 4;
                vbf8 b0 = *(const vbf8*)((char*)Kl + ((krow * 128 + q4 * 16) ^ swz));
                vbf8 b1 = *(const vbf8*)((char*)Kl + ((krow * 128 + 64 + q4 * 16) ^ swz));
                vf4 z4 = vf4{0.f, 0.f, 0.f, 0.f};
                vf4 sv = __builtin_amdgcn_mfma_f32_16x16x32_bf16(qf0, b0, z4, 0, 0, 0);
                sv = __builtin_amdgcn_mfma_f32_16x16x32_bf16(qf1, b1, sv, 0, 0, 0);
                bool inv = (ks * 16 + lr) >= kvalid;
#pragma unroll
                for (int r = 0; r < 4; r++)
                    S[ks][r] = inv ? -1e30f : sv[r] * 0.125f;
            }

            float tm[4], ts[4], corr[4];
#pragma unroll
            for (int r = 0; r < 4; r++) tm[r] = fmaxf(S[0][r], S[1][r]);
#pragma unroll
            for (int off = 1; off <= 8; off <<= 1)
#pragma unroll
                for (int r = 0; r < 4; r++) tm[r] = fmaxf(tm[r], __shfl_xor(tm[r], off));
#pragma unroll
            for (int r = 0; r < 4; r++) {
                float nm = fmaxf(m[r], tm[r]);
                corr[r] = __expf(m[r] - nm);
                m[r] = nm;
            }
#pragma unroll
            for (int ks = 0; ks < 2; ks++)
#pragma unroll
                for (int r = 0; r < 4; r++) S[ks][r] = __expf(S[ks][r] - m[r]);
#pragma unroll
            for (int r = 0; r < 4; r++) ts[r] = S[0][r] + S[1][r];
#pragma unroll
            for (int off = 1; off <= 8; off <<= 1)
#pragma unroll
                for (int r = 0; r < 4; r++) ts[r] += __shfl_xor(ts[r], off);
#pragma unroll
            for (int r = 0; r < 4; r++) l[r] = l[r] * corr[r] + ts[r];
#pragma unroll
            for (int dc = 0; dc < 4; dc++)
#pragma unroll
                for (int r = 0; r < 4; r++) accO[dc][r] *= corr[r];

            {
                u16* pw = Pl[w];
#pragma unroll
                for (int ks = 0; ks < 2; ks++)
#pragma unroll
                    for (int r = 0; r < 4; r++)
                        pw[(q4 * 4 + r) * 40 + ks * 16 + lr] = f2bf(S[ks][r]);
            }
            vbf8 pf = *(const vbf8*)&Pl[w][lr * 40 + q4 * 8];

#pragma unroll
            for (int dc = 0; dc < 4; dc++) {
                vbf8 vf_ = *(const vbf8*)&Vt[(dc * 16 + lr) * VTS + kt * 32 + q4 * 8];
                accO[dc] = __builtin_amdgcn_mfma_f32_16x16x32_bf16(pf, vf_, accO[dc], 0, 0, 0);
            }
        }

        float invl[4];
#pragma unroll
        for (int r = 0; r < 4; r++) invl[r] = 1.f / l[r];

        vbf8 sq0, sq1;
        float dpart = 0.f;
#pragma unroll
        for (int j = 0; j < 8; j++) {
            float s0 = elu1(bf2f(((u16*)&qf0)[j]));
            float s1 = elu1(bf2f(((u16*)&qf1)[j]));
            ((u16*)&sq0)[j] = f2bf(s0);
            ((u16*)&sq1)[j] = f2bf(s1);
            dpart += s0 * zp[q4 * 8 + j] + s1 * zp[32 + q4 * 8 + j];
        }
        dpart += __shfl_xor(dpart, 16);
        dpart += __shfl_xor(dpart, 32);
        if (q4 == 0) red[w][lr] = dpart;

        vf4 am[4];
#pragma unroll
        for (int dc = 0; dc < 4; dc++) {
            vbf8 b0 = *(const vbf8*)(mtb + (dc * 16 + lr) * 64 + q4 * 8);
            vbf8 b1 = *(const vbf8*)(mtb + (dc * 16 + lr) * 64 + 32 + q4 * 8);
            vf4 z4 = vf4{0.f, 0.f, 0.f, 0.f};
            vf4 a = __builtin_amdgcn_mfma_f32_16x16x32_bf16(sq0, b0, z4, 0, 0, 0);
            am[dc] = __builtin_amdgcn_mfma_f32_16x16x32_bf16(sq1, b1, a, 0, 0, 0);
        }
        float den[4];
#pragma unroll
        for (int r = 0; r < 4; r++) den[r] = 1.f / red[w][q4 * 4 + r];

#pragma unroll
        for (int dc = 0; dc < 4; dc++) {
            float bb = betas[h * D_ + dc * 16 + lr];
            float beta = 1.f / (1.f + __expf(-bb));
#pragma unroll
            for (int r = 0; r < 4; r++) {
                int qs = s * 16 + q4 * 4 + r;
                if (qs < NS) {
                    float o = beta * (am[dc][r] * den[r]) +
                              (1.f - beta) * (accO[dc][r] * invl[r]);
                    concat[((long long)(b * N_ + NT + qs)) * C_ + h * D_ + dc * 16 + lr] = f2bf(o);
                }
            }
        }
    }
}

// ---------------------------------------------------------------------------
// attn_mt_mfma (unchanged)
// ---------------------------------------------------------------------------
#define MTS 136
__global__ __launch_bounds__(512) void attn_mt_mfma(
    const u16* __restrict__ qkv, u16* __restrict__ concat)
{
    __shared__ __align__(16) u16 Kl[NT * 64];
    __shared__ __align__(16) u16 Vt[64 * MTS];
    __shared__ __align__(16) u16 Pl[8][16 * 40];

    int bh = blockIdx.x;
    int b = bh / H_, h = bh % H_;
    int t = threadIdx.x, lane = t & 63, w = t >> 6;
    int lr = lane & 15, q4 = lane >> 4;

    {
        int key0 = t >> 3;
        int d0 = (t & 7) * 8;
#pragma unroll
        for (int kp = 0; kp < NT; kp += 64) {
            int key = kp + key0;
            const u16* base = qkv + ((long long)(b * N_ + key)) * K3 + h * D_;
            vbf8 kv = *(const vbf8*)(base + C_ + d0);
            vbf8 vv = *(const vbf8*)(base + 2 * C_ + d0);
            *(vbf8*)((char*)Kl + ((key * 128 + d0 * 2) ^ ((key & 7) << 4))) = kv;
#pragma unroll
            for (int u = 0; u < 8; u++) Vt[(d0 + u) * MTS + key] = ((u16*)&vv)[u];
        }
    }
    __syncthreads();

    int qtok = w * 16 + lr;
    const u16* qbase = qkv + ((long long)(b * N_ + qtok)) * K3 + h * D_;
    vbf8 qf0 = *(const vbf8*)(qbase + q4 * 8);
    vbf8 qf1 = *(const vbf8*)(qbase + 32 + q4 * 8);

    float m[4], l[4];
    vf4 accO[4];
#pragma unroll
    for (int r = 0; r < 4; r++) { m[r] = -1e30f; l[r] = 0.f; }
#pragma unroll
    for (int dc = 0; dc < 4; dc++) accO[dc] = vf4{0.f, 0.f, 0.f, 0.f};

#pragma unroll
    for (int kt = 0; kt < 4; kt++) {
        vf4 S[2];
#pragma unroll
        for (int ks = 0; ks < 2; ks++) {
            int krow = kt * 32 + ks * 16 + lr;
            int swz = (krow & 7) << 4;
            vbf8 b0 = *(const vbf8*)((char*)Kl + ((krow * 128 + q4 * 16) ^ swz));
            vbf8 b1 = *(const vbf8*)((char*)Kl + ((krow * 128 + 64 + q4 * 16) ^ swz));
            vf4 z4 = vf4{0.f, 0.f, 0.f, 0.f};
            vf4 sv = __builtin_amdgcn_mfma_f32_16x16x32_bf16(qf0, b0, z4, 0, 0, 0);
            sv = __builtin_amdgcn_mfma_f32_16x16x32_bf16(qf1, b1, sv, 0, 0, 0);
#pragma unroll
            for (int r = 0; r < 4; r++) S[ks][r] = sv[r] * 0.125f;
        }

        float tm[4], ts[4], corr[4];
#pragma unroll
        for (int r = 0; r < 4; r++) tm[r] = fmaxf(S[0][r], S[1][r]);
#pragma unroll
        for (int off = 1; off <= 8; off <<= 1)
#pragma unroll
            for (int r = 0; r < 4; r++) tm[r] = fmaxf(tm[r], __shfl_xor(tm[r], off));
#pragma unroll
        for (int r = 0; r < 4; r++) {
            float nm = fmaxf(m[r], tm[r]);
            corr[r] = __expf(m[r] - nm);
            m[r] = nm;
        }
#pragma unroll
        for (int ks = 0; ks < 2; ks++)
#pragma unroll
            for (int r = 0; r < 4; r++) S[ks][r] = __expf(S[ks][r] - m[r]);
#pragma unroll
        for (int r = 0; r < 4; r++) ts[r] = S[0][r] + S[1][r];
#pragma unroll
        for (int off = 1; off <= 8; off <<= 1)
#pragma unroll
            for (int r = 0; r < 4; r++) ts[r] += __shfl_xor(ts[r], off);
#pragma unroll
        for (int r = 0; r < 4; r++) l[r] = l[r] * corr[r] + ts[r];
#pragma unroll
        for (int dc = 0; dc < 4; dc++)
#pragma unroll
            for (int r = 0; r < 4; r++) accO[dc][r] *= corr[r];

        {
            u16* pw = Pl[w];
#pragma unroll
            for (int ks = 0; ks < 2; ks++)
#pragma unroll
                for (int r = 0; r < 4; r++)
                    pw[(q4 * 4 + r) * 40 + ks * 16 + lr] = f2bf(S[ks][r]);
        }
        vbf8 pf = *(const vbf8*)&Pl[w][lr * 40 + q4 * 8];

#pragma unroll
        for (int dc = 0; dc < 4; dc++) {
            vbf8 vf_ = *(const vbf8*)&Vt[(dc * 16 + lr) * MTS + kt * 32 + q4 * 8];
            accO[dc] = __builtin_amdgcn_mfma_f32_16x16x32_bf16(pf, vf_, accO[dc], 0, 0, 0);
        }
    }

    float invl[4];
#pragma unroll
    for (int r = 0; r < 4; r++) invl[r] = 1.f / l[r];

    int qt0 = w * 16;
#pragma unroll
    for (int dc = 0; dc < 4; dc++)
#pragma unroll
        for (int r = 0; r < 4; r++) {
            int row = qt0 + q4 * 4 + r;
            concat[((long long)(b * N_ + row)) * C_ + h * D_ + dc * 16 + lr] =
                f2bf(accO[dc][r] * invl[r]);
        }
}

// ---------------------------------------------------------------------------
// sigma_pred_mfma (unchanged)
// ---------------------------------------------------------------------------
__global__ __launch_bounds__(512) void sigma_pred_mfma(
    const u16* __restrict__ ksm, const u16* __restrict__ vsm,
    const u16* __restrict__ memT, const float* __restrict__ zin,
    u16* __restrict__ sigT, u16* __restrict__ wT,
    float* __restrict__ z_out)
{
    __shared__ u16 sigLDS[8][64][18];
    __shared__ u16 wLDS[8][64][18];
    __shared__ float red[8][16];
    __shared__ float zpart[8][64];
    __shared__ float zlds[64];

    int bh = blockIdx.x;
    int b = bh / H_, h = bh % H_;
    int t = threadIdx.x, lane = t & 63, w = t >> 6;
    int lr = lane & 15, q4 = lane >> 4;

    if (t < 64) zlds[t] = zin[bh * 64 + t];
    __syncthreads();

    const u16* mtb = memT + (long long)bh * 4096;
    float zacc[16];
#pragma unroll
    for (int j = 0; j < 16; j++) zacc[j] = 0.f;

    for (int s = w; s < 18; s += 8) {
        int n0 = s * 16;
        int nrow = n0 + lr;
        bool vrow = nrow < NS;
        int nclamp = vrow ? nrow : NS - 1;
        const u16* kbase = ksm + ((long long)(b * NS + nclamp)) * C_ + h * D_;
        vbf8 k0 = *(const vbf8*)(kbase + q4 * 8);
        vbf8 k1 = *(const vbf8*)(kbase + 32 + q4 * 8);

        vbf8 sq0, sq1;
        float dpart = 0.f;
#pragma unroll
        for (int j = 0; j < 8; j++) {
            float s0 = vrow ? elu1(bf2f(((u16*)&k0)[j])) : 0.f;
            float s1 = vrow ? elu1(bf2f(((u16*)&k1)[j])) : 0.f;
            ((u16*)&sq0)[j] = f2bf(s0);
            ((u16*)&sq1)[j] = f2bf(s1);
            zacc[j]     += s0;
            zacc[8 + j] += s1;
            dpart += s0 * zlds[q4 * 8 + j] + s1 * zlds[32 + q4 * 8 + j];
        }
        dpart += __shfl_xor(dpart, 16);
        dpart += __shfl_xor(dpart, 32);
        if (q4 == 0) red[w][lr] = dpart;

#pragma unroll
        for (int j = 0; j < 8; j++) {
            sigLDS[w][q4 * 8 + j][lr]      = ((u16*)&sq0)[j];
            sigLDS[w][32 + q4 * 8 + j][lr] = ((u16*)&sq1)[j];
        }

        vf4 am[4];
#pragma unroll
        for (int dc = 0; dc < 4; dc++) {
            vbf8 b0 = *(const vbf8*)(mtb + (dc * 16 + lr) * 64 + q4 * 8);
            vbf8 b1 = *(const vbf8*)(mtb + (dc * 16 + lr) * 64 + 32 + q4 * 8);
            vf4 z4 = vf4{0.f, 0.f, 0.f, 0.f};
            vf4 a = __builtin_amdgcn_mfma_f32_16x16x32_bf16(sq0, b0, z4, 0, 0, 0);
            am[dc] = __builtin_amdgcn_mfma_f32_16x16x32_bf16(sq1, b1, a, 0, 0, 0);
        }
        float rden[4];
#pragma unroll
        for (int r = 0; r < 4; r++) rden[r] = 1.f / red[w][q4 * 4 + r];

#pragma unroll
        for (int dc = 0; dc < 4; dc++) {
            int e = dc * 16 + lr;
#pragma unroll
            for (int r = 0; r < 4; r++) {
                int nn = n0 + q4 * 4 + r;
                float wv = 0.f;
                if (nn < NS) {
                    float pv = am[dc][r] * rden[r];
                    wv = bf2f(vsm[((long long)(b * NS + nn)) * C_ + h * D_ + e]) - pv;
                }
                wLDS[w][e][q4 * 4 + r] = f2bf(wv);
            }
        }

        {
            long long dst = ((long long)bh * 64 + lane) * SPS + n0;
            unsigned pk[8];
#pragma unroll
            for (int j2 = 0; j2 < 8; j2++)
                pk[j2] = (unsigned)sigLDS[w][lane][2 * j2] |
                         ((unsigned)sigLDS[w][lane][2 * j2 + 1] << 16);
            *(uint4*)(sigT + dst)     = uint4{pk[0], pk[1], pk[2], pk[3]};
            *(uint4*)(sigT + dst + 8) = uint4{pk[4], pk[5], pk[6], pk[7]};
#pragma unroll
            for (int j2 = 0; j2 < 8; j2++)
                pk[j2] = (unsigned)wLDS[w][lane][2 * j2] |
                         ((unsigned)wLDS[w][lane][2 * j2 + 1] << 16);
            *(uint4*)(wT + dst)     = uint4{pk[0], pk[1], pk[2], pk[3]};
            *(uint4*)(wT + dst + 8) = uint4{pk[4], pk[5], pk[6], pk[7]};
        }
    }

#pragma unroll
    for (int off = 1; off <= 8; off <<= 1)
#pragma unroll
        for (int j = 0; j < 16; j++) zacc[j] += __shfl_xor(zacc[j], off);
    if (lr == 0) {
#pragma unroll
        for (int j = 0; j < 8; j++) {
            zpart[w][q4 * 8 + j]      = zacc[j];
            zpart[w][32 + q4 * 8 + j] = zacc[8 + j];
        }
    }
    __syncthreads();
    if (t < 64) {
        float tot = 0.f;
#pragma unroll
        for (int ww = 0; ww < 8; ww++) tot += zpart[ww][t];
        z_out[bh * 64 + t] = zlds[t] + tot;
    }
}

// ---------------------------------------------------------------------------
// mem_update_mfma (unchanged)
// ---------------------------------------------------------------------------
__global__ __launch_bounds__(64) void mem_update_mfma(
    const u16* __restrict__ sigT, const u16* __restrict__ wT,
    const float* __restrict__ memin, float* __restrict__ mem_out)
{
    int bh = blockIdx.x;
    int lane = threadIdx.x;
    int lr = lane & 15, q4 = lane >> 4;

    const u16* sb = sigT + (long long)bh * 64 * SPS;
    const u16* wb = wT   + (long long)bh * 64 * SPS;

    vf4 acc[4][4];
#pragma unroll
    for (int i = 0; i < 4; i++)
#pragma unroll
        for (int j = 0; j < 4; j++) acc[i][j] = vf4{0.f, 0.f, 0.f, 0.f};

    for (int kt = 0; kt < SPS; kt += 32) {
        vbf8 af[4], bf[4];
#pragma unroll
        for (int i = 0; i < 4; i++)
            af[i] = *(const vbf8*)(sb + (long long)(i * 16 + lr) * SPS + kt + q4 * 8);
#pragma unroll
        for (int j = 0; j < 4; j++)
            bf[j] = *(const vbf8*)(wb + (long long)(j * 16 + lr) * SPS + kt + q4 * 8);
#pragma unroll
        for (int i = 0; i < 4; i++)
#pragma unroll
            for (int j = 0; j < 4; j++)
                acc[i][j] = __builtin_amdgcn_mfma_f32_16x16x32_bf16(
                    af[i], bf[j], acc[i][j], 0, 0, 0);
    }

    long long mb = (long long)bh * 4096;
#pragma unroll
    for (int i = 0; i < 4; i++)
#pragma unroll
        for (int j = 0; j < 4; j++)
#pragma unroll
            for (int r = 0; r < 4; r++) {
                int d = i * 16 + q4 * 4 + r;
                int e = j * 16 + lr;
                mem_out[mb + d * 64 + e] = memin[mb + d * 64 + e] + acc[i][j][r];
            }
}

// ---------------------------------------------------------------------------
extern "C" void kernel_launch(void* const* d_in, const int* in_sizes, int n_in,
                              void* d_out, int out_size, void* d_ws, size_t ws_size,
                              hipStream_t stream)
{
    const float* x      = (const float*)d_in[0];
    const float* mem    = (const float*)d_in[1];
    const float* z      = (const float*)d_in[2];
    const float* qkv_w  = (const float*)d_in[3];
    const float* qkv_b  = (const float*)d_in[4];
    const float* proj_w = (const float*)d_in[5];
    const float* proj_b = (const float*)d_in[6];
    const float* memk_w = (const float*)d_in[7];
    const float* memk_b = (const float*)d_in[8];
    const float* memv_w = (const float*)d_in[9];
    const float* memv_b = (const float*)d_in[10];
    const float* betas  = (const float*)d_in[11];

    u16* ws     = (u16*)d_ws;
    u16* qkv    = ws;
    u16* ksm    = qkv + QKV_LEN;
    u16* vsm    = ksm + KSM_LEN;
    u16* concat = vsm + KSM_LEN;      // doubles as x_bf before attn writes it

    float* out     = (float*)d_out;
    float* mem_out = out + CAT_LEN;
    float* z_out   = mem_out + MEM_LEN;

    u16* x_bf = concat;               // alias: dead after qkv GEMM
    u16* memT = (u16*)mem_out;        // scratch in mem_out region (overwritten last)
    u16* sigT = qkv;                  // alias: qkv dead after attn kernels
    u16* wT   = qkv + SWT_LEN;

    // 0. conversions
    convert_bf16<<<dim3(2048), dim3(256), 0, stream>>>(x, x_bf, CAT_LEN);
    convert_wbf<<<dim3(864), dim3(256), 0, stream>>>(qkv_w,  WOFF_QKV,  1769472ll);
    convert_wbf<<<dim3(288), dim3(256), 0, stream>>>(memk_w, WOFF_MEMK, 589824ll);
    convert_wbf<<<dim3(288), dim3(256), 0, stream>>>(memv_w, WOFF_MEMV, 589824ll);
    convert_wbf<<<dim3(288), dim3(256), 0, stream>>>(proj_w, WOFF_PROJ, 589824ll);
    memT_kernel<<<dim3(B_ * H_), dim3(256), 0, stream>>>(mem, memT);

    // 1. qkv = x @ qkv_w^T + qkv_b   (grid 18 x 388 = 6984, %8 == 0)
    gemm_mfma<0><<<dim3(6984), dim3(256), 0, stream>>>(
        x_bf, 0ll, 49664, 0ll, 768ll, WOFF_QKV, qkv_b, qkv, K3, 18);
    // 2. k_s_mem                      (grid 6 x 260 = 1560)
    gemm_mfma<0><<<dim3(1560), dim3(256), 0, stream>>>(
        qkv, (long long)(NT * K3 + C_), NS, (long long)N_ * K3, (long long)K3,
        WOFF_MEMK, memk_b, ksm, C_, 6);
    // 3. v_s_mem
    gemm_mfma<0><<<dim3(1560), dim3(256), 0, stream>>>(
        qkv, (long long)(NT * K3 + 2 * C_), NS, (long long)N_ * K3, (long long)K3,
        WOFF_MEMV, memv_b, vsm, C_, 6);
    // 4. spatial attention (+ mem readout + blend) -> concat[:, NT:]
    attn_s_mfma<<<dim3(B_ * H_), dim3(512), 0, stream>>>(
        qkv, memT, z, betas, concat);
    // 5. token/token attention -> concat[:, :NT]
    attn_mt_mfma<<<dim3(B_ * H_), dim3(512), 0, stream>>>(qkv, concat);
    // 6. sigma/pred -> sigT/wT (overwrites qkv region) + z_new
    sigma_pred_mfma<<<dim3(B_ * H_), dim3(512), 0, stream>>>(
        ksm, vsm, memT, z, sigT, wT, z_out);
    // 7. mem_new = mem + sigT @ wT^T (overwrites memT scratch)
    mem_update_mfma<<<dim3(B_ * H_), dim3(64), 0, stream>>>(
        sigT, wT, mem, mem_out);
    // 8. out = concat @ proj_w^T + proj_b   (grid 6 x 388 = 2328)
    gemm_mfma<1><<<dim3(2328), dim3(256), 0, stream>>>(
        concat, 0ll, 49664, 0ll, 768ll, WOFF_PROJ, proj_b, out, C_, 6);
}

// Round 9
// 966.862 us; speedup vs baseline: 7.1941x; 1.0386x over previous
//
#include <hip/hip_runtime.h>

typedef unsigned short u16;
typedef __attribute__((ext_vector_type(8))) short  vbf8;   // 8 bf16 (4 VGPRs)
typedef __attribute__((ext_vector_type(4))) float  vf4;    // 4 f32 acc

#define B_   128
#define N_   388
#define NT   128
#define NS   260
#define C_   768
#define H_   12
#define D_   64
#define K3   2304   // 3*C

#define QKV_LEN  114425856ll   // 49664*2304  (bf16 ws)
#define KSM_LEN  25559040ll    // 33280*768
#define CAT_LEN  38141952ll    // 49664*768
#define MEM_LEN  6291456ll     // 128*12*64*64 (f32, in d_out)

#define SPS  288               // sigmaT/wT row stride (keys padded 260->288)
#define SWT_LEN 28311552ll     // 1536*64*288

// bf16 weights: [qkv_w | memk_w | memv_w | proj_w]
#define WOFF_QKV  0ll
#define WOFF_MEMK 1769472ll
#define WOFF_MEMV 2359296ll
#define WOFF_PROJ 2949120ll
__device__ __align__(16) u16 g_wbf[3538944];

__device__ __forceinline__ float bf2f(u16 u) {
    union { unsigned int i; float f; } v; v.i = ((unsigned int)u) << 16; return v.f;
}
__device__ __forceinline__ u16 f2bf(float f) {
    union { float f; unsigned int i; } v; v.f = f;
    unsigned int r = v.i + 0x7fffu + ((v.i >> 16) & 1u);
    return (u16)(r >> 16);
}
__device__ __forceinline__ float elu1(float x) { return x > 0.f ? x + 1.f : __expf(x); }

__device__ __forceinline__ void gload_lds16(const u16* g, u16* l) {
    __builtin_amdgcn_global_load_lds(
        (const __attribute__((address_space(1))) unsigned int*)g,
        (__attribute__((address_space(3))) unsigned int*)l, 16, 0, 0);
}

// ---------------------------------------------------------------------------
// f32 -> bf16 converters
// ---------------------------------------------------------------------------
__global__ __launch_bounds__(256) void convert_bf16(
    const float* __restrict__ src, u16* __restrict__ dst, long long n)
{
    long long i0 = ((long long)blockIdx.x * 256 + threadIdx.x) * 8;
    long long stride = (long long)gridDim.x * 256 * 8;
    for (long long i = i0; i < n; i += stride) {
        float4 a = *(const float4*)(src + i);
        float4 b = *(const float4*)(src + i + 4);
        ushort4 u1; u1.x = f2bf(a.x); u1.y = f2bf(a.y); u1.z = f2bf(a.z); u1.w = f2bf(a.w);
        ushort4 u2; u2.x = f2bf(b.x); u2.y = f2bf(b.y); u2.z = f2bf(b.z); u2.w = f2bf(b.w);
        *(ushort4*)(dst + i)     = u1;
        *(ushort4*)(dst + i + 4) = u2;
    }
}

__global__ __launch_bounds__(256) void convert_wbf(
    const float* __restrict__ src, long long dst_off, long long n)
{
    u16* dst = g_wbf + dst_off;
    long long i0 = ((long long)blockIdx.x * 256 + threadIdx.x) * 8;
    long long stride = (long long)gridDim.x * 256 * 8;
    for (long long i = i0; i < n; i += stride) {
        float4 a = *(const float4*)(src + i);
        float4 b = *(const float4*)(src + i + 4);
        ushort4 u1; u1.x = f2bf(a.x); u1.y = f2bf(a.y); u1.z = f2bf(a.z); u1.w = f2bf(a.w);
        ushort4 u2; u2.x = f2bf(b.x); u2.y = f2bf(b.y); u2.z = f2bf(b.z); u2.w = f2bf(b.w);
        *(ushort4*)(dst + i)     = u1;
        *(ushort4*)(dst + i + 4) = u2;
    }
}

// ---------------------------------------------------------------------------
// memT[bh][dout][din] = bf16(mem[bh][din][dout])
// ---------------------------------------------------------------------------
__global__ __launch_bounds__(256) void memT_kernel(
    const float* __restrict__ memin, u16* __restrict__ memT)
{
    __shared__ float ml[64 * 65];
    int bh = blockIdx.x, t = threadIdx.x;
    const float* src = memin + (long long)bh * 4096;
#pragma unroll
    for (int i = 0; i < 16; i++) {
        int idx = i * 256 + t;
        ml[(idx >> 6) * 65 + (idx & 63)] = src[idx];
    }
    __syncthreads();
    u16* dst = memT + (long long)bh * 4096;
#pragma unroll
    for (int i = 0; i < 16; i++) {
        int o = i * 256 + t;
        int dout = o >> 6, din = o & 63;
        dst[o] = f2bf(ml[din * 65 + dout]);
    }
}

// ---------------------------------------------------------------------------
// MFMA GEMM v2 (unchanged from round 8)
// ---------------------------------------------------------------------------
template<int CF32>
__global__ __launch_bounds__(256) void gemm_mfma(
    const u16* __restrict__ A, long long off0, int rows_per_b,
    long long stride_b, long long stride_r,
    long long w_off, const float* __restrict__ bias,
    void* __restrict__ Cv, int Nout, int nbx)
{
    __shared__ __align__(16) u16 lds[2][2][4096];

    const u16* W = g_wbf + w_off;
    int t = threadIdx.x;

    int wg = blockIdx.x;
    wg = (wg & 7) * ((int)gridDim.x >> 3) + (wg >> 3);
    int m0 = (wg / nbx) * 128;
    int n0 = (wg % nbx) * 128;

    int lane = t & 63, w = t >> 6;
    int w512 = w * 512;

    int srow  = t >> 2;
    int scol  = (((t & 3) ^ (srow & 3))) * 8;
    long long aoff0, aoff1;
    {
        int g1 = m0 + srow, g2 = g1 + 64;
        int b1 = g1 / rows_per_b, j1 = g1 - b1 * rows_per_b;
        int b2 = g2 / rows_per_b, j2 = g2 - b2 * rows_per_b;
        aoff0 = off0 + (long long)b1 * stride_b + (long long)j1 * stride_r + scol;
        aoff1 = off0 + (long long)b2 * stride_b + (long long)j2 * stride_r + scol;
    }
    const u16* wp0 = W + (long long)(n0 + srow) * 768 + scol;
    const u16* wp1 = W + (long long)(n0 + srow + 64) * 768 + scol;

    int lr = lane & 15, kg = lane >> 4;
    int wm = w >> 1, wn = w & 1;
    int aslot = (kg ^ (lr & 3)) * 8;
    int abase = (wm * 64 + lr) * 32 + aslot;
    int bbase = (wn * 64 + lr) * 32 + aslot;

    vf4 acc[4][4];
#pragma unroll
    for (int i = 0; i < 4; i++)
#pragma unroll
        for (int j = 0; j < 4; j++) acc[i][j] = vf4{0.f, 0.f, 0.f, 0.f};

    auto stage = [&](int buf, int kt) {
        gload_lds16(A + aoff0 + kt, &lds[buf][0][w512]);
        gload_lds16(A + aoff1 + kt, &lds[buf][0][2048 + w512]);
        gload_lds16(wp0 + kt,       &lds[buf][1][w512]);
        gload_lds16(wp1 + kt,       &lds[buf][1][2048 + w512]);
    };

    stage(0, 0);
    __syncthreads();

    int cur = 0;
    for (int kt = 0; kt < 768; kt += 32) {
        if (kt != 736) stage(cur ^ 1, kt + 32);

        vbf8 af[4], bf[4];
#pragma unroll
        for (int f = 0; f < 4; f++) {
            af[f] = *(const vbf8*)&lds[cur][0][abase + f * 512];
            bf[f] = *(const vbf8*)&lds[cur][1][bbase + f * 512];
        }
#pragma unroll
        for (int i = 0; i < 4; i++)
#pragma unroll
            for (int j = 0; j < 4; j++)
                acc[i][j] = __builtin_amdgcn_mfma_f32_16x16x32_bf16(
                    af[i], bf[j], acc[i][j], 0, 0, 0);

        __syncthreads();
        cur ^= 1;
    }

    if (!CF32) {
        u16* ct = &lds[0][0][0];
#pragma unroll
        for (int i = 0; i < 4; i++)
#pragma unroll
            for (int j = 0; j < 4; j++) {
                int col = wn * 64 + j * 16 + lr;
                float bb = bias[n0 + col];
#pragma unroll
                for (int r = 0; r < 4; r++)
                    ct[(wm * 64 + i * 16 + kg * 4 + r) * 128 + col] =
                        f2bf(acc[i][j][r] + bb);
            }
        __syncthreads();
        int col0 = (t & 15) * 8;
#pragma unroll
        for (int rr = 0; rr < 8; rr++) {
            int row_l = rr * 16 + (t >> 4);
            vbf8 v = *(const vbf8*)&ct[row_l * 128 + col0];
            *(vbf8*)((u16*)Cv + (long long)(m0 + row_l) * Nout + n0 + col0) = v;
        }
    } else {
        float* cf = (float*)&lds[0][0][0];
#pragma unroll
        for (int p = 0; p < 2; p++) {
            if (wm == p) {
#pragma unroll
                for (int i = 0; i < 4; i++)
#pragma unroll
                    for (int j = 0; j < 4; j++) {
                        int col = wn * 64 + j * 16 + lr;
                        float bb = bias[n0 + col];
#pragma unroll
                        for (int r = 0; r < 4; r++)
                            cf[(i * 16 + kg * 4 + r) * 128 + col] =
                                acc[i][j][r] + bb;
                    }
            }
            __syncthreads();
            int col0 = (t & 15) * 8;
#pragma unroll
            for (int rr = 0; rr < 4; rr++) {
                int row_l = rr * 16 + (t >> 4);
                float4 v0 = *(const float4*)&cf[row_l * 128 + col0];
                float4 v1 = *(const float4*)&cf[row_l * 128 + col0 + 4];
                float* dst = (float*)Cv + (long long)(m0 + p * 64 + row_l) * Nout + n0 + col0;
                *(float4*)dst = v0;
                *(float4*)(dst + 4) = v1;
            }
            __syncthreads();
        }
    }
}

// ---------------------------------------------------------------------------
// attn_s_mfma v2: full-row softmax (all 388 keys LDS-resident, so no online
// rescaling). Per strip: S[13][2] in regs -> one max pass -> one exp/sum
// pass -> 13 unnormalized-P PV MFMAs -> single invl scale. Q pre-scaled by
// 0.125 (exact in bf16). Only tile 12 (keys 388..415) needs masking.
// ---------------------------------------------------------------------------
#define SKP 416
#define VTS 424
__global__ __launch_bounds__(512) void attn_s_mfma(
    const u16* __restrict__ qkv, const u16* __restrict__ memT,
    const float* __restrict__ zin, const float* __restrict__ betas,
    u16* __restrict__ concat)
{
    __shared__ __align__(16) u16 Kl[SKP * 64];
    __shared__ __align__(16) u16 Vt[64 * VTS];
    __shared__ __align__(16) u16 Pl[8][16 * 40];
    __shared__ float red[8][16];

    int bh = blockIdx.x;
    int b = bh / H_, h = bh % H_;
    int t = threadIdx.x, lane = t & 63, w = t >> 6;
    int lr = lane & 15, q4 = lane >> 4;

    {
        int key0 = t >> 3;
        int d0 = (t & 7) * 8;
        for (int kp = 0; kp < SKP; kp += 64) {
            int key = kp + key0;
            if (key < SKP) {
                vbf8 kv, vv;
#pragma unroll
                for (int u = 0; u < 8; u++) { ((short*)&kv)[u] = 0; ((short*)&vv)[u] = 0; }
                if (key < N_) {
                    const u16* base = qkv + ((long long)(b * N_ + key)) * K3 + h * D_;
                    kv = *(const vbf8*)(base + C_ + d0);
                    vv = *(const vbf8*)(base + 2 * C_ + d0);
                }
                *(vbf8*)((char*)Kl + ((key * 128 + d0 * 2) ^ ((key & 7) << 4))) = kv;
#pragma unroll
                for (int u = 0; u < 8; u++) Vt[(d0 + u) * VTS + key] = ((u16*)&vv)[u];
            }
        }
    }
    __syncthreads();

    const float* zp = zin + bh * 64;
    const u16* mtb = memT + (long long)bh * 4096;

    for (int s = w; s < 17; s += 8) {
        int qtok = NT + s * 16 + lr;
        if (qtok > N_ - 1) qtok = N_ - 1;
        const u16* qbase = qkv + ((long long)(b * N_ + qtok)) * K3 + h * D_;
        vbf8 qf0 = *(const vbf8*)(qbase + q4 * 8);      // raw (epilogue sigma_q)
        vbf8 qf1 = *(const vbf8*)(qbase + 32 + q4 * 8);

        // pre-scaled Q for QK^T (0.125 = 2^-3 exact in bf16)
        vbf8 qs0, qs1;
#pragma unroll
        for (int j = 0; j < 8; j++) {
            ((u16*)&qs0)[j] = f2bf(bf2f(((u16*)&qf0)[j]) * 0.125f);
            ((u16*)&qs1)[j] = f2bf(bf2f(((u16*)&qf1)[j]) * 0.125f);
        }

        // ---- all S tiles into registers
        vf4 S[13][2];
#pragma unroll
        for (int kt = 0; kt < 13; kt++) {
#pragma unroll
            for (int ks = 0; ks < 2; ks++) {
                int krow = kt * 32 + ks * 16 + lr;
                int swz = (krow & 7) << 4;
                vbf8 b0 = *(const vbf8*)((char*)Kl + ((krow * 128 + q4 * 16) ^ swz));
                vbf8 b1 = *(const vbf8*)((char*)Kl + ((krow * 128 + 64 + q4 * 16) ^ swz));
                vf4 z4 = vf4{0.f, 0.f, 0.f, 0.f};
                vf4 sv = __builtin_amdgcn_mfma_f32_16x16x32_bf16(qs0, b0, z4, 0, 0, 0);
                S[kt][ks] = __builtin_amdgcn_mfma_f32_16x16x32_bf16(qs1, b1, sv, 0, 0, 0);
            }
        }
        // mask pad keys 388..415 (tile 12: valid only ks=0, lr<4)
#pragma unroll
        for (int ks = 0; ks < 2; ks++)
#pragma unroll
            for (int r = 0; r < 4; r++)
                if (ks * 16 + lr >= 4) S[12][ks][r] = -1e30f;

        // ---- one-shot softmax
        float mx[4];
#pragma unroll
        for (int r = 0; r < 4; r++) mx[r] = S[0][0][r];
#pragma unroll
        for (int kt = 0; kt < 13; kt++)
#pragma unroll
            for (int ks = 0; ks < 2; ks++)
#pragma unroll
                for (int r = 0; r < 4; r++) mx[r] = fmaxf(mx[r], S[kt][ks][r]);
#pragma unroll
        for (int off = 1; off <= 8; off <<= 1)
#pragma unroll
            for (int r = 0; r < 4; r++) mx[r] = fmaxf(mx[r], __shfl_xor(mx[r], off));

        float l[4] = {0.f, 0.f, 0.f, 0.f};
#pragma unroll
        for (int kt = 0; kt < 13; kt++)
#pragma unroll
            for (int ks = 0; ks < 2; ks++)
#pragma unroll
                for (int r = 0; r < 4; r++) {
                    float p = __expf(S[kt][ks][r] - mx[r]);
                    S[kt][ks][r] = p;
                    l[r] += p;
                }
#pragma unroll
        for (int off = 1; off <= 8; off <<= 1)
#pragma unroll
            for (int r = 0; r < 4; r++) l[r] += __shfl_xor(l[r], off);

        // ---- PV with unnormalized P
        vf4 accO[4];
#pragma unroll
        for (int dc = 0; dc < 4; dc++) accO[dc] = vf4{0.f, 0.f, 0.f, 0.f};
#pragma unroll
        for (int kt = 0; kt < 13; kt++) {
            u16* pw = Pl[w];
#pragma unroll
            for (int ks = 0; ks < 2; ks++)
#pragma unroll
                for (int r = 0; r < 4; r++)
                    pw[(q4 * 4 + r) * 40 + ks * 16 + lr] = f2bf(S[kt][ks][r]);
            vbf8 pf = *(const vbf8*)&Pl[w][lr * 40 + q4 * 8];
#pragma unroll
            for (int dc = 0; dc < 4; dc++) {
                vbf8 vf_ = *(const vbf8*)&Vt[(dc * 16 + lr) * VTS + kt * 32 + q4 * 8];
                accO[dc] = __builtin_amdgcn_mfma_f32_16x16x32_bf16(pf, vf_, accO[dc], 0, 0, 0);
            }
        }

        float invl[4];
#pragma unroll
        for (int r = 0; r < 4; r++) invl[r] = 1.f / l[r];

        // ---- sigma_q + denom + mem readout + blend (unchanged)
        vbf8 sq0, sq1;
        float dpart = 0.f;
#pragma unroll
        for (int j = 0; j < 8; j++) {
            float s0 = elu1(bf2f(((u16*)&qf0)[j]));
            float s1 = elu1(bf2f(((u16*)&qf1)[j]));
            ((u16*)&sq0)[j] = f2bf(s0);
            ((u16*)&sq1)[j] = f2bf(s1);
            dpart += s0 * zp[q4 * 8 + j] + s1 * zp[32 + q4 * 8 + j];
        }
        dpart += __shfl_xor(dpart, 16);
        dpart += __shfl_xor(dpart, 32);
        if (q4 == 0) red[w][lr] = dpart;

        vf4 am[4];
#pragma unroll
        for (int dc = 0; dc < 4; dc++) {
            vbf8 b0 = *(const vbf8*)(mtb + (dc * 16 + lr) * 64 + q4 * 8);
            vbf8 b1 = *(const vbf8*)(mtb + (dc * 16 + lr) * 64 + 32 + q4 * 8);
            vf4 z4 = vf4{0.f, 0.f, 0.f, 0.f};
            vf4 a = __builtin_amdgcn_mfma_f32_16x16x32_bf16(sq0, b0, z4, 0, 0, 0);
            am[dc] = __builtin_amdgcn_mfma_f32_16x16x32_bf16(sq1, b1, a, 0, 0, 0);
        }
        float den[4];
#pragma unroll
        for (int r = 0; r < 4; r++) den[r] = 1.f / red[w][q4 * 4 + r];

#pragma unroll
        for (int dc = 0; dc < 4; dc++) {
            float bb = betas[h * D_ + dc * 16 + lr];
            float beta = 1.f / (1.f + __expf(-bb));
#pragma unroll
            for (int r = 0; r < 4; r++) {
                int qs = s * 16 + q4 * 4 + r;
                if (qs < NS) {
                    float o = beta * (am[dc][r] * den[r]) +
                              (1.f - beta) * (accO[dc][r] * invl[r]);
                    concat[((long long)(b * N_ + NT + qs)) * C_ + h * D_ + dc * 16 + lr] = f2bf(o);
                }
            }
        }
    }
}

// ---------------------------------------------------------------------------
// attn_mt_mfma v2: same full-row softmax (128 keys, no masking needed).
// ---------------------------------------------------------------------------
#define MTS 136
__global__ __launch_bounds__(512) void attn_mt_mfma(
    const u16* __restrict__ qkv, u16* __restrict__ concat)
{
    __shared__ __align__(16) u16 Kl[NT * 64];
    __shared__ __align__(16) u16 Vt[64 * MTS];
    __shared__ __align__(16) u16 Pl[8][16 * 40];

    int bh = blockIdx.x;
    int b = bh / H_, h = bh % H_;
    int t = threadIdx.x, lane = t & 63, w = t >> 6;
    int lr = lane & 15, q4 = lane >> 4;

    {
        int key0 = t >> 3;
        int d0 = (t & 7) * 8;
#pragma unroll
        for (int kp = 0; kp < NT; kp += 64) {
            int key = kp + key0;
            const u16* base = qkv + ((long long)(b * N_ + key)) * K3 + h * D_;
            vbf8 kv = *(const vbf8*)(base + C_ + d0);
            vbf8 vv = *(const vbf8*)(base + 2 * C_ + d0);
            *(vbf8*)((char*)Kl + ((key * 128 + d0 * 2) ^ ((key & 7) << 4))) = kv;
#pragma unroll
            for (int u = 0; u < 8; u++) Vt[(d0 + u) * MTS + key] = ((u16*)&vv)[u];
        }
    }
    __syncthreads();

    int qtok = w * 16 + lr;
    const u16* qbase = qkv + ((long long)(b * N_ + qtok)) * K3 + h * D_;
    vbf8 qf0 = *(const vbf8*)(qbase + q4 * 8);
    vbf8 qf1 = *(const vbf8*)(qbase + 32 + q4 * 8);
    vbf8 qs0, qs1;
#pragma unroll
    for (int j = 0; j < 8; j++) {
        ((u16*)&qs0)[j] = f2bf(bf2f(((u16*)&qf0)[j]) * 0.125f);
        ((u16*)&qs1)[j] = f2bf(bf2f(((u16*)&qf1)[j]) * 0.125f);
    }

    vf4 S[4][2];
#pragma unroll
    for (int kt = 0; kt < 4; kt++) {
#pragma unroll
        for (int ks = 0; ks < 2; ks++) {
            int krow = kt * 32 + ks * 16 + lr;
            int swz = (krow & 7) << 4;
            vbf8 b0 = *(const vbf8*)((char*)Kl + ((krow * 128 + q4 * 16) ^ swz));
            vbf8 b1 = *(const vbf8*)((char*)Kl + ((krow * 128 + 64 + q4 * 16) ^ swz));
            vf4 z4 = vf4{0.f, 0.f, 0.f, 0.f};
            vf4 sv = __builtin_amdgcn_mfma_f32_16x16x32_bf16(qs0, b0, z4, 0, 0, 0);
            S[kt][ks] = __builtin_amdgcn_mfma_f32_16x16x32_bf16(qs1, b1, sv, 0, 0, 0);
        }
    }

    float mx[4];
#pragma unroll
    for (int r = 0; r < 4; r++) mx[r] = S[0][0][r];
#pragma unroll
    for (int kt = 0; kt < 4; kt++)
#pragma unroll
        for (int ks = 0; ks < 2; ks++)
#pragma unroll
            for (int r = 0; r < 4; r++) mx[r] = fmaxf(mx[r], S[kt][ks][r]);
#pragma unroll
    for (int off = 1; off <= 8; off <<= 1)
#pragma unroll
        for (int r = 0; r < 4; r++) mx[r] = fmaxf(mx[r], __shfl_xor(mx[r], off));

    float l[4] = {0.f, 0.f, 0.f, 0.f};
#pragma unroll
    for (int kt = 0; kt < 4; kt++)
#pragma unroll
        for (int ks = 0; ks < 2; ks++)
#pragma unroll
            for (int r = 0; r < 4; r++) {
                float p = __expf(S[kt][ks][r] - mx[r]);
                S[kt][ks][r] = p;
                l[r] += p;
            }
#pragma unroll
    for (int off = 1; off <= 8; off <<= 1)
#pragma unroll
        for (int r = 0; r < 4; r++) l[r] += __shfl_xor(l[r], off);

    vf4 accO[4];
#pragma unroll
    for (int dc = 0; dc < 4; dc++) accO[dc] = vf4{0.f, 0.f, 0.f, 0.f};
#pragma unroll
    for (int kt = 0; kt < 4; kt++) {
        u16* pw = Pl[w];
#pragma unroll
        for (int ks = 0; ks < 2; ks++)
#pragma unroll
            for (int r = 0; r < 4; r++)
                pw[(q4 * 4 + r) * 40 + ks * 16 + lr] = f2bf(S[kt][ks][r]);
        vbf8 pf = *(const vbf8*)&Pl[w][lr * 40 + q4 * 8];
#pragma unroll
        for (int dc = 0; dc < 4; dc++) {
            vbf8 vf_ = *(const vbf8*)&Vt[(dc * 16 + lr) * MTS + kt * 32 + q4 * 8];
            accO[dc] = __builtin_amdgcn_mfma_f32_16x16x32_bf16(pf, vf_, accO[dc], 0, 0, 0);
        }
    }

    float invl[4];
#pragma unroll
    for (int r = 0; r < 4; r++) invl[r] = 1.f / l[r];

    int qt0 = w * 16;
#pragma unroll
    for (int dc = 0; dc < 4; dc++)
#pragma unroll
        for (int r = 0; r < 4; r++) {
            int row = qt0 + q4 * 4 + r;
            concat[((long long)(b * N_ + row)) * C_ + h * D_ + dc * 16 + lr] =
                f2bf(accO[dc][r] * invl[r]);
        }
}

// ---------------------------------------------------------------------------
// sigma_pred_mfma (unchanged)
// ---------------------------------------------------------------------------
__global__ __launch_bounds__(512) void sigma_pred_mfma(
    const u16* __restrict__ ksm, const u16* __restrict__ vsm,
    const u16* __restrict__ memT, const float* __restrict__ zin,
    u16* __restrict__ sigT, u16* __restrict__ wT,
    float* __restrict__ z_out)
{
    __shared__ u16 sigLDS[8][64][18];
    __shared__ u16 wLDS[8][64][18];
    __shared__ float red[8][16];
    __shared__ float zpart[8][64];
    __shared__ float zlds[64];

    int bh = blockIdx.x;
    int b = bh / H_, h = bh % H_;
    int t = threadIdx.x, lane = t & 63, w = t >> 6;
    int lr = lane & 15, q4 = lane >> 4;

    if (t < 64) zlds[t] = zin[bh * 64 + t];
    __syncthreads();

    const u16* mtb = memT + (long long)bh * 4096;
    float zacc[16];
#pragma unroll
    for (int j = 0; j < 16; j++) zacc[j] = 0.f;

    for (int s = w; s < 18; s += 8) {
        int n0 = s * 16;
        int nrow = n0 + lr;
        bool vrow = nrow < NS;
        int nclamp = vrow ? nrow : NS - 1;
        const u16* kbase = ksm + ((long long)(b * NS + nclamp)) * C_ + h * D_;
        vbf8 k0 = *(const vbf8*)(kbase + q4 * 8);
        vbf8 k1 = *(const vbf8*)(kbase + 32 + q4 * 8);

        vbf8 sq0, sq1;
        float dpart = 0.f;
#pragma unroll
        for (int j = 0; j < 8; j++) {
            float s0 = vrow ? elu1(bf2f(((u16*)&k0)[j])) : 0.f;
            float s1 = vrow ? elu1(bf2f(((u16*)&k1)[j])) : 0.f;
            ((u16*)&sq0)[j] = f2bf(s0);
            ((u16*)&sq1)[j] = f2bf(s1);
            zacc[j]     += s0;
            zacc[8 + j] += s1;
            dpart += s0 * zlds[q4 * 8 + j] + s1 * zlds[32 + q4 * 8 + j];
        }
        dpart += __shfl_xor(dpart, 16);
        dpart += __shfl_xor(dpart, 32);
        if (q4 == 0) red[w][lr] = dpart;

#pragma unroll
        for (int j = 0; j < 8; j++) {
            sigLDS[w][q4 * 8 + j][lr]      = ((u16*)&sq0)[j];
            sigLDS[w][32 + q4 * 8 + j][lr] = ((u16*)&sq1)[j];
        }

        vf4 am[4];
#pragma unroll
        for (int dc = 0; dc < 4; dc++) {
            vbf8 b0 = *(const vbf8*)(mtb + (dc * 16 + lr) * 64 + q4 * 8);
            vbf8 b1 = *(const vbf8*)(mtb + (dc * 16 + lr) * 64 + 32 + q4 * 8);
            vf4 z4 = vf4{0.f, 0.f, 0.f, 0.f};
            vf4 a = __builtin_amdgcn_mfma_f32_16x16x32_bf16(sq0, b0, z4, 0, 0, 0);
            am[dc] = __builtin_amdgcn_mfma_f32_16x16x32_bf16(sq1, b1, a, 0, 0, 0);
        }
        float rden[4];
#pragma unroll
        for (int r = 0; r < 4; r++) rden[r] = 1.f / red[w][q4 * 4 + r];

#pragma unroll
        for (int dc = 0; dc < 4; dc++) {
            int e = dc * 16 + lr;
#pragma unroll
            for (int r = 0; r < 4; r++) {
                int nn = n0 + q4 * 4 + r;
                float wv = 0.f;
                if (nn < NS) {
                    float pv = am[dc][r] * rden[r];
                    wv = bf2f(vsm[((long long)(b * NS + nn)) * C_ + h * D_ + e]) - pv;
                }
                wLDS[w][e][q4 * 4 + r] = f2bf(wv);
            }
        }

        {
            long long dst = ((long long)bh * 64 + lane) * SPS + n0;
            unsigned pk[8];
#pragma unroll
            for (int j2 = 0; j2 < 8; j2++)
                pk[j2] = (unsigned)sigLDS[w][lane][2 * j2] |
                         ((unsigned)sigLDS[w][lane][2 * j2 + 1] << 16);
            *(uint4*)(sigT + dst)     = uint4{pk[0], pk[1], pk[2], pk[3]};
            *(uint4*)(sigT + dst + 8) = uint4{pk[4], pk[5], pk[6], pk[7]};
#pragma unroll
            for (int j2 = 0; j2 < 8; j2++)
                pk[j2] = (unsigned)wLDS[w][lane][2 * j2] |
                         ((unsigned)wLDS[w][lane][2 * j2 + 1] << 16);
            *(uint4*)(wT + dst)     = uint4{pk[0], pk[1], pk[2], pk[3]};
            *(uint4*)(wT + dst + 8) = uint4{pk[4], pk[5], pk[6], pk[7]};
        }
    }

#pragma unroll
    for (int off = 1; off <= 8; off <<= 1)
#pragma unroll
        for (int j = 0; j < 16; j++) zacc[j] += __shfl_xor(zacc[j], off);
    if (lr == 0) {
#pragma unroll
        for (int j = 0; j < 8; j++) {
            zpart[w][q4 * 8 + j]      = zacc[j];
            zpart[w][32 + q4 * 8 + j] = zacc[8 + j];
        }
    }
    __syncthreads();
    if (t < 64) {
        float tot = 0.f;
#pragma unroll
        for (int ww = 0; ww < 8; ww++) tot += zpart[ww][t];
        z_out[bh * 64 + t] = zlds[t] + tot;
    }
}

// ---------------------------------------------------------------------------
// mem_update_mfma (unchanged)
// ---------------------------------------------------------------------------
__global__ __launch_bounds__(64) void mem_update_mfma(
    const u16* __restrict__ sigT, const u16* __restrict__ wT,
    const float* __restrict__ memin, float* __restrict__ mem_out)
{
    int bh = blockIdx.x;
    int lane = threadIdx.x;
    int lr = lane & 15, q4 = lane >> 4;

    const u16* sb = sigT + (long long)bh * 64 * SPS;
    const u16* wb = wT   + (long long)bh * 64 * SPS;

    vf4 acc[4][4];
#pragma unroll
    for (int i = 0; i < 4; i++)
#pragma unroll
        for (int j = 0; j < 4; j++) acc[i][j] = vf4{0.f, 0.f, 0.f, 0.f};

    for (int kt = 0; kt < SPS; kt += 32) {
        vbf8 af[4], bf[4];
#pragma unroll
        for (int i = 0; i < 4; i++)
            af[i] = *(const vbf8*)(sb + (long long)(i * 16 + lr) * SPS + kt + q4 * 8);
#pragma unroll
        for (int j = 0; j < 4; j++)
            bf[j] = *(const vbf8*)(wb + (long long)(j * 16 + lr) * SPS + kt + q4 * 8);
#pragma unroll
        for (int i = 0; i < 4; i++)
#pragma unroll
            for (int j = 0; j < 4; j++)
                acc[i][j] = __builtin_amdgcn_mfma_f32_16x16x32_bf16(
                    af[i], bf[j], acc[i][j], 0, 0, 0);
    }

    long long mb = (long long)bh * 4096;
#pragma unroll
    for (int i = 0; i < 4; i++)
#pragma unroll
        for (int j = 0; j < 4; j++)
#pragma unroll
            for (int r = 0; r < 4; r++) {
                int d = i * 16 + q4 * 4 + r;
                int e = j * 16 + lr;
                mem_out[mb + d * 64 + e] = memin[mb + d * 64 + e] + acc[i][j][r];
            }
}

// ---------------------------------------------------------------------------
extern "C" void kernel_launch(void* const* d_in, const int* in_sizes, int n_in,
                              void* d_out, int out_size, void* d_ws, size_t ws_size,
                              hipStream_t stream)
{
    const float* x      = (const float*)d_in[0];
    const float* mem    = (const float*)d_in[1];
    const float* z      = (const float*)d_in[2];
    const float* qkv_w  = (const float*)d_in[3];
    const float* qkv_b  = (const float*)d_in[4];
    const float* proj_w = (const float*)d_in[5];
    const float* proj_b = (const float*)d_in[6];
    const float* memk_w = (const float*)d_in[7];
    const float* memk_b = (const float*)d_in[8];
    const float* memv_w = (const float*)d_in[9];
    const float* memv_b = (const float*)d_in[10];
    const float* betas  = (const float*)d_in[11];

    u16* ws     = (u16*)d_ws;
    u16* qkv    = ws;
    u16* ksm    = qkv + QKV_LEN;
    u16* vsm    = ksm + KSM_LEN;
    u16* concat = vsm + KSM_LEN;      // doubles as x_bf before attn writes it

    float* out     = (float*)d_out;
    float* mem_out = out + CAT_LEN;
    float* z_out   = mem_out + MEM_LEN;

    u16* x_bf = concat;               // alias: dead after qkv GEMM
    u16* memT = (u16*)mem_out;        // scratch in mem_out region (overwritten last)
    u16* sigT = qkv;                  // alias: qkv dead after attn kernels
    u16* wT   = qkv + SWT_LEN;

    // 0. conversions
    convert_bf16<<<dim3(2048), dim3(256), 0, stream>>>(x, x_bf, CAT_LEN);
    convert_wbf<<<dim3(864), dim3(256), 0, stream>>>(qkv_w,  WOFF_QKV,  1769472ll);
    convert_wbf<<<dim3(288), dim3(256), 0, stream>>>(memk_w, WOFF_MEMK, 589824ll);
    convert_wbf<<<dim3(288), dim3(256), 0, stream>>>(memv_w, WOFF_MEMV, 589824ll);
    convert_wbf<<<dim3(288), dim3(256), 0, stream>>>(proj_w, WOFF_PROJ, 589824ll);
    memT_kernel<<<dim3(B_ * H_), dim3(256), 0, stream>>>(mem, memT);

    // 1. qkv = x @ qkv_w^T + qkv_b   (grid 18 x 388 = 6984, %8 == 0)
    gemm_mfma<0><<<dim3(6984), dim3(256), 0, stream>>>(
        x_bf, 0ll, 49664, 0ll, 768ll, WOFF_QKV, qkv_b, qkv, K3, 18);
    // 2. k_s_mem                      (grid 6 x 260 = 1560)
    gemm_mfma<0><<<dim3(1560), dim3(256), 0, stream>>>(
        qkv, (long long)(NT * K3 + C_), NS, (long long)N_ * K3, (long long)K3,
        WOFF_MEMK, memk_b, ksm, C_, 6);
    // 3. v_s_mem
    gemm_mfma<0><<<dim3(1560), dim3(256), 0, stream>>>(
        qkv, (long long)(NT * K3 + 2 * C_), NS, (long long)N_ * K3, (long long)K3,
        WOFF_MEMV, memv_b, vsm, C_, 6);
    // 4. spatial attention (+ mem readout + blend) -> concat[:, NT:]
    attn_s_mfma<<<dim3(B_ * H_), dim3(512), 0, stream>>>(
        qkv, memT, z, betas, concat);
    // 5. token/token attention -> concat[:, :NT]
    attn_mt_mfma<<<dim3(B_ * H_), dim3(512), 0, stream>>>(qkv, concat);
    // 6. sigma/pred -> sigT/wT (overwrites qkv region) + z_new
    sigma_pred_mfma<<<dim3(B_ * H_), dim3(512), 0, stream>>>(
        ksm, vsm, memT, z, sigT, wT, z_out);
    // 7. mem_new = mem + sigT @ wT^T (overwrites memT scratch)
    mem_update_mfma<<<dim3(B_ * H_), dim3(64), 0, stream>>>(
        sigT, wT, mem, mem_out);
    // 8. out = concat @ proj_w^T + proj_b   (grid 6 x 388 = 2328)
    gemm_mfma<1><<<dim3(2328), dim3(256), 0, stream>>>(
        concat, 0ll, 49664, 0ll, 768ll, WOFF_PROJ, proj_b, out, C_, 6);
}